// Round 7
// baseline (1567365.820 us; speedup 1.0000x reference)
//
#include <hip/hip_runtime.h>
#include <math.h>

// MPS center-orthogonalization sweep (CHI=512, Q=2, NQUBIT=24, complex64).
// Faithful GPU port of the Vh/S side of LAPACK cgesdd (jobz='S') over 23
// sites.  Round 7: R6's per-reflector dispatch chains (22.7k launches, ~43us
// fixed cost each = ~0.97s) are replaced by PERSISTENT kernels (pk_qr, pk_bd)
// with a hand-rolled device-scope barrier between phases.  Phase bodies are
// byte-identical to R6's verified u_qr / u_bd_col / u_bd_row.  128 blocks x
// 256 thr (<=256 CUs) guarantees co-residency; spin uses s_sleep + bail-out
// flag (degrades to wrong answer, never hangs).  Small sites, sbdsdc, u_ph,
// glue: R6 verbatim.

#define LDV 513
typedef float2 cplx;

__device__ __forceinline__ cplx cmul(cplx a, cplx b){ return make_float2(a.x*b.x - a.y*b.y, a.x*b.y + a.y*b.x); }
__device__ __forceinline__ cplx cmulc(cplx a, cplx b){ /*conj(a)*b*/ return make_float2(a.x*b.x + a.y*b.y, a.x*b.y - a.y*b.x); }
__device__ __forceinline__ cplx cadd(cplx a, cplx b){ return make_float2(a.x+b.x, a.y+b.y); }
__device__ __forceinline__ cplx csub(cplx a, cplx b){ return make_float2(a.x-b.x, a.y-b.y); }
__device__ __forceinline__ cplx conjc(cplx a){ return make_float2(a.x, -a.y); }

#define EPS_S 5.9604645e-8f
#define UNFL_S 1.17549435e-38f
#define UW 512    // waves in persistent update grid (128 blocks x 256 thr)
#define UBLK 128  // blocks for persistent/hot kernels

// ---------------- device global workspace ----------------
__device__ cplx g_A[1024*512];     // current M / QR-LQ factors (raw)
__device__ cplx g_B[512*512];      // square matrix for bidiagonalization (raw)
__device__ cplx g_VTc[512*512];    // complex VT being assembled
__device__ cplx g_R[512*512];      // bond matrix R = diag(s)*VT
__device__ cplx g_tauf[520];       // LQ taus (small path)
__device__ cplx g_taup[520];       // cgebd2 row taus
__device__ float g_d[520], g_e[520];
__device__ float g_VTr[LDV*LDV];
__device__ float g_VT2[LDV*LDV];
__device__ float g_W[LDV*LDV];
__device__ float g_z[520], g_zz[520], g_zorig[520], g_dtmp[520], g_ztmp[520], g_dsig[520];
__device__ double g_root[520];
__device__ int g_idxq[520], g_idx[520], g_idxp[520], g_rowmap[520];
__device__ int g_inode[80], g_ndiml[80], g_ndimr[80];
__device__ float g_sig[520];
__device__ int g_K, g_nlvl_, g_nd_;
__device__ float g_tol_, g_z1_;
__device__ double g_rho_;
// big-path chain scalars
__device__ float g_scq[520];       // QR column-tail norms
__device__ float g_betaq[520];     // QR betas (R diagonal)
__device__ float g_rn[520];        // BD row-reflector tail norms (u_ph recompute)
__device__ float g_partC[UW];      // BD col-phase per-wave partials
__device__ float g_partR[UW];      // BD row-phase / prologue partials
// device barrier state
__device__ unsigned g_barc = 0;    // arrival count
__device__ unsigned g_barg = 0;    // generation
__device__ int g_barfail = 0;      // set on spin timeout -> all barriers bail

// ---------------- device-scope sense-reversing barrier ----------------
__device__ __forceinline__ void gbar(){
  __syncthreads();
  if (threadIdx.x==0){
    if (!g_barfail){
      __threadfence();
      unsigned gen=__hip_atomic_load(&g_barg,__ATOMIC_RELAXED,__HIP_MEMORY_SCOPE_AGENT);
      unsigned prev=__hip_atomic_fetch_add(&g_barc,1u,__ATOMIC_ACQ_REL,__HIP_MEMORY_SCOPE_AGENT);
      if (prev+1u==(unsigned)gridDim.x){
        __hip_atomic_store(&g_barc,0u,__ATOMIC_RELAXED,__HIP_MEMORY_SCOPE_AGENT);
        __hip_atomic_store(&g_barg,gen+1u,__ATOMIC_RELEASE,__HIP_MEMORY_SCOPE_AGENT);
      } else {
        long k=0;
        while (__hip_atomic_load(&g_barg,__ATOMIC_ACQUIRE,__HIP_MEMORY_SCOPE_AGENT)==gen){
          __builtin_amdgcn_s_sleep(2);
          if (++k>(1L<<24)){ g_barfail=1; break; }
        }
      }
      __threadfence();
    }
  }
  __syncthreads();
}

// ---------------- reduce helpers ----------------
__device__ __forceinline__ float wred(float v){
  for (int off=32;off;off>>=1) v+=__shfl_down(v,off);
  return v;
}
// deterministic 512-entry reduce done identically in every block (256 thr)
__device__ __forceinline__ float reduce512(const float* arr){
  __shared__ float sr[256];
  sr[threadIdx.x]=arr[threadIdx.x]+arr[threadIdx.x+256];
  __syncthreads();
  for (int s=128;s>0;s>>=1){
    if (threadIdx.x<s) sr[threadIdx.x]+=sr[threadIdx.x+s];
    __syncthreads();
  }
  float v=sr[0];
  __syncthreads();
  return v;
}

// ---------------- clarfg (LAPACK conventions) ----------------
struct RfgOut { float beta; cplx tau; cplx scal; int skip; };
__device__ RfgOut clarfg_head(cplx alpha, float xn2){
  RfgOut o;
  if (xn2==0.f && alpha.y==0.f){
    o.beta=alpha.x; o.tau=make_float2(0.f,0.f); o.scal=make_float2(0.f,0.f); o.skip=1;
  } else {
    float anorm=sqrtf(alpha.x*alpha.x+alpha.y*alpha.y+xn2);
    float beta=(alpha.x>=0.f)?-anorm:anorm;
    o.beta=beta;
    o.tau=make_float2((beta-alpha.x)/beta,-alpha.y/beta);
    cplx dd=make_float2(alpha.x-beta,alpha.y);
    float dn=dd.x*dd.x+dd.y*dd.y;
    o.scal=make_float2(dd.x/dn,-dd.y/dn);
    o.skip=0;
  }
  return o;
}

// ---------------- small serial real-LAPACK helpers (round-2 verbatim) ----------------
__device__ float slapy2(float x, float y){
  float xa=fabsf(x), ya=fabsf(y);
  float w=fmaxf(xa,ya), z=fminf(xa,ya);
  if (z==0.f) return w;
  float q=z/w; return w*sqrtf(1.f+q*q);
}

__device__ void slartg(float f, float g, float* cs, float* sn, float* r){
  if (g==0.f){ *cs=1.f; *sn=0.f; *r=f; }
  else if (f==0.f){ *cs=0.f; *sn=(g>0.f)?1.f:-1.f; *r=fabsf(g); }
  else {
    float f1=fabsf(f);
    float d=sqrtf(f*f+g*g);
    *cs = f1/d;
    *r = (f>0.f)? d : -d;
    *sn = g / *r;
  }
}

__device__ void slas2(float f, float g, float h, float* ssmin, float* ssmax){
  float fa=fabsf(f), ga=fabsf(g), ha=fabsf(h);
  float fhmn=fminf(fa,ha), fhmx=fmaxf(fa,ha);
  if (fhmn==0.f){
    *ssmin=0.f;
    if (fhmx==0.f) *ssmax=ga;
    else { float mx=fmaxf(fhmx,ga), mn=fminf(fhmx,ga); float q=mn/mx; *ssmax=mx*sqrtf(1.f+q*q); }
  } else {
    if (ga < fhmx){
      float as=1.f+fhmn/fhmx, at=(fhmx-fhmn)/fhmx;
      float au=ga/fhmx; au=au*au;
      float c=2.f/(sqrtf(as*as+au)+sqrtf(at*at+au));
      *ssmin=fhmn*c; *ssmax=fhmx/c;
    } else {
      float au=fhmx/ga;
      if (au==0.f){ *ssmin=(fhmn*fhmx)/ga; *ssmax=ga; }
      else {
        float as=1.f+fhmn/fhmx, at=(fhmx-fhmn)/fhmx;
        float c=1.f/(sqrtf(1.f+(as*au)*(as*au))+sqrtf(1.f+(at*au)*(at*au)));
        *ssmin=(fhmn*c)*au; *ssmin=*ssmin+*ssmin;
        *ssmax=ga/(c+c);
      }
    }
  }
}

__device__ void slasv2(float f, float g, float h, float* ssmin, float* ssmax,
                       float* snr, float* csr, float* snl, float* csl){
  float ft=f, fa=fabsf(f), ht=h, ha=fabsf(h);
  int pmax=1;
  bool swap_=(ha>fa);
  if (swap_){ pmax=3; float t=ft; ft=ht; ht=t; t=fa; fa=ha; ha=t; }
  float gt=g, ga=fabsf(g);
  float clt=0.f, crt=0.f, slt=0.f, srt=0.f;
  if (ga==0.f){ *ssmin=ha; *ssmax=fa; clt=1.f; crt=1.f; slt=0.f; srt=0.f; }
  else {
    bool gasmal=true;
    if (ga>fa){
      pmax=2;
      if ((fa/ga) < EPS_S){
        gasmal=false;
        *ssmax=ga;
        if (ha>1.f) *ssmin=fa/(ga/ha); else *ssmin=(fa/ga)*ha;
        clt=1.f; slt=ht/gt; srt=1.f; crt=ft/gt;
      }
    }
    if (gasmal){
      float d=fa-ha;
      float l=(d==fa)?1.f:(d/fa);
      float mm=gt/ft;
      float t=2.f-l;
      float mm2=mm*mm, tt=t*t;
      float s=sqrtf(tt+mm2);
      float r=(l==0.f)?fabsf(mm):sqrtf(l*l+mm2);
      float a=0.5f*(s+r);
      *ssmin=ha/a; *ssmax=fa*a;
      if (mm2==0.f){
        if (l==0.f) t=copysignf(2.f,ft)*copysignf(1.f,gt);
        else t=gt/copysignf(d,ft)+mm/t;
      } else {
        t=(mm/(s+t)+mm/(r+l))*(1.f+a);
      }
      float l2=sqrtf(t*t+4.f);
      crt=2.f/l2; srt=t/l2;
      clt=(crt+srt*mm)/a;
      slt=(ht/ft)*srt/a;
    }
  }
  if (swap_){ *csl=srt; *snl=crt; *csr=slt; *snr=clt; }
  else      { *csl=clt; *snl=slt; *csr=crt; *snr=srt; }
  float tsign=0.f;
  if (pmax==1) tsign=copysignf(1.f,*csr)*copysignf(1.f,*csl)*copysignf(1.f,f);
  if (pmax==2) tsign=copysignf(1.f,*snr)*copysignf(1.f,*csl)*copysignf(1.f,g);
  if (pmax==3) tsign=copysignf(1.f,*snr)*copysignf(1.f,*snl)*copysignf(1.f,h);
  *ssmax=copysignf(*ssmax,tsign);
  *ssmin=copysignf(*ssmin,tsign*copysignf(1.f,f)*copysignf(1.f,h));
}

__device__ void slasr_f(int mrows, int ncols, const float* c1, const float* s1, float* a, int lda){
  for (int j=1;j<=mrows-1;++j){
    float ct=c1[j], st=s1[j];
    if (ct!=1.f || st!=0.f){
      float* rj=&a[(j-1)*lda]; float* rj1=&a[j*lda];
      for (int i=0;i<ncols;++i){
        float tmp=rj1[i];
        rj1[i]=ct*tmp-st*rj[i];
        rj[i]=st*tmp+ct*rj[i];
      }
    }
  }
}
__device__ void slasr_b(int mrows, int ncols, const float* c1, const float* s1, float* a, int lda){
  for (int j=mrows-1;j>=1;--j){
    float ct=c1[j], st=s1[j];
    if (ct!=1.f || st!=0.f){
      float* rj=&a[(j-1)*lda]; float* rj1=&a[j*lda];
      for (int i=0;i<ncols;++i){
        float tmp=rj1[i];
        rj1[i]=ct*tmp-st*rj[i];
        rj[i]=st*tmp+ct*rj[i];
      }
    }
  }
}

// serial SBDSQR('U', n, ncvt, 0, 0) — VT only.
__device__ void sbdsqr_u(int n, int ncvt, float* d, float* e, float* vt, int ldvt){
  const int MAXITR=6;
  if (n==0) return;
  if (n>1){
    int nm1=n-1, nm12=nm1+nm1, nm13=nm12+nm1;
    float wk[112];
    float tolmul=10.f;
    float tol=tolmul*EPS_S;
    float smax=0.f;
    for (int i=1;i<=n;i++) smax=fmaxf(smax,fabsf(d[i]));
    for (int i=1;i<=n-1;i++) smax=fmaxf(smax,fabsf(e[i]));
    float sminl=0.f, thresh;
    {
      float sminoa=fabsf(d[1]);
      if (sminoa!=0.f){
        float mu=sminoa;
        for (int i=2;i<=n;i++){
          mu=fabsf(d[i])*(mu/(mu+fabsf(e[i-1])));
          sminoa=fminf(sminoa,mu);
          if (sminoa==0.f) break;
        }
      }
      sminoa=sminoa/sqrtf((float)n);
      thresh=fmaxf(tol*sminoa,(float)(MAXITR*n*n)*UNFL_S);
    }
    int M=n, iter=0, maxit=MAXITR*n*n;
    int oldll=-1, oldm=-1, idir=0;
    while (1){
      if (M<=1) break;
      if (iter>maxit) break;
      int ll=0; bool split=false;
      smax=fabsf(d[M]);
      for (int lll=1;lll<=M-1;++lll){
        ll=M-lll;
        float abss=fabsf(d[ll]), abse=fabsf(e[ll]);
        if (abse<=thresh){ split=true; break; }
        smax=fmaxf(smax,fmaxf(abss,abse));
      }
      if (!split) ll=0;
      else {
        e[ll]=0.f;
        if (ll==M-1){ M=M-1; continue; }
      }
      ll=ll+1;
      if (ll==M-1){
        float sigmn,sigmx,sinr,cosr,sinl,cosl;
        slasv2(d[M-1],e[M-1],d[M],&sigmn,&sigmx,&sinr,&cosr,&sinl,&cosl);
        d[M-1]=sigmx; e[M-1]=0.f; d[M]=sigmn;
        if (ncvt>0){
          float* x=&vt[(M-2)*ldvt]; float* y=&vt[(M-1)*ldvt];
          for (int c=0;c<ncvt;c++){ float xv=x[c],yv=y[c]; x[c]=cosr*xv+sinr*yv; y[c]=cosr*yv-sinr*xv; }
        }
        M-=2; continue;
      }
      if (ll>oldm || M<oldll) idir=(fabsf(d[ll])>=fabsf(d[M]))?1:2;
      bool conv=false;
      if (idir==1){
        if (fabsf(e[M-1])<=fabsf(tol)*fabsf(d[M])){ e[M-1]=0.f; conv=true; }
        else {
          float mu=fabsf(d[ll]); sminl=mu;
          for (int lll=ll;lll<=M-1;++lll){
            if (fabsf(e[lll])<=tol*mu){ e[lll]=0.f; conv=true; break; }
            mu=fabsf(d[lll+1])*(mu/(mu+fabsf(e[lll])));
            sminl=fminf(sminl,mu);
          }
        }
      } else {
        if (fabsf(e[ll])<=fabsf(tol)*fabsf(d[ll])){ e[ll]=0.f; conv=true; }
        else {
          float mu=fabsf(d[M]); sminl=mu;
          for (int lll=M-1;lll>=ll;--lll){
            if (fabsf(e[lll])<=tol*mu){ e[lll]=0.f; conv=true; break; }
            mu=fabsf(d[lll])*(mu/(mu+fabsf(e[lll])));
            sminl=fminf(sminl,mu);
          }
        }
      }
      if (conv) continue;
      oldll=ll; oldm=M;
      float shift=0.f, rr;
      if ((float)n*tol*(sminl/smax)<=fmaxf(EPS_S,0.01f*tol)) shift=0.f;
      else {
        float sll;
        if (idir==1){ sll=fabsf(d[ll]); slas2(d[M-1],e[M-1],d[M],&shift,&rr); }
        else        { sll=fabsf(d[M]);  slas2(d[ll],e[ll],d[ll+1],&shift,&rr); }
        if (sll>0.f){ float q=shift/sll; if (q*q<EPS_S) shift=0.f; }
      }
      iter += M-ll;
      if (shift==0.f){
        if (idir==1){
          float cs=1.f, oldcs=1.f, sn=0.f, oldsn=0.f;
          for (int i=ll;i<=M-1;++i){
            float c2,r1;
            slartg(d[i]*cs,e[i],&c2,&sn,&r1); cs=c2;
            if (i>ll) e[i-1]=oldsn*r1;
            float oc2;
            slartg(oldcs*r1,d[i+1]*sn,&oc2,&oldsn,&d[i]); oldcs=oc2;
            wk[i-ll+1]=cs; wk[i-ll+1+nm1]=sn;
          }
          float h=d[M]*cs; d[M]=h*oldcs; e[M-1]=h*oldsn;
          if (ncvt>0) slasr_f(M-ll+1,ncvt,wk,wk+nm1,&vt[(ll-1)*ldvt],ldvt);
          if (fabsf(e[M-1])<=thresh) e[M-1]=0.f;
        } else {
          float cs=1.f, oldcs=1.f, sn=0.f, oldsn=0.f;
          for (int i=M;i>=ll+1;--i){
            float c2,r1;
            slartg(d[i]*cs,e[i-1],&c2,&sn,&r1); cs=c2;
            if (i<M) e[i]=oldsn*r1;
            float oc2;
            slartg(oldcs*r1,d[i-1]*sn,&oc2,&oldsn,&d[i]); oldcs=oc2;
            wk[i-ll]=cs; wk[i-ll+nm1]=-sn;
            wk[i-ll+nm12]=oldcs; wk[i-ll+nm13]=-oldsn;
          }
          float h=d[ll]*cs; d[ll]=h*oldcs; e[ll]=h*oldsn;
          if (ncvt>0) slasr_b(M-ll+1,ncvt,wk+nm12,wk+nm13,&vt[(ll-1)*ldvt],ldvt);
          if (fabsf(e[ll])<=thresh) e[ll]=0.f;
        }
      } else {
        if (idir==1){
          float f=(fabsf(d[ll])-shift)*(copysignf(1.f,d[ll])+shift/d[ll]);
          float g=e[ll], cosr,sinr,cosl,sinl,r1;
          for (int i=ll;i<=M-1;++i){
            slartg(f,g,&cosr,&sinr,&r1);
            if (i>ll) e[i-1]=r1;
            f=cosr*d[i]+sinr*e[i];
            e[i]=cosr*e[i]-sinr*d[i];
            g=sinr*d[i+1];
            d[i+1]=cosr*d[i+1];
            slartg(f,g,&cosl,&sinl,&r1);
            d[i]=r1;
            f=cosl*e[i]+sinl*d[i+1];
            d[i+1]=cosl*d[i+1]-sinl*e[i];
            if (i<M-1){ g=sinl*e[i+1]; e[i+1]=cosl*e[i+1]; }
            wk[i-ll+1]=cosr; wk[i-ll+1+nm1]=sinr;
            wk[i-ll+1+nm12]=cosl; wk[i-ll+1+nm13]=sinl;
          }
          e[M-1]=f;
          if (ncvt>0) slasr_f(M-ll+1,ncvt,wk,wk+nm1,&vt[(ll-1)*ldvt],ldvt);
          if (fabsf(e[M-1])<=thresh) e[M-1]=0.f;
        } else {
          float f=(fabsf(d[M])-shift)*(copysignf(1.f,d[M])+shift/d[M]);
          float g=e[M-1], cosr,sinr,cosl,sinl,r1;
          for (int i=M;i>=ll+1;--i){
            slartg(f,g,&cosr,&sinr,&r1);
            if (i<M) e[i]=r1;
            f=cosr*d[i]+sinr*e[i-1];
            e[i-1]=cosr*e[i-1]-sinr*d[i];
            g=sinr*d[i-1];
            d[i-1]=cosr*d[i-1];
            slartg(f,g,&cosl,&sinl,&r1);
            d[i]=r1;
            f=cosl*e[i-1]+sinl*d[i-1];
            d[i-1]=cosl*d[i-1]-sinl*e[i-1];
            if (i>ll+1){ g=sinl*e[i-2]; e[i-2]=cosl*e[i-2]; }
            wk[i-ll]=cosr; wk[i-ll+nm1]=-sinr;
            wk[i-ll+nm12]=cosl; wk[i-ll+nm13]=-sinl;
          }
          e[ll]=f;
          if (fabsf(e[ll])<=thresh) e[ll]=0.f;
          if (ncvt>0) slasr_b(M-ll+1,ncvt,wk+nm12,wk+nm13,&vt[(ll-1)*ldvt],ldvt);
        }
      }
    }
  }
  for (int i=1;i<=n;i++){
    if (d[i]<0.f){
      d[i]=-d[i];
      if (ncvt>0){ float* row=&vt[(i-1)*ldvt]; for (int c=0;c<ncvt;c++) row[c]=-row[c]; }
    }
  }
  for (int i=1;i<=n-1;i++){
    int isub=1; float smin2=d[1];
    for (int j=2;j<=n+1-i;j++){ if (d[j]<=smin2){ isub=j; smin2=d[j]; } }
    if (isub!=n+1-i){
      d[isub]=d[n+1-i]; d[n+1-i]=smin2;
      if (ncvt>0){
        float* a=&vt[(isub-1)*ldvt]; float* b=&vt[(n-i)*ldvt];
        for (int c=0;c<ncvt;c++){ float t=a[c]; a[c]=b[c]; b[c]=t; }
      }
    }
  }
}

__device__ void slasdq_u(int sqre, int n, int ncvt, float* d, float* e, float* vt, int ldvt){
  if (n==0) return;
  float cwk[33], swk[33];
  int np1=n+1;
  if (sqre==1){
    for (int i=1;i<=n-1;i++){
      float cs,sn,r; slartg(d[i],e[i],&cs,&sn,&r);
      d[i]=r; e[i]=sn*d[i+1]; d[i+1]=cs*d[i+1];
      cwk[i]=cs; swk[i]=sn;
    }
    { float cs,sn,r; slartg(d[n],e[n],&cs,&sn,&r);
      d[n]=r; e[n]=0.f; cwk[n]=cs; swk[n]=sn; }
    if (ncvt>0) slasr_f(np1,ncvt,cwk,swk,vt,ldvt);
    for (int i=1;i<=n-1;i++){
      float cs,sn,r; slartg(d[i],e[i],&cs,&sn,&r);
      d[i]=r; e[i]=sn*d[i+1]; d[i+1]=cs*d[i+1];
    }
  }
  sbdsqr_u(n,ncvt,d,e,vt,ldvt);
  for (int i=1;i<=n;i++){
    int isub=i; float smin2=d[i];
    for (int j=i+1;j<=n;j++){ if (d[j]<smin2){ isub=j; smin2=d[j]; } }
    if (isub!=i){
      d[isub]=d[i]; d[i]=smin2;
      if (ncvt>0){
        float* a=&vt[(isub-1)*ldvt]; float* b=&vt[(i-1)*ldvt];
        for (int c=0;c<ncvt;c++){ float t=a[c]; a[c]=b[c]; b[c]=t; }
      }
    }
  }
}

__device__ void slamrg(int n1, int n2, const float* a, int s1, int s2, int* idx){
  int n1sv=n1, n2sv=n2, i=1;
  int ind1=(s1>0)?1:n1;
  int ind2=(s2>0)?(1+n1):(n1+n2);
  while (n1sv>0 && n2sv>0){
    if (a[ind1]<=a[ind2]){ idx[i++]=ind1; ind1+=s1; n1sv--; }
    else { idx[i++]=ind2; ind2+=s2; n2sv--; }
  }
  if (n1sv==0){ for(;n2sv>0;n2sv--){ idx[i++]=ind2; ind2+=s2; } }
  else { for(;n1sv>0;n1sv--){ idx[i++]=ind1; ind1+=s1; } }
}

__device__ void slasdt(int n, int* lvl, int* nd, int* inode, int* ndiml, int* ndimr, int msub){
  int maxn=(n>1)?n:1;
  float temp=logf((float)maxn/(float)(msub+1))/logf(2.f);
  *lvl=(int)temp+1;
  int i=n/2;
  inode[1]=i+1; ndiml[1]=i; ndimr[1]=n-i-1;
  int il=0, ir=1, llst=1;
  for (int nl=1;nl<=*lvl-1;++nl){
    for (int j=0;j<=llst-1;++j){
      il+=2; ir+=2;
      int nc=llst+j;
      ndiml[il]=ndiml[nc]/2;
      ndimr[il]=ndiml[nc]-ndiml[il]-1;
      inode[il]=inode[nc]-ndimr[il]-1;
      ndiml[ir]=ndimr[nc]/2;
      ndimr[ir]=ndimr[nc]-ndiml[ir]-1;
      inode[ir]=inode[nc]+ndiml[ir]+1;
    }
    llst*=2;
  }
  *nd=llst*2-1;
}

// ---------------- block-cooperative slasd1 (round-2 verbatim) ----------------
__device__ void merge_node(int nl, int nr, int sqre, float* d, int* idxq,
                           float alpha, float beta, float* VT, int ld)
{
  const int tid=threadIdx.x, nth=blockDim.x;
  const int n=nl+nr+1, m=n+sqre, nlp1=nl+1, nlp2=nl+2;
  if (tid==0){
    float* z=g_z;
    float z1=alpha*VT[(nlp1-1)*ld+(nlp1-1)];
    z[1]=z1; g_z1_=z1;
    for (int i=nl;i>=1;--i){
      z[i+1]=alpha*VT[(i-1)*ld+(nlp1-1)];
      d[i+1]=d[i];
      idxq[i+1]=idxq[i]+1;
    }
    for (int i=nlp2;i<=m;++i) z[i]=beta*VT[(i-1)*ld+(nlp2-1)];
    d[1]=0.f;
    for (int i=nlp2;i<=n;++i) idxq[i]+=nlp1;
    for (int i=2;i<=n;++i){ g_dtmp[i]=d[idxq[i]]; g_ztmp[i]=z[idxq[i]]; }
    slamrg(nl,nr,g_dtmp+1,1,1,g_idx+1);
    for (int i=2;i<=n;++i){
      int idxi=1+g_idx[i];
      d[i]=g_dtmp[idxi];
      z[i]=g_ztmp[idxi];
    }
    float tol=fmaxf(fabsf(alpha),fabsf(beta));
    tol=8.f*EPS_S*fmaxf(fabsf(d[n]),tol);
    g_tol_=tol;
    int K=1, K2=n+1, jprev=0, j;
    for (j=2;j<=n;++j){
      if (fabsf(z[j])<=tol){
        K2--; g_idxp[K2]=j;
        if (j==n){ jprev=0; break; }
      } else { jprev=j; break; }
    }
    if (jprev>0){
      j=jprev;
      for (;;){
        j++;
        if (j>n) break;
        if (fabsf(z[j])<=tol){ K2--; g_idxp[K2]=j; }
        else {
          if (fabsf(d[j]-d[jprev])<=tol){
            float s_=z[jprev], c_=z[j];
            float tau_=slapy2(c_,s_);
            c_/=tau_; s_=-s_/tau_;
            z[j]=tau_; z[jprev]=0.f;
            int idxjp=idxq[g_idx[jprev]+1];
            int idxj =idxq[g_idx[j]+1];
            if (idxjp<=nlp1) idxjp--;
            if (idxj <=nlp1) idxj--;
            float* xr=&VT[(idxjp-1)*ld];
            float* yr=&VT[(idxj-1)*ld];
            for (int cc=0;cc<m;++cc){
              float xv=xr[cc], yv=yr[cc];
              xr[cc]=c_*xv+s_*yv;
              yr[cc]=c_*yv-s_*xv;
            }
            K2--; g_idxp[K2]=jprev;
            jprev=j;
          } else {
            K++; g_zz[K]=z[jprev]; g_idxp[K]=jprev;
            jprev=j;
          }
        }
      }
      K++; g_zz[K]=z[jprev]; g_idxp[K]=jprev;
    }
    g_K=K;
    for (int jj=2;jj<=n;++jj){
      g_dsig[jj]=d[g_idxp[jj]];
      int rm=idxq[g_idx[g_idxp[jj]]+1];
      if (rm<=nlp1) rm--;
      g_rowmap[jj]=rm;
    }
  }
  __syncthreads();
  int K=g_K;
  for (int t=tid;t<(n-1)*m;t+=nth){
    int jj=2+t/m, cc=t%m;
    g_VT2[(jj-1)*LDV+cc]=VT[(g_rowmap[jj]-1)*ld+cc];
  }
  __syncthreads();
  if (tid==0){
    float tol=g_tol_;
    g_dsig[1]=0.f;
    float hlftol=tol*0.5f;
    if (fabsf(g_dsig[2])<=hlftol) g_dsig[2]=hlftol;
    float z1=g_z1_;
    float c_=1.f, s_=0.f;
    if (m>n){
      float t1=slapy2(z1,g_z[m]);
      if (t1<=tol){ c_=1.f; s_=0.f; g_z[1]=tol; }
      else { g_z[1]=t1; c_=z1/t1; s_=g_z[m]/t1; }
    } else {
      if (fabsf(z1)<=tol) g_z[1]=tol; else g_z[1]=z1;
    }
    for (int jj=2;jj<=K;++jj) g_z[jj]=g_zz[jj];
    if (m>n){
      for (int i=1;i<=nlp1;++i){
        float v=VT[(nlp1-1)*ld+(i-1)];
        VT[(m-1)*ld+(i-1)]=-s_*v;
        g_VT2[(i-1)]=c_*v;
      }
      for (int i=nlp2;i<=m;++i){
        float v=VT[(m-1)*ld+(i-1)];
        g_VT2[(i-1)]=s_*v;
        VT[(m-1)*ld+(i-1)]=c_*v;
      }
    } else {
      for (int i=1;i<=m;++i) g_VT2[(i-1)]=VT[(nlp1-1)*ld+(i-1)];
    }
    for (int jj=K+1;jj<=n;++jj) d[jj]=g_dsig[jj];
    double rho=0.0;
    for (int jj=1;jj<=K;++jj){ double zz2=(double)g_z[jj]; rho+=zz2*zz2; g_zorig[jj]=g_z[jj]; }
    g_rho_=rho;
  }
  __syncthreads();
  for (int t=tid;t<(n-K)*m;t+=nth){
    int jj=K+1+t/m, cc=t%m;
    VT[(jj-1)*ld+cc]=g_VT2[(jj-1)*LDV+cc];
  }
  __syncthreads();
  if (K==1){
    if (tid==0){
      d[1]=fabsf(g_z[1]);
      for (int cc=0;cc<m;++cc) VT[cc]=g_VT2[cc];
      slamrg(1,n-1,d,1,-1,idxq);
    }
    __syncthreads();
    return;
  }
  {
    double rho=g_rho_;
    for (int i=1+tid;i<=K;i+=nth){
      double di=(double)g_dsig[i];
      double lo=di*di, hi;
      if (i<K){ double dn=(double)g_dsig[i+1]; hi=dn*dn; }
      else { double dn=(double)g_dsig[K]; hi=dn*dn+rho; }
      for (int it=0;it<110;++it){
        double mid=0.5*(lo+hi);
        double f=1.0;
        for (int j=1;j<=K;++j){
          double dj=(double)g_dsig[j];
          double zj=(double)g_z[j];
          f+=zj*zj/(dj*dj-mid);
        }
        if (f>=0.0) hi=mid; else lo=mid;
      }
      g_root[i]=0.5*(lo+hi);
      d[i]=(float)sqrt(g_root[i]);
    }
  }
  __syncthreads();
  for (int i=1+tid;i<=K;i+=nth){
    double di=(double)g_dsig[i], di2=di*di;
    double p=di2-g_root[K];
    for (int j=1;j<=i-1;++j){
      double dj=(double)g_dsig[j];
      p*=(di2-g_root[j])/((di-dj)*(di+dj));
    }
    for (int j=i;j<=K-1;++j){
      double dj1=(double)g_dsig[j+1];
      p*=(di2-g_root[j])/((di-dj1)*(di+dj1));
    }
    g_ztmp[i]=copysignf((float)sqrt(fabs(p)),g_zorig[i]);
  }
  __syncthreads();
  for (int i=1+tid;i<=K;i+=nth) g_z[i]=g_ztmp[i];
  __syncthreads();
  for (int i=1+tid;i<=K;i+=nth){
    double xi=g_root[i];
    double nrm=0.0;
    for (int j=1;j<=K;++j){
      double dj=(double)g_dsig[j];
      double w=(double)g_z[j]/(dj*dj-xi);
      g_W[(i-1)*LDV+(j-1)]=(float)w;
      nrm+=w*w;
    }
    float inv=(float)(1.0/sqrt(nrm));
    for (int j=1;j<=K;++j) g_W[(i-1)*LDV+(j-1)]*=inv;
  }
  __syncthreads();
  for (int t=tid;t<K*m;t+=nth){
    int i=1+t/m, cc=t%m;
    float acc=0.f;
    for (int j=1;j<=K;++j)
      acc=fmaf(g_W[(i-1)*LDV+(j-1)],g_VT2[(j-1)*LDV+cc],acc);
    VT[(i-1)*ld+cc]=acc;
  }
  __syncthreads();
  if (tid==0) slamrg(K,n-K,d,1,-1,idxq);
  __syncthreads();
}

// ---------------- sbdsdc driver kernel (round-2 verbatim) ----------------
__global__ __launch_bounds__(1024) void k_sbdsdc(int n){
  const int tid=threadIdx.x, lane=tid&63, wv=tid>>6;
  for (int t=tid;t<n*n;t+=1024)
    g_VTr[(t/n)*LDV+(t%n)]=((t/n)==(t%n))?1.f:0.f;
  __syncthreads();
  if (n<=25){
    if (tid==0){
      slasdq_u(0,n,n,g_d,g_e,g_VTr,LDV);
      for (int j=1;j<=n;++j) g_idxq[j]=j;
    }
    __syncthreads();
  } else {
    if (tid==0){
      int lvl,nd;
      slasdt(n,&lvl,&nd,g_inode,g_ndiml,g_ndimr,25);
      g_nlvl_=lvl; g_nd_=nd;
    }
    __syncthreads();
    int nd=g_nd_, nlvl=g_nlvl_;
    int ndb1=(nd+1)/2;
    int ntask=(nd-ndb1+1)*2;
    for (int task=wv;task<ntask;task+=16){
      if (lane==0){
        int node=ndb1+(task>>1);
        int ic=g_inode[node], nl=g_ndiml[node], nr=g_ndimr[node];
        if ((task&1)==0){
          int nlf=ic-nl;
          slasdq_u(1,nl,nl+1,g_d+(nlf-1),g_e+(nlf-1),&g_VTr[(nlf-1)*LDV+(nlf-1)],LDV);
          for (int j2=1;j2<=nl;++j2) g_idxq[nlf-1+j2]=j2;
        } else {
          int nrf=ic+1;
          int sq=(node==nd)?0:1;
          slasdq_u(sq,nr,nr+sq,g_d+(nrf-1),g_e+(nrf-1),&g_VTr[(nrf-1)*LDV+(nrf-1)],LDV);
          for (int j2=1;j2<=nr;++j2) g_idxq[nrf-1+j2]=j2;
        }
      }
    }
    __syncthreads();
    for (int lvl=nlvl;lvl>=1;--lvl){
      int lf=(lvl==1)?1:(1<<(lvl-1));
      int llast=(lvl==1)?1:(2*lf-1);
      for (int node=lf;node<=llast;++node){
        int ic=g_inode[node], nl=g_ndiml[node], nr=g_ndimr[node];
        int nlf=ic-nl;
        int sq=(node==llast)?0:1;
        float alpha=g_d[ic], beta=g_e[ic];
        merge_node(nl,nr,sq,g_d+(nlf-1),g_idxq+(nlf-1),alpha,beta,
                   &g_VTr[(nlf-1)*LDV+(nlf-1)],LDV);
      }
    }
  }
  __syncthreads();
  for (int t=tid;t<n*512;t+=1024){
    int i=t/512, c=t%512;
    int o=g_idxq[n-i];
    float v=(c<n)?g_VTr[(o-1)*LDV+c]:0.f;
    g_VTc[i*512+c]=make_float2(v,0.f);
    if (c==0) g_sig[i]=g_d[o];
  }
}

// ---------------- small-site single-block kernels (round-2 verbatim) ----------------
__global__ void k_m0(const float* __restrict__ tf){
  int i=blockIdx.x*blockDim.x+threadIdx.x;
  if (i<1024) g_A[i]=make_float2(tf[2*i],tf[2*i+1]);
}

__global__ __launch_bounds__(1024) void k_lq(int m){
  const int n=512;
  const int tid=threadIdx.x, lane=tid&63, wv=tid>>6;
  __shared__ float s_part[16];
  __shared__ cplx s_tau, s_scal;
  __shared__ float s_beta; __shared__ int s_skip;
  for (int i=1;i<=m;++i){
    for (int c=i+tid;c<=n;c+=1024) g_A[(i-1)*512+(c-1)].y=-g_A[(i-1)*512+(c-1)].y;
    __syncthreads();
    float sq=0.f;
    for (int c=i+1+tid;c<=n;c+=1024){
      cplx a=g_A[(i-1)*512+(c-1)];
      sq=fmaf(a.x,a.x,fmaf(a.y,a.y,sq));
    }
    sq=wred(sq);
    if (lane==0) s_part[wv]=sq;
    __syncthreads();
    if (tid==0){
      float xn2=0.f; for (int w=0;w<16;w++) xn2+=s_part[w];
      RfgOut o=clarfg_head(g_A[(i-1)*512+(i-1)],xn2);
      s_beta=o.beta; s_tau=o.tau; s_scal=o.scal; s_skip=o.skip;
      g_tauf[i]=o.tau;
    }
    __syncthreads();
    if (!s_skip){
      for (int c=i+1+tid;c<=n;c+=1024)
        g_A[(i-1)*512+(c-1)]=cmul(g_A[(i-1)*512+(c-1)],s_scal);
    }
    __syncthreads();
    if (!s_skip){
      cplx tau=s_tau;
      for (int r=i+1+wv;r<=m;r+=16){
        cplx acc=make_float2(0.f,0.f);
        for (int c=i+lane;c<=n;c+=64){
          cplx u=(c==i)?make_float2(1.f,0.f):g_A[(i-1)*512+(c-1)];
          acc=cadd(acc,cmul(g_A[(r-1)*512+(c-1)],u));
        }
        acc.x=wred(acc.x); acc.y=wred(acc.y);
        acc.x=__shfl(acc.x,0); acc.y=__shfl(acc.y,0);
        cplx tw=cmul(tau,acc);
        for (int c=i+lane;c<=n;c+=64){
          cplx u=(c==i)?make_float2(1.f,0.f):g_A[(i-1)*512+(c-1)];
          g_A[(r-1)*512+(c-1)]=csub(g_A[(r-1)*512+(c-1)],cmul(tw,conjc(u)));
        }
      }
    }
    __syncthreads();
    if (tid==0) g_A[(i-1)*512+(i-1)]=make_float2(s_beta,0.f);
    __syncthreads();
  }
}

__global__ void k_copyL(int m){
  int t=blockIdx.x*blockDim.x+threadIdx.x;
  if (t>=m*m) return;
  int r=t/m, c=t%m;
  g_B[r*512+c]=(c<=r)?g_A[r*512+c]:make_float2(0.f,0.f);
}
__global__ void k_copyM(){
  int t=blockIdx.x*blockDim.x+threadIdx.x;
  if (t<512*512) g_B[t]=g_A[t];
}
__global__ void k_copyR_b(){
  int t=blockIdx.x*blockDim.x+threadIdx.x;
  if (t>=512*512) return;
  int r=t/512, c=t%512;
  g_B[t]=(c>r)?g_A[t]:((c==r)?make_float2(g_betaq[r+1],0.f):make_float2(0.f,0.f));
}

__global__ __launch_bounds__(1024) void k_bd(int n){
  const int tid=threadIdx.x, lane=tid&63, wv=tid>>6;
  __shared__ float s_part[16];
  __shared__ cplx s_tau, s_scal;
  __shared__ float s_beta; __shared__ int s_skip;
  for (int i=1;i<=n;++i){
    float sq=0.f;
    for (int r=i+1+tid;r<=n;r+=1024){
      cplx a=g_B[(r-1)*512+(i-1)];
      sq=fmaf(a.x,a.x,fmaf(a.y,a.y,sq));
    }
    sq=wred(sq);
    if (lane==0) s_part[wv]=sq;
    __syncthreads();
    if (tid==0){
      float xn2=0.f; for (int w=0;w<16;w++) xn2+=s_part[w];
      RfgOut o=clarfg_head(g_B[(i-1)*512+(i-1)],xn2);
      s_beta=o.beta; s_tau=o.tau; s_scal=o.scal; s_skip=o.skip;
      g_d[i]=o.beta;
    }
    __syncthreads();
    if (!s_skip){
      for (int r=i+1+tid;r<=n;r+=1024)
        g_B[(r-1)*512+(i-1)]=cmul(g_B[(r-1)*512+(i-1)],s_scal);
    }
    __syncthreads();
    if (!s_skip){
      cplx tauc=conjc(s_tau);
      for (int c=i+1+wv;c<=n;c+=16){
        cplx acc=make_float2(0.f,0.f);
        for (int r=i+lane;r<=n;r+=64){
          cplx v=(r==i)?make_float2(1.f,0.f):g_B[(r-1)*512+(i-1)];
          acc=cadd(acc,cmulc(v,g_B[(r-1)*512+(c-1)]));
        }
        acc.x=wred(acc.x); acc.y=wred(acc.y);
        acc.x=__shfl(acc.x,0); acc.y=__shfl(acc.y,0);
        cplx tw=cmul(tauc,acc);
        for (int r=i+lane;r<=n;r+=64){
          cplx v=(r==i)?make_float2(1.f,0.f):g_B[(r-1)*512+(i-1)];
          g_B[(r-1)*512+(c-1)]=csub(g_B[(r-1)*512+(c-1)],cmul(tw,v));
        }
      }
    }
    __syncthreads();
    if (tid==0) g_B[(i-1)*512+(i-1)]=make_float2(s_beta,0.f);
    __syncthreads();
    if (i<n){
      for (int c=i+1+tid;c<=n;c+=1024) g_B[(i-1)*512+(c-1)].y=-g_B[(i-1)*512+(c-1)].y;
      __syncthreads();
      float sq2=0.f;
      for (int c=i+2+tid;c<=n;c+=1024){
        cplx a=g_B[(i-1)*512+(c-1)];
        sq2=fmaf(a.x,a.x,fmaf(a.y,a.y,sq2));
      }
      sq2=wred(sq2);
      if (lane==0) s_part[wv]=sq2;
      __syncthreads();
      if (tid==0){
        float xn2=0.f; for (int w=0;w<16;w++) xn2+=s_part[w];
        RfgOut o=clarfg_head(g_B[(i-1)*512+(i)],xn2);
        s_beta=o.beta; s_tau=o.tau; s_scal=o.scal; s_skip=o.skip;
        g_e[i]=o.beta; g_taup[i]=o.tau;
      }
      __syncthreads();
      if (!s_skip){
        for (int c=i+2+tid;c<=n;c+=1024)
          g_B[(i-1)*512+(c-1)]=cmul(g_B[(i-1)*512+(c-1)],s_scal);
      }
      __syncthreads();
      if (!s_skip){
        cplx tau=s_tau;
        for (int r=i+1+wv;r<=n;r+=16){
          cplx acc=make_float2(0.f,0.f);
          for (int c=i+1+lane;c<=n;c+=64){
            cplx v=(c==i+1)?make_float2(1.f,0.f):g_B[(i-1)*512+(c-1)];
            acc=cadd(acc,cmul(g_B[(r-1)*512+(c-1)],v));
          }
          acc.x=wred(acc.x); acc.y=wred(acc.y);
          acc.x=__shfl(acc.x,0); acc.y=__shfl(acc.y,0);
          cplx tw=cmul(tau,acc);
          for (int c=i+1+lane;c<=n;c+=64){
            cplx v=(c==i+1)?make_float2(1.f,0.f):g_B[(i-1)*512+(c-1)];
            g_B[(r-1)*512+(c-1)]=csub(g_B[(r-1)*512+(c-1)],cmul(tw,conjc(v)));
          }
        }
      }
      __syncthreads();
      for (int c=i+2+tid;c<=n;c+=1024) g_B[(i-1)*512+(c-1)].y=-g_B[(i-1)*512+(c-1)].y;
      if (tid==0) g_B[(i-1)*512+(i)]=make_float2(s_beta,0.f);
      __syncthreads();
    }
  }
}

__global__ __launch_bounds__(1024) void k_applyPH(int n){
  const int tid=threadIdx.x, lane=tid&63, wv=tid>>6;
  for (int i=n-1;i>=1;--i){
    cplx tau=g_taup[i];
    if (tau.x==0.f && tau.y==0.f) continue;
    cplx tauc=conjc(tau);
    for (int r=1+wv;r<=n;r+=16){
      cplx acc=make_float2(0.f,0.f);
      for (int c=i+1+lane;c<=n;c+=64){
        cplx v=(c==i+1)?make_float2(1.f,0.f):conjc(g_B[(i-1)*512+(c-1)]);
        acc=cadd(acc,cmul(g_VTc[(r-1)*512+(c-1)],v));
      }
      acc.x=wred(acc.x); acc.y=wred(acc.y);
      acc.x=__shfl(acc.x,0); acc.y=__shfl(acc.y,0);
      cplx tw=cmul(tauc,acc);
      for (int c=i+1+lane;c<=n;c+=64){
        cplx vb=(c==i+1)?make_float2(1.f,0.f):g_B[(i-1)*512+(c-1)];
        g_VTc[(r-1)*512+(c-1)]=csub(g_VTc[(r-1)*512+(c-1)],cmul(tw,vb));
      }
    }
    __syncthreads();
  }
}

__global__ __launch_bounds__(1024) void k_applyQlq(int m){
  const int tid=threadIdx.x, lane=tid&63, wv=tid>>6;
  for (int i=m;i>=1;--i){
    cplx tau=g_tauf[i];
    if (tau.x==0.f && tau.y==0.f) continue;
    cplx tauc=conjc(tau);
    for (int r=1+wv;r<=m;r+=16){
      cplx acc=make_float2(0.f,0.f);
      for (int c=i+lane;c<=512;c+=64){
        cplx u=(c==i)?make_float2(1.f,0.f):g_A[(i-1)*512+(c-1)];
        acc=cadd(acc,cmul(g_VTc[(r-1)*512+(c-1)],u));
      }
      acc.x=wred(acc.x); acc.y=wred(acc.y);
      acc.x=__shfl(acc.x,0); acc.y=__shfl(acc.y,0);
      cplx tw=cmul(tauc,acc);
      for (int c=i+lane;c<=512;c+=64){
        cplx u=(c==i)?make_float2(1.f,0.f):g_A[(i-1)*512+(c-1)];
        g_VTc[(r-1)*512+(c-1)]=csub(g_VTc[(r-1)*512+(c-1)],cmul(tw,conjc(u)));
      }
    }
    __syncthreads();
  }
}

// ---------------- persistent big-site kernels (R6 phase bodies + gbar) ----------------

// cgeqr2 on g_A (1024 x 512), all 512 reflectors in one launch.
__global__ __launch_bounds__(256) void pk_qr(){
  const int m=1024, n=512;
  const int gtid=blockIdx.x*256+threadIdx.x;
  const int lane=gtid&63, gw=gtid>>6;
  { // prologue: col-1 tail norm (redundant per block; block 0 writes)
    __shared__ float sr[256];
    int t=threadIdx.x;
    float sq=0.f;
    for (int r=2+t;r<=1024;r+=256){ cplx a=g_A[(r-1)*512]; sq=fmaf(a.x,a.x,fmaf(a.y,a.y,sq)); }
    sr[t]=sq; __syncthreads();
    for (int s=128;s>0;s>>=1){ if (t<s) sr[t]+=sr[t+s]; __syncthreads(); }
    if (gtid==0) g_scq[1]=sr[0];
  }
  gbar();
  for (int j=1;j<=n;++j){
    float xn2=g_scq[j];
    cplx alpha=g_A[(j-1)*512+(j-1)];
    RfgOut o=clarfg_head(alpha,xn2);
    if (gtid==0) g_betaq[j]=o.beta;
    cplx tauc=conjc(o.tau);
    float nsq=0.f;
    for (int c=j+1+gw;c<=n;c+=UW){
      cplx acc=make_float2(0.f,0.f);
      for (int r=j+lane;r<=m;r+=64){
        cplx v=(r==j)?make_float2(1.f,0.f):cmul(g_A[(r-1)*512+(j-1)],o.scal);
        acc=cadd(acc,cmulc(v,g_A[(r-1)*512+(c-1)]));
      }
      acc.x=wred(acc.x); acc.y=wred(acc.y);
      acc.x=__shfl(acc.x,0); acc.y=__shfl(acc.y,0);
      cplx tw=cmul(tauc,acc);
      for (int r=j+lane;r<=m;r+=64){
        cplx v=(r==j)?make_float2(1.f,0.f):cmul(g_A[(r-1)*512+(j-1)],o.scal);
        cplx nv=csub(g_A[(r-1)*512+(c-1)],cmul(tw,v));
        g_A[(r-1)*512+(c-1)]=nv;
        if (c==j+1 && r>=j+2) nsq=fmaf(nv.x,nv.x,fmaf(nv.y,nv.y,nsq));
      }
    }
    if (gw==0){
      nsq=wred(nsq);
      if (lane==0) g_scq[j+1]=nsq;
    }
    gbar();
  }
}

// cgebd2 on g_B (512 x 512), all 1023 phases in one launch.
__global__ __launch_bounds__(256) void pk_bd(){
  const int n=512;
  const int gtid=blockIdx.x*256+threadIdx.x;
  const int lane=gtid&63, gw=gtid>>6;
  // prologue: col-1 tail norm partials (512 threads worth -> blocks 0,1)
  if (blockIdx.x<2){
    int t=gtid;
    float sq=0.f;
    for (int r=2+t;r<=512;r+=512){ cplx a=g_B[(r-1)*512]; sq=fmaf(a.x,a.x,fmaf(a.y,a.y,sq)); }
    g_partR[t]=sq;
  }
  gbar();
  for (int i=1;i<=n;++i){
    { // ---- column phase (u_bd_col body) ----
      float xn2c=reduce512(g_partR);
      cplx alpha=g_B[(i-1)*512+(i-1)];
      RfgOut oc=clarfg_head(alpha,xn2c);
      if (gtid==0) g_d[i]=oc.beta;
      cplx tauc=conjc(oc.tau);
      float nsqA=0.f;
      for (int c=i+1+gw;c<=n;c+=UW){
        cplx acc=make_float2(0.f,0.f);
        for (int r=i+lane;r<=n;r+=64){
          cplx v=(r==i)?make_float2(1.f,0.f):cmul(g_B[(r-1)*512+(i-1)],oc.scal);
          acc=cadd(acc,cmulc(v,g_B[(r-1)*512+(c-1)]));
        }
        acc.x=wred(acc.x); acc.y=wred(acc.y);
        acc.x=__shfl(acc.x,0); acc.y=__shfl(acc.y,0);
        cplx tw=cmul(tauc,acc);
        for (int r=i+lane;r<=n;r+=64){
          cplx v=(r==i)?make_float2(1.f,0.f):cmul(g_B[(r-1)*512+(i-1)],oc.scal);
          cplx nv=csub(g_B[(r-1)*512+(c-1)],cmul(tw,v));
          g_B[(r-1)*512+(c-1)]=nv;
          if (r==i && c>=i+2) nsqA=fmaf(nv.x,nv.x,fmaf(nv.y,nv.y,nsqA));
        }
      }
      if (lane==0) g_partC[gw]=nsqA;
    }
    gbar();
    if (i==n) break;
    { // ---- row phase (u_bd_row body) ----
      float xn2r=reduce512(g_partC);
      cplx alphar=conjc(g_B[(i-1)*512+(i)]);
      RfgOut orr=clarfg_head(alphar,xn2r);
      if (gtid==0){ g_e[i]=orr.beta; g_taup[i]=orr.tau; g_rn[i]=xn2r; }
      float nsqB=0.f;
      for (int r=i+1+gw;r<=n;r+=UW){
        cplx acc=make_float2(0.f,0.f);
        for (int c=i+1+lane;c<=n;c+=64){
          cplx v=(c==i+1)?make_float2(1.f,0.f):cmul(conjc(g_B[(i-1)*512+(c-1)]),orr.scal);
          acc=cadd(acc,cmul(g_B[(r-1)*512+(c-1)],v));
        }
        acc.x=wred(acc.x); acc.y=wred(acc.y);
        acc.x=__shfl(acc.x,0); acc.y=__shfl(acc.y,0);
        cplx tw=cmul(orr.tau,acc);
        for (int c=i+1+lane;c<=n;c+=64){
          cplx v=(c==i+1)?make_float2(1.f,0.f):cmul(conjc(g_B[(i-1)*512+(c-1)]),orr.scal);
          cplx nv=csub(g_B[(r-1)*512+(c-1)],cmul(tw,conjc(v)));
          g_B[(r-1)*512+(c-1)]=nv;
          if (c==i+1 && r>=i+2) nsqB=fmaf(nv.x,nv.x,fmaf(nv.y,nv.y,nsqB));
        }
      }
      if (lane==0) g_partR[gw]=nsqB;
    }
    gbar();
  }
}

// big-site P^H chain: VTc (512x512) <- VTc * prod_{i=511..1} G_i^H.
// 128 blocks x 4 waves, one VTc row per wave.
__global__ __launch_bounds__(256) void u_ph(){
  const int n=512;
  int b=blockIdx.x;
  int wv=threadIdx.x>>6, lane=threadIdx.x&63;
  int r=b*4+wv+1;   // 1-based row, 512 rows over 512 waves
  for (int i=n-1;i>=1;--i){
    cplx alphar=conjc(g_B[(i-1)*512+(i)]);
    RfgOut o=clarfg_head(alphar,g_rn[i]);
    if (o.skip) continue;
    cplx tauc=conjc(o.tau);
    cplx acc=make_float2(0.f,0.f);
    for (int c=i+1+lane;c<=n;c+=64){
      cplx v=(c==i+1)?make_float2(1.f,0.f):cmul(conjc(g_B[(i-1)*512+(c-1)]),o.scal);
      acc=cadd(acc,cmul(g_VTc[(r-1)*512+(c-1)],v));
    }
    acc.x=wred(acc.x); acc.y=wred(acc.y);
    acc.x=__shfl(acc.x,0); acc.y=__shfl(acc.y,0);
    cplx tw=cmul(tauc,acc);
    for (int c=i+1+lane;c<=n;c+=64){
      cplx v=(c==i+1)?make_float2(1.f,0.f):cmul(conjc(g_B[(i-1)*512+(c-1)]),o.scal);
      g_VTc[(r-1)*512+(c-1)]=csub(g_VTc[(r-1)*512+(c-1)],cmul(tw,conjc(v)));
    }
  }
}

// ---------------- glue kernels ----------------
__global__ void k_formR(int kk){
  int t=blockIdx.x*blockDim.x+threadIdx.x;
  if (t>=kk*512) return;
  float s=g_sig[t/512];
  cplx v=g_VTc[t];
  g_R[t]=make_float2(s*v.x,s*v.y);
}

__global__ void k_next(const float* __restrict__ tmid, int site){
  int row=blockIdx.x;
  int a=row>>1, s=row&1;
  int b=blockIdx.y*blockDim.x+threadIdx.x;
  const float* base=tmid+(size_t)site*512*2*512*2;
  cplx acc=make_float2(0.f,0.f);
  for (int c=0;c<512;++c){
    cplx r=g_R[a*512+c];
    size_t off=((((size_t)c)*2+s)*512+b)*2;
    cplx x=make_float2(base[off],base[off+1]);
    acc=cadd(acc,cmul(r,x));
  }
  g_A[row*512+b]=acc;
}

__global__ void k_final(const float* __restrict__ tlast, float* __restrict__ out){
  int a=blockIdx.x*blockDim.x+threadIdx.x;
  if (a>=512) return;
  for (int s=0;s<2;++s){
    cplx acc=make_float2(0.f,0.f);
    for (int c=0;c<512;++c){
      cplx r=g_R[a*512+c];
      cplx x=make_float2(tlast[(c*2+s)*2],tlast[(c*2+s)*2+1]);
      acc=cadd(acc,cmul(r,x));
    }
    out[a*4+s*2+0]=acc.x;
    out[a*4+s*2+1]=acc.y;
  }
}

extern "C" void kernel_launch(void* const* d_in, const int* in_sizes, int n_in,
                              void* d_out, int out_size, void* d_ws, size_t ws_size,
                              hipStream_t stream) {
  const float* t_first=(const float*)d_in[0];
  const float* t_mid  =(const float*)d_in[1];
  const float* t_last =(const float*)d_in[2];
  float* out=(float*)d_out;
  (void)in_sizes; (void)n_in; (void)d_ws; (void)ws_size; (void)out_size;

  k_m0<<<dim3(4),256,0,stream>>>(t_first);

  int rows=2;
  for (int site=0;site<23;++site){
    int mm=rows;
    int nb=(mm<512)?mm:512;
    if (mm<512){
      // small sites: round-2 verified single-block path
      k_lq<<<1,1024,0,stream>>>(mm);
      k_copyL<<<dim3((mm*mm+255)/256),256,0,stream>>>(mm);
      k_bd<<<1,1024,0,stream>>>(mm);
      k_sbdsdc<<<1,1024,0,stream>>>(mm);
      k_applyPH<<<1,1024,0,stream>>>(mm);
      k_applyQlq<<<1,1024,0,stream>>>(mm);
    } else {
      if (mm==512){
        k_copyM<<<dim3((512*512+255)/256),256,0,stream>>>();
      } else {
        pk_qr<<<UBLK,256,0,stream>>>();
        k_copyR_b<<<dim3((512*512+255)/256),256,0,stream>>>();
      }
      pk_bd<<<UBLK,256,0,stream>>>();
      k_sbdsdc<<<1,1024,0,stream>>>(512);
      u_ph<<<UBLK,256,0,stream>>>();
    }
    k_formR<<<dim3((nb*512+255)/256),256,0,stream>>>(nb);
    if (site<22){
      k_next<<<dim3(2*nb,2),256,0,stream>>>(t_mid,site);
      rows=2*nb;
    } else {
      k_final<<<dim3(2),256,0,stream>>>(t_last,out);
    }
  }
}

// Round 8
// 1566719.629 us; speedup vs baseline: 1.0004x; 1.0004x over previous
//
#include <hip/hip_runtime.h>
#include <math.h>

// MPS center-orthogonalization sweep (CHI=512, Q=2, NQUBIT=24, complex64).
// Faithful GPU port of the Vh/S side of LAPACK cgesdd (jobz='S') over 23
// sites.  Round 7: R6's per-reflector dispatch chains (22.7k launches, ~43us
// fixed cost each = ~0.97s) are replaced by PERSISTENT kernels (pk_qr, pk_bd)
// with a hand-rolled device-scope barrier between phases.  Phase bodies are
// byte-identical to R6's verified u_qr / u_bd_col / u_bd_row.  128 blocks x
// 256 thr (<=256 CUs) guarantees co-residency; spin uses s_sleep + bail-out
// flag (degrades to wrong answer, never hangs).  Small sites, sbdsdc, u_ph,
// glue: R6 verbatim.

#define LDV 513
typedef float2 cplx;

__device__ __forceinline__ cplx cmul(cplx a, cplx b){ return make_float2(a.x*b.x - a.y*b.y, a.x*b.y + a.y*b.x); }
__device__ __forceinline__ cplx cmulc(cplx a, cplx b){ /*conj(a)*b*/ return make_float2(a.x*b.x + a.y*b.y, a.x*b.y - a.y*b.x); }
__device__ __forceinline__ cplx cadd(cplx a, cplx b){ return make_float2(a.x+b.x, a.y+b.y); }
__device__ __forceinline__ cplx csub(cplx a, cplx b){ return make_float2(a.x-b.x, a.y-b.y); }
__device__ __forceinline__ cplx conjc(cplx a){ return make_float2(a.x, -a.y); }

#define EPS_S 5.9604645e-8f
#define UNFL_S 1.17549435e-38f
#define UW 512    // waves in persistent update grid (128 blocks x 256 thr)
#define UBLK 128  // blocks for persistent/hot kernels

// ---------------- device global workspace ----------------
__device__ cplx g_A[1024*512];     // current M / QR-LQ factors (raw)
__device__ cplx g_B[512*512];      // square matrix for bidiagonalization (raw)
__device__ cplx g_VTc[512*512];    // complex VT being assembled
__device__ cplx g_R[512*512];      // bond matrix R = diag(s)*VT
__device__ cplx g_tauf[520];       // LQ taus (small path)
__device__ cplx g_taup[520];       // cgebd2 row taus
__device__ float g_d[520], g_e[520];
__device__ float g_VTr[LDV*LDV];
__device__ float g_VT2[LDV*LDV];
__device__ float g_W[LDV*LDV];
__device__ float g_z[520], g_zz[520], g_zorig[520], g_dtmp[520], g_ztmp[520], g_dsig[520];
__device__ double g_root[520];
__device__ int g_idxq[520], g_idx[520], g_idxp[520], g_rowmap[520];
__device__ int g_inode[80], g_ndiml[80], g_ndimr[80];
__device__ float g_sig[520];
__device__ int g_K, g_nlvl_, g_nd_;
__device__ float g_tol_, g_z1_;
__device__ double g_rho_;
// big-path chain scalars
__device__ float g_scq[520];       // QR column-tail norms
__device__ float g_betaq[520];     // QR betas (R diagonal)
__device__ float g_rn[520];        // BD row-reflector tail norms (u_ph recompute)
__device__ float g_partC[UW];      // BD col-phase per-wave partials
__device__ float g_partR[UW];      // BD row-phase / prologue partials
// device barrier state
__device__ unsigned g_barc = 0;    // arrival count
__device__ unsigned g_barg = 0;    // generation
__device__ int g_barfail = 0;      // set on spin timeout -> all barriers bail

// ---------------- device-scope sense-reversing barrier ----------------
__device__ __forceinline__ void gbar(){
  __syncthreads();
  if (threadIdx.x==0){
    if (!g_barfail){
      __threadfence();
      unsigned gen=__hip_atomic_load(&g_barg,__ATOMIC_RELAXED,__HIP_MEMORY_SCOPE_AGENT);
      unsigned prev=__hip_atomic_fetch_add(&g_barc,1u,__ATOMIC_ACQ_REL,__HIP_MEMORY_SCOPE_AGENT);
      if (prev+1u==(unsigned)gridDim.x){
        __hip_atomic_store(&g_barc,0u,__ATOMIC_RELAXED,__HIP_MEMORY_SCOPE_AGENT);
        __hip_atomic_store(&g_barg,gen+1u,__ATOMIC_RELEASE,__HIP_MEMORY_SCOPE_AGENT);
      } else {
        long k=0;
        while (__hip_atomic_load(&g_barg,__ATOMIC_ACQUIRE,__HIP_MEMORY_SCOPE_AGENT)==gen){
          __builtin_amdgcn_s_sleep(2);
          if (++k>(1L<<24)){ g_barfail=1; break; }
        }
      }
      __threadfence();
    }
  }
  __syncthreads();
}

// ---------------- reduce helpers ----------------
__device__ __forceinline__ float wred(float v){
  for (int off=32;off;off>>=1) v+=__shfl_down(v,off);
  return v;
}
// deterministic 512-entry reduce done identically in every block (256 thr)
__device__ __forceinline__ float reduce512(const float* arr){
  __shared__ float sr[256];
  sr[threadIdx.x]=arr[threadIdx.x]+arr[threadIdx.x+256];
  __syncthreads();
  for (int s=128;s>0;s>>=1){
    if (threadIdx.x<s) sr[threadIdx.x]+=sr[threadIdx.x+s];
    __syncthreads();
  }
  float v=sr[0];
  __syncthreads();
  return v;
}

// ---------------- clarfg (LAPACK conventions) ----------------
struct RfgOut { float beta; cplx tau; cplx scal; int skip; };
__device__ RfgOut clarfg_head(cplx alpha, float xn2){
  RfgOut o;
  if (xn2==0.f && alpha.y==0.f){
    o.beta=alpha.x; o.tau=make_float2(0.f,0.f); o.scal=make_float2(0.f,0.f); o.skip=1;
  } else {
    float anorm=sqrtf(alpha.x*alpha.x+alpha.y*alpha.y+xn2);
    float beta=(alpha.x>=0.f)?-anorm:anorm;
    o.beta=beta;
    o.tau=make_float2((beta-alpha.x)/beta,-alpha.y/beta);
    cplx dd=make_float2(alpha.x-beta,alpha.y);
    float dn=dd.x*dd.x+dd.y*dd.y;
    o.scal=make_float2(dd.x/dn,-dd.y/dn);
    o.skip=0;
  }
  return o;
}

// ---------------- small serial real-LAPACK helpers (round-2 verbatim) ----------------
__device__ float slapy2(float x, float y){
  float xa=fabsf(x), ya=fabsf(y);
  float w=fmaxf(xa,ya), z=fminf(xa,ya);
  if (z==0.f) return w;
  float q=z/w; return w*sqrtf(1.f+q*q);
}

__device__ void slartg(float f, float g, float* cs, float* sn, float* r){
  if (g==0.f){ *cs=1.f; *sn=0.f; *r=f; }
  else if (f==0.f){ *cs=0.f; *sn=(g>0.f)?1.f:-1.f; *r=fabsf(g); }
  else {
    float f1=fabsf(f);
    float d=sqrtf(f*f+g*g);
    *cs = f1/d;
    *r = (f>0.f)? d : -d;
    *sn = g / *r;
  }
}

__device__ void slas2(float f, float g, float h, float* ssmin, float* ssmax){
  float fa=fabsf(f), ga=fabsf(g), ha=fabsf(h);
  float fhmn=fminf(fa,ha), fhmx=fmaxf(fa,ha);
  if (fhmn==0.f){
    *ssmin=0.f;
    if (fhmx==0.f) *ssmax=ga;
    else { float mx=fmaxf(fhmx,ga), mn=fminf(fhmx,ga); float q=mn/mx; *ssmax=mx*sqrtf(1.f+q*q); }
  } else {
    if (ga < fhmx){
      float as=1.f+fhmn/fhmx, at=(fhmx-fhmn)/fhmx;
      float au=ga/fhmx; au=au*au;
      float c=2.f/(sqrtf(as*as+au)+sqrtf(at*at+au));
      *ssmin=fhmn*c; *ssmax=fhmx/c;
    } else {
      float au=fhmx/ga;
      if (au==0.f){ *ssmin=(fhmn*fhmx)/ga; *ssmax=ga; }
      else {
        float as=1.f+fhmn/fhmx, at=(fhmx-fhmn)/fhmx;
        float c=1.f/(sqrtf(1.f+(as*au)*(as*au))+sqrtf(1.f+(at*au)*(at*au)));
        *ssmin=(fhmn*c)*au; *ssmin=*ssmin+*ssmin;
        *ssmax=ga/(c+c);
      }
    }
  }
}

__device__ void slasv2(float f, float g, float h, float* ssmin, float* ssmax,
                       float* snr, float* csr, float* snl, float* csl){
  float ft=f, fa=fabsf(f), ht=h, ha=fabsf(h);
  int pmax=1;
  bool swap_=(ha>fa);
  if (swap_){ pmax=3; float t=ft; ft=ht; ht=t; t=fa; fa=ha; ha=t; }
  float gt=g, ga=fabsf(g);
  float clt=0.f, crt=0.f, slt=0.f, srt=0.f;
  if (ga==0.f){ *ssmin=ha; *ssmax=fa; clt=1.f; crt=1.f; slt=0.f; srt=0.f; }
  else {
    bool gasmal=true;
    if (ga>fa){
      pmax=2;
      if ((fa/ga) < EPS_S){
        gasmal=false;
        *ssmax=ga;
        if (ha>1.f) *ssmin=fa/(ga/ha); else *ssmin=(fa/ga)*ha;
        clt=1.f; slt=ht/gt; srt=1.f; crt=ft/gt;
      }
    }
    if (gasmal){
      float d=fa-ha;
      float l=(d==fa)?1.f:(d/fa);
      float mm=gt/ft;
      float t=2.f-l;
      float mm2=mm*mm, tt=t*t;
      float s=sqrtf(tt+mm2);
      float r=(l==0.f)?fabsf(mm):sqrtf(l*l+mm2);
      float a=0.5f*(s+r);
      *ssmin=ha/a; *ssmax=fa*a;
      if (mm2==0.f){
        if (l==0.f) t=copysignf(2.f,ft)*copysignf(1.f,gt);
        else t=gt/copysignf(d,ft)+mm/t;
      } else {
        t=(mm/(s+t)+mm/(r+l))*(1.f+a);
      }
      float l2=sqrtf(t*t+4.f);
      crt=2.f/l2; srt=t/l2;
      clt=(crt+srt*mm)/a;
      slt=(ht/ft)*srt/a;
    }
  }
  if (swap_){ *csl=srt; *snl=crt; *csr=slt; *snr=clt; }
  else      { *csl=clt; *snl=slt; *csr=crt; *snr=srt; }
  float tsign=0.f;
  if (pmax==1) tsign=copysignf(1.f,*csr)*copysignf(1.f,*csl)*copysignf(1.f,f);
  if (pmax==2) tsign=copysignf(1.f,*snr)*copysignf(1.f,*csl)*copysignf(1.f,g);
  if (pmax==3) tsign=copysignf(1.f,*snr)*copysignf(1.f,*snl)*copysignf(1.f,h);
  *ssmax=copysignf(*ssmax,tsign);
  *ssmin=copysignf(*ssmin,tsign*copysignf(1.f,f)*copysignf(1.f,h));
}

__device__ void slasr_f(int mrows, int ncols, const float* c1, const float* s1, float* a, int lda){
  for (int j=1;j<=mrows-1;++j){
    float ct=c1[j], st=s1[j];
    if (ct!=1.f || st!=0.f){
      float* rj=&a[(j-1)*lda]; float* rj1=&a[j*lda];
      for (int i=0;i<ncols;++i){
        float tmp=rj1[i];
        rj1[i]=ct*tmp-st*rj[i];
        rj[i]=st*tmp+ct*rj[i];
      }
    }
  }
}
__device__ void slasr_b(int mrows, int ncols, const float* c1, const float* s1, float* a, int lda){
  for (int j=mrows-1;j>=1;--j){
    float ct=c1[j], st=s1[j];
    if (ct!=1.f || st!=0.f){
      float* rj=&a[(j-1)*lda]; float* rj1=&a[j*lda];
      for (int i=0;i<ncols;++i){
        float tmp=rj1[i];
        rj1[i]=ct*tmp-st*rj[i];
        rj[i]=st*tmp+ct*rj[i];
      }
    }
  }
}

// serial SBDSQR('U', n, ncvt, 0, 0) — VT only.
__device__ void sbdsqr_u(int n, int ncvt, float* d, float* e, float* vt, int ldvt){
  const int MAXITR=6;
  if (n==0) return;
  if (n>1){
    int nm1=n-1, nm12=nm1+nm1, nm13=nm12+nm1;
    float wk[112];
    float tolmul=10.f;
    float tol=tolmul*EPS_S;
    float smax=0.f;
    for (int i=1;i<=n;i++) smax=fmaxf(smax,fabsf(d[i]));
    for (int i=1;i<=n-1;i++) smax=fmaxf(smax,fabsf(e[i]));
    float sminl=0.f, thresh;
    {
      float sminoa=fabsf(d[1]);
      if (sminoa!=0.f){
        float mu=sminoa;
        for (int i=2;i<=n;i++){
          mu=fabsf(d[i])*(mu/(mu+fabsf(e[i-1])));
          sminoa=fminf(sminoa,mu);
          if (sminoa==0.f) break;
        }
      }
      sminoa=sminoa/sqrtf((float)n);
      thresh=fmaxf(tol*sminoa,(float)(MAXITR*n*n)*UNFL_S);
    }
    int M=n, iter=0, maxit=MAXITR*n*n;
    int oldll=-1, oldm=-1, idir=0;
    while (1){
      if (M<=1) break;
      if (iter>maxit) break;
      int ll=0; bool split=false;
      smax=fabsf(d[M]);
      for (int lll=1;lll<=M-1;++lll){
        ll=M-lll;
        float abss=fabsf(d[ll]), abse=fabsf(e[ll]);
        if (abse<=thresh){ split=true; break; }
        smax=fmaxf(smax,fmaxf(abss,abse));
      }
      if (!split) ll=0;
      else {
        e[ll]=0.f;
        if (ll==M-1){ M=M-1; continue; }
      }
      ll=ll+1;
      if (ll==M-1){
        float sigmn,sigmx,sinr,cosr,sinl,cosl;
        slasv2(d[M-1],e[M-1],d[M],&sigmn,&sigmx,&sinr,&cosr,&sinl,&cosl);
        d[M-1]=sigmx; e[M-1]=0.f; d[M]=sigmn;
        if (ncvt>0){
          float* x=&vt[(M-2)*ldvt]; float* y=&vt[(M-1)*ldvt];
          for (int c=0;c<ncvt;c++){ float xv=x[c],yv=y[c]; x[c]=cosr*xv+sinr*yv; y[c]=cosr*yv-sinr*xv; }
        }
        M-=2; continue;
      }
      if (ll>oldm || M<oldll) idir=(fabsf(d[ll])>=fabsf(d[M]))?1:2;
      bool conv=false;
      if (idir==1){
        if (fabsf(e[M-1])<=fabsf(tol)*fabsf(d[M])){ e[M-1]=0.f; conv=true; }
        else {
          float mu=fabsf(d[ll]); sminl=mu;
          for (int lll=ll;lll<=M-1;++lll){
            if (fabsf(e[lll])<=tol*mu){ e[lll]=0.f; conv=true; break; }
            mu=fabsf(d[lll+1])*(mu/(mu+fabsf(e[lll])));
            sminl=fminf(sminl,mu);
          }
        }
      } else {
        if (fabsf(e[ll])<=fabsf(tol)*fabsf(d[ll])){ e[ll]=0.f; conv=true; }
        else {
          float mu=fabsf(d[M]); sminl=mu;
          for (int lll=M-1;lll>=ll;--lll){
            if (fabsf(e[lll])<=tol*mu){ e[lll]=0.f; conv=true; break; }
            mu=fabsf(d[lll])*(mu/(mu+fabsf(e[lll])));
            sminl=fminf(sminl,mu);
          }
        }
      }
      if (conv) continue;
      oldll=ll; oldm=M;
      float shift=0.f, rr;
      if ((float)n*tol*(sminl/smax)<=fmaxf(EPS_S,0.01f*tol)) shift=0.f;
      else {
        float sll;
        if (idir==1){ sll=fabsf(d[ll]); slas2(d[M-1],e[M-1],d[M],&shift,&rr); }
        else        { sll=fabsf(d[M]);  slas2(d[ll],e[ll],d[ll+1],&shift,&rr); }
        if (sll>0.f){ float q=shift/sll; if (q*q<EPS_S) shift=0.f; }
      }
      iter += M-ll;
      if (shift==0.f){
        if (idir==1){
          float cs=1.f, oldcs=1.f, sn=0.f, oldsn=0.f;
          for (int i=ll;i<=M-1;++i){
            float c2,r1;
            slartg(d[i]*cs,e[i],&c2,&sn,&r1); cs=c2;
            if (i>ll) e[i-1]=oldsn*r1;
            float oc2;
            slartg(oldcs*r1,d[i+1]*sn,&oc2,&oldsn,&d[i]); oldcs=oc2;
            wk[i-ll+1]=cs; wk[i-ll+1+nm1]=sn;
          }
          float h=d[M]*cs; d[M]=h*oldcs; e[M-1]=h*oldsn;
          if (ncvt>0) slasr_f(M-ll+1,ncvt,wk,wk+nm1,&vt[(ll-1)*ldvt],ldvt);
          if (fabsf(e[M-1])<=thresh) e[M-1]=0.f;
        } else {
          float cs=1.f, oldcs=1.f, sn=0.f, oldsn=0.f;
          for (int i=M;i>=ll+1;--i){
            float c2,r1;
            slartg(d[i]*cs,e[i-1],&c2,&sn,&r1); cs=c2;
            if (i<M) e[i]=oldsn*r1;
            float oc2;
            slartg(oldcs*r1,d[i-1]*sn,&oc2,&oldsn,&d[i]); oldcs=oc2;
            wk[i-ll]=cs; wk[i-ll+nm1]=-sn;
            wk[i-ll+nm12]=oldcs; wk[i-ll+nm13]=-oldsn;
          }
          float h=d[ll]*cs; d[ll]=h*oldcs; e[ll]=h*oldsn;
          if (ncvt>0) slasr_b(M-ll+1,ncvt,wk+nm12,wk+nm13,&vt[(ll-1)*ldvt],ldvt);
          if (fabsf(e[ll])<=thresh) e[ll]=0.f;
        }
      } else {
        if (idir==1){
          float f=(fabsf(d[ll])-shift)*(copysignf(1.f,d[ll])+shift/d[ll]);
          float g=e[ll], cosr,sinr,cosl,sinl,r1;
          for (int i=ll;i<=M-1;++i){
            slartg(f,g,&cosr,&sinr,&r1);
            if (i>ll) e[i-1]=r1;
            f=cosr*d[i]+sinr*e[i];
            e[i]=cosr*e[i]-sinr*d[i];
            g=sinr*d[i+1];
            d[i+1]=cosr*d[i+1];
            slartg(f,g,&cosl,&sinl,&r1);
            d[i]=r1;
            f=cosl*e[i]+sinl*d[i+1];
            d[i+1]=cosl*d[i+1]-sinl*e[i];
            if (i<M-1){ g=sinl*e[i+1]; e[i+1]=cosl*e[i+1]; }
            wk[i-ll+1]=cosr; wk[i-ll+1+nm1]=sinr;
            wk[i-ll+1+nm12]=cosl; wk[i-ll+1+nm13]=sinl;
          }
          e[M-1]=f;
          if (ncvt>0) slasr_f(M-ll+1,ncvt,wk,wk+nm1,&vt[(ll-1)*ldvt],ldvt);
          if (fabsf(e[M-1])<=thresh) e[M-1]=0.f;
        } else {
          float f=(fabsf(d[M])-shift)*(copysignf(1.f,d[M])+shift/d[M]);
          float g=e[M-1], cosr,sinr,cosl,sinl,r1;
          for (int i=M;i>=ll+1;--i){
            slartg(f,g,&cosr,&sinr,&r1);
            if (i<M) e[i]=r1;
            f=cosr*d[i]+sinr*e[i-1];
            e[i-1]=cosr*e[i-1]-sinr*d[i];
            g=sinr*d[i-1];
            d[i-1]=cosr*d[i-1];
            slartg(f,g,&cosl,&sinl,&r1);
            d[i]=r1;
            f=cosl*e[i-1]+sinl*d[i-1];
            d[i-1]=cosl*d[i-1]-sinl*e[i-1];
            if (i>ll+1){ g=sinl*e[i-2]; e[i-2]=cosl*e[i-2]; }
            wk[i-ll]=cosr; wk[i-ll+nm1]=-sinr;
            wk[i-ll+nm12]=cosl; wk[i-ll+nm13]=-sinl;
          }
          e[ll]=f;
          if (fabsf(e[ll])<=thresh) e[ll]=0.f;
          if (ncvt>0) slasr_b(M-ll+1,ncvt,wk+nm12,wk+nm13,&vt[(ll-1)*ldvt],ldvt);
        }
      }
    }
  }
  for (int i=1;i<=n;i++){
    if (d[i]<0.f){
      d[i]=-d[i];
      if (ncvt>0){ float* row=&vt[(i-1)*ldvt]; for (int c=0;c<ncvt;c++) row[c]=-row[c]; }
    }
  }
  for (int i=1;i<=n-1;i++){
    int isub=1; float smin2=d[1];
    for (int j=2;j<=n+1-i;j++){ if (d[j]<=smin2){ isub=j; smin2=d[j]; } }
    if (isub!=n+1-i){
      d[isub]=d[n+1-i]; d[n+1-i]=smin2;
      if (ncvt>0){
        float* a=&vt[(isub-1)*ldvt]; float* b=&vt[(n-i)*ldvt];
        for (int c=0;c<ncvt;c++){ float t=a[c]; a[c]=b[c]; b[c]=t; }
      }
    }
  }
}

__device__ void slasdq_u(int sqre, int n, int ncvt, float* d, float* e, float* vt, int ldvt){
  if (n==0) return;
  float cwk[33], swk[33];
  int np1=n+1;
  if (sqre==1){
    for (int i=1;i<=n-1;i++){
      float cs,sn,r; slartg(d[i],e[i],&cs,&sn,&r);
      d[i]=r; e[i]=sn*d[i+1]; d[i+1]=cs*d[i+1];
      cwk[i]=cs; swk[i]=sn;
    }
    { float cs,sn,r; slartg(d[n],e[n],&cs,&sn,&r);
      d[n]=r; e[n]=0.f; cwk[n]=cs; swk[n]=sn; }
    if (ncvt>0) slasr_f(np1,ncvt,cwk,swk,vt,ldvt);
    for (int i=1;i<=n-1;i++){
      float cs,sn,r; slartg(d[i],e[i],&cs,&sn,&r);
      d[i]=r; e[i]=sn*d[i+1]; d[i+1]=cs*d[i+1];
    }
  }
  sbdsqr_u(n,ncvt,d,e,vt,ldvt);
  for (int i=1;i<=n;i++){
    int isub=i; float smin2=d[i];
    for (int j=i+1;j<=n;j++){ if (d[j]<smin2){ isub=j; smin2=d[j]; } }
    if (isub!=i){
      d[isub]=d[i]; d[i]=smin2;
      if (ncvt>0){
        float* a=&vt[(isub-1)*ldvt]; float* b=&vt[(i-1)*ldvt];
        for (int c=0;c<ncvt;c++){ float t=a[c]; a[c]=b[c]; b[c]=t; }
      }
    }
  }
}

__device__ void slamrg(int n1, int n2, const float* a, int s1, int s2, int* idx){
  int n1sv=n1, n2sv=n2, i=1;
  int ind1=(s1>0)?1:n1;
  int ind2=(s2>0)?(1+n1):(n1+n2);
  while (n1sv>0 && n2sv>0){
    if (a[ind1]<=a[ind2]){ idx[i++]=ind1; ind1+=s1; n1sv--; }
    else { idx[i++]=ind2; ind2+=s2; n2sv--; }
  }
  if (n1sv==0){ for(;n2sv>0;n2sv--){ idx[i++]=ind2; ind2+=s2; } }
  else { for(;n1sv>0;n1sv--){ idx[i++]=ind1; ind1+=s1; } }
}

__device__ void slasdt(int n, int* lvl, int* nd, int* inode, int* ndiml, int* ndimr, int msub){
  int maxn=(n>1)?n:1;
  float temp=logf((float)maxn/(float)(msub+1))/logf(2.f);
  *lvl=(int)temp+1;
  int i=n/2;
  inode[1]=i+1; ndiml[1]=i; ndimr[1]=n-i-1;
  int il=0, ir=1, llst=1;
  for (int nl=1;nl<=*lvl-1;++nl){
    for (int j=0;j<=llst-1;++j){
      il+=2; ir+=2;
      int nc=llst+j;
      ndiml[il]=ndiml[nc]/2;
      ndimr[il]=ndiml[nc]-ndiml[il]-1;
      inode[il]=inode[nc]-ndimr[il]-1;
      ndiml[ir]=ndimr[nc]/2;
      ndimr[ir]=ndimr[nc]-ndiml[ir]-1;
      inode[ir]=inode[nc]+ndiml[ir]+1;
    }
    llst*=2;
  }
  *nd=llst*2-1;
}

// ---------------- block-cooperative slasd1 (round-2 verbatim) ----------------
__device__ void merge_node(int nl, int nr, int sqre, float* d, int* idxq,
                           float alpha, float beta, float* VT, int ld)
{
  const int tid=threadIdx.x, nth=blockDim.x;
  const int n=nl+nr+1, m=n+sqre, nlp1=nl+1, nlp2=nl+2;
  if (tid==0){
    float* z=g_z;
    float z1=alpha*VT[(nlp1-1)*ld+(nlp1-1)];
    z[1]=z1; g_z1_=z1;
    for (int i=nl;i>=1;--i){
      z[i+1]=alpha*VT[(i-1)*ld+(nlp1-1)];
      d[i+1]=d[i];
      idxq[i+1]=idxq[i]+1;
    }
    for (int i=nlp2;i<=m;++i) z[i]=beta*VT[(i-1)*ld+(nlp2-1)];
    d[1]=0.f;
    for (int i=nlp2;i<=n;++i) idxq[i]+=nlp1;
    for (int i=2;i<=n;++i){ g_dtmp[i]=d[idxq[i]]; g_ztmp[i]=z[idxq[i]]; }
    slamrg(nl,nr,g_dtmp+1,1,1,g_idx+1);
    for (int i=2;i<=n;++i){
      int idxi=1+g_idx[i];
      d[i]=g_dtmp[idxi];
      z[i]=g_ztmp[idxi];
    }
    float tol=fmaxf(fabsf(alpha),fabsf(beta));
    tol=8.f*EPS_S*fmaxf(fabsf(d[n]),tol);
    g_tol_=tol;
    int K=1, K2=n+1, jprev=0, j;
    for (j=2;j<=n;++j){
      if (fabsf(z[j])<=tol){
        K2--; g_idxp[K2]=j;
        if (j==n){ jprev=0; break; }
      } else { jprev=j; break; }
    }
    if (jprev>0){
      j=jprev;
      for (;;){
        j++;
        if (j>n) break;
        if (fabsf(z[j])<=tol){ K2--; g_idxp[K2]=j; }
        else {
          if (fabsf(d[j]-d[jprev])<=tol){
            float s_=z[jprev], c_=z[j];
            float tau_=slapy2(c_,s_);
            c_/=tau_; s_=-s_/tau_;
            z[j]=tau_; z[jprev]=0.f;
            int idxjp=idxq[g_idx[jprev]+1];
            int idxj =idxq[g_idx[j]+1];
            if (idxjp<=nlp1) idxjp--;
            if (idxj <=nlp1) idxj--;
            float* xr=&VT[(idxjp-1)*ld];
            float* yr=&VT[(idxj-1)*ld];
            for (int cc=0;cc<m;++cc){
              float xv=xr[cc], yv=yr[cc];
              xr[cc]=c_*xv+s_*yv;
              yr[cc]=c_*yv-s_*xv;
            }
            K2--; g_idxp[K2]=jprev;
            jprev=j;
          } else {
            K++; g_zz[K]=z[jprev]; g_idxp[K]=jprev;
            jprev=j;
          }
        }
      }
      K++; g_zz[K]=z[jprev]; g_idxp[K]=jprev;
    }
    g_K=K;
    for (int jj=2;jj<=n;++jj){
      g_dsig[jj]=d[g_idxp[jj]];
      int rm=idxq[g_idx[g_idxp[jj]]+1];
      if (rm<=nlp1) rm--;
      g_rowmap[jj]=rm;
    }
  }
  __syncthreads();
  int K=g_K;
  for (int t=tid;t<(n-1)*m;t+=nth){
    int jj=2+t/m, cc=t%m;
    g_VT2[(jj-1)*LDV+cc]=VT[(g_rowmap[jj]-1)*ld+cc];
  }
  __syncthreads();
  if (tid==0){
    float tol=g_tol_;
    g_dsig[1]=0.f;
    float hlftol=tol*0.5f;
    if (fabsf(g_dsig[2])<=hlftol) g_dsig[2]=hlftol;
    float z1=g_z1_;
    float c_=1.f, s_=0.f;
    if (m>n){
      float t1=slapy2(z1,g_z[m]);
      if (t1<=tol){ c_=1.f; s_=0.f; g_z[1]=tol; }
      else { g_z[1]=t1; c_=z1/t1; s_=g_z[m]/t1; }
    } else {
      if (fabsf(z1)<=tol) g_z[1]=tol; else g_z[1]=z1;
    }
    for (int jj=2;jj<=K;++jj) g_z[jj]=g_zz[jj];
    if (m>n){
      for (int i=1;i<=nlp1;++i){
        float v=VT[(nlp1-1)*ld+(i-1)];
        VT[(m-1)*ld+(i-1)]=-s_*v;
        g_VT2[(i-1)]=c_*v;
      }
      for (int i=nlp2;i<=m;++i){
        float v=VT[(m-1)*ld+(i-1)];
        g_VT2[(i-1)]=s_*v;
        VT[(m-1)*ld+(i-1)]=c_*v;
      }
    } else {
      for (int i=1;i<=m;++i) g_VT2[(i-1)]=VT[(nlp1-1)*ld+(i-1)];
    }
    for (int jj=K+1;jj<=n;++jj) d[jj]=g_dsig[jj];
    double rho=0.0;
    for (int jj=1;jj<=K;++jj){ double zz2=(double)g_z[jj]; rho+=zz2*zz2; g_zorig[jj]=g_z[jj]; }
    g_rho_=rho;
  }
  __syncthreads();
  for (int t=tid;t<(n-K)*m;t+=nth){
    int jj=K+1+t/m, cc=t%m;
    VT[(jj-1)*ld+cc]=g_VT2[(jj-1)*LDV+cc];
  }
  __syncthreads();
  if (K==1){
    if (tid==0){
      d[1]=fabsf(g_z[1]);
      for (int cc=0;cc<m;++cc) VT[cc]=g_VT2[cc];
      slamrg(1,n-1,d,1,-1,idxq);
    }
    __syncthreads();
    return;
  }
  {
    double rho=g_rho_;
    for (int i=1+tid;i<=K;i+=nth){
      double di=(double)g_dsig[i];
      double lo=di*di, hi;
      if (i<K){ double dn=(double)g_dsig[i+1]; hi=dn*dn; }
      else { double dn=(double)g_dsig[K]; hi=dn*dn+rho; }
      for (int it=0;it<110;++it){
        double mid=0.5*(lo+hi);
        double f=1.0;
        for (int j=1;j<=K;++j){
          double dj=(double)g_dsig[j];
          double zj=(double)g_z[j];
          f+=zj*zj/(dj*dj-mid);
        }
        if (f>=0.0) hi=mid; else lo=mid;
      }
      g_root[i]=0.5*(lo+hi);
      d[i]=(float)sqrt(g_root[i]);
    }
  }
  __syncthreads();
  for (int i=1+tid;i<=K;i+=nth){
    double di=(double)g_dsig[i], di2=di*di;
    double p=di2-g_root[K];
    for (int j=1;j<=i-1;++j){
      double dj=(double)g_dsig[j];
      p*=(di2-g_root[j])/((di-dj)*(di+dj));
    }
    for (int j=i;j<=K-1;++j){
      double dj1=(double)g_dsig[j+1];
      p*=(di2-g_root[j])/((di-dj1)*(di+dj1));
    }
    g_ztmp[i]=copysignf((float)sqrt(fabs(p)),g_zorig[i]);
  }
  __syncthreads();
  for (int i=1+tid;i<=K;i+=nth) g_z[i]=g_ztmp[i];
  __syncthreads();
  for (int i=1+tid;i<=K;i+=nth){
    double xi=g_root[i];
    double nrm=0.0;
    for (int j=1;j<=K;++j){
      double dj=(double)g_dsig[j];
      double w=(double)g_z[j]/(dj*dj-xi);
      g_W[(i-1)*LDV+(j-1)]=(float)w;
      nrm+=w*w;
    }
    float inv=(float)(1.0/sqrt(nrm));
    for (int j=1;j<=K;++j) g_W[(i-1)*LDV+(j-1)]*=inv;
  }
  __syncthreads();
  for (int t=tid;t<K*m;t+=nth){
    int i=1+t/m, cc=t%m;
    float acc=0.f;
    for (int j=1;j<=K;++j)
      acc=fmaf(g_W[(i-1)*LDV+(j-1)],g_VT2[(j-1)*LDV+cc],acc);
    VT[(i-1)*ld+cc]=acc;
  }
  __syncthreads();
  if (tid==0) slamrg(K,n-K,d,1,-1,idxq);
  __syncthreads();
}

// ---------------- sbdsdc driver kernel (round-2 verbatim) ----------------
__global__ __launch_bounds__(1024) void k_sbdsdc(int n){
  const int tid=threadIdx.x, lane=tid&63, wv=tid>>6;
  for (int t=tid;t<n*n;t+=1024)
    g_VTr[(t/n)*LDV+(t%n)]=((t/n)==(t%n))?1.f:0.f;
  __syncthreads();
  if (n<=25){
    if (tid==0){
      slasdq_u(0,n,n,g_d,g_e,g_VTr,LDV);
      for (int j=1;j<=n;++j) g_idxq[j]=j;
    }
    __syncthreads();
  } else {
    if (tid==0){
      int lvl,nd;
      slasdt(n,&lvl,&nd,g_inode,g_ndiml,g_ndimr,25);
      g_nlvl_=lvl; g_nd_=nd;
    }
    __syncthreads();
    int nd=g_nd_, nlvl=g_nlvl_;
    int ndb1=(nd+1)/2;
    int ntask=(nd-ndb1+1)*2;
    for (int task=wv;task<ntask;task+=16){
      if (lane==0){
        int node=ndb1+(task>>1);
        int ic=g_inode[node], nl=g_ndiml[node], nr=g_ndimr[node];
        if ((task&1)==0){
          int nlf=ic-nl;
          slasdq_u(1,nl,nl+1,g_d+(nlf-1),g_e+(nlf-1),&g_VTr[(nlf-1)*LDV+(nlf-1)],LDV);
          for (int j2=1;j2<=nl;++j2) g_idxq[nlf-1+j2]=j2;
        } else {
          int nrf=ic+1;
          int sq=(node==nd)?0:1;
          slasdq_u(sq,nr,nr+sq,g_d+(nrf-1),g_e+(nrf-1),&g_VTr[(nrf-1)*LDV+(nrf-1)],LDV);
          for (int j2=1;j2<=nr;++j2) g_idxq[nrf-1+j2]=j2;
        }
      }
    }
    __syncthreads();
    for (int lvl=nlvl;lvl>=1;--lvl){
      int lf=(lvl==1)?1:(1<<(lvl-1));
      int llast=(lvl==1)?1:(2*lf-1);
      for (int node=lf;node<=llast;++node){
        int ic=g_inode[node], nl=g_ndiml[node], nr=g_ndimr[node];
        int nlf=ic-nl;
        int sq=(node==llast)?0:1;
        float alpha=g_d[ic], beta=g_e[ic];
        merge_node(nl,nr,sq,g_d+(nlf-1),g_idxq+(nlf-1),alpha,beta,
                   &g_VTr[(nlf-1)*LDV+(nlf-1)],LDV);
      }
    }
  }
  __syncthreads();
  for (int t=tid;t<n*512;t+=1024){
    int i=t/512, c=t%512;
    int o=g_idxq[n-i];
    float v=(c<n)?g_VTr[(o-1)*LDV+c]:0.f;
    g_VTc[i*512+c]=make_float2(v,0.f);
    if (c==0) g_sig[i]=g_d[o];
  }
}

// ---------------- small-site single-block kernels (round-2 verbatim) ----------------
__global__ void k_m0(const float* __restrict__ tf){
  int i=blockIdx.x*blockDim.x+threadIdx.x;
  if (i<1024) g_A[i]=make_float2(tf[2*i],tf[2*i+1]);
}

__global__ __launch_bounds__(1024) void k_lq(int m){
  const int n=512;
  const int tid=threadIdx.x, lane=tid&63, wv=tid>>6;
  __shared__ float s_part[16];
  __shared__ cplx s_tau, s_scal;
  __shared__ float s_beta; __shared__ int s_skip;
  for (int i=1;i<=m;++i){
    for (int c=i+tid;c<=n;c+=1024) g_A[(i-1)*512+(c-1)].y=-g_A[(i-1)*512+(c-1)].y;
    __syncthreads();
    float sq=0.f;
    for (int c=i+1+tid;c<=n;c+=1024){
      cplx a=g_A[(i-1)*512+(c-1)];
      sq=fmaf(a.x,a.x,fmaf(a.y,a.y,sq));
    }
    sq=wred(sq);
    if (lane==0) s_part[wv]=sq;
    __syncthreads();
    if (tid==0){
      float xn2=0.f; for (int w=0;w<16;w++) xn2+=s_part[w];
      RfgOut o=clarfg_head(g_A[(i-1)*512+(i-1)],xn2);
      s_beta=o.beta; s_tau=o.tau; s_scal=o.scal; s_skip=o.skip;
      g_tauf[i]=o.tau;
    }
    __syncthreads();
    if (!s_skip){
      for (int c=i+1+tid;c<=n;c+=1024)
        g_A[(i-1)*512+(c-1)]=cmul(g_A[(i-1)*512+(c-1)],s_scal);
    }
    __syncthreads();
    if (!s_skip){
      cplx tau=s_tau;
      for (int r=i+1+wv;r<=m;r+=16){
        cplx acc=make_float2(0.f,0.f);
        for (int c=i+lane;c<=n;c+=64){
          cplx u=(c==i)?make_float2(1.f,0.f):g_A[(i-1)*512+(c-1)];
          acc=cadd(acc,cmul(g_A[(r-1)*512+(c-1)],u));
        }
        acc.x=wred(acc.x); acc.y=wred(acc.y);
        acc.x=__shfl(acc.x,0); acc.y=__shfl(acc.y,0);
        cplx tw=cmul(tau,acc);
        for (int c=i+lane;c<=n;c+=64){
          cplx u=(c==i)?make_float2(1.f,0.f):g_A[(i-1)*512+(c-1)];
          g_A[(r-1)*512+(c-1)]=csub(g_A[(r-1)*512+(c-1)],cmul(tw,conjc(u)));
        }
      }
    }
    __syncthreads();
    if (tid==0) g_A[(i-1)*512+(i-1)]=make_float2(s_beta,0.f);
    __syncthreads();
  }
}

__global__ void k_copyL(int m){
  int t=blockIdx.x*blockDim.x+threadIdx.x;
  if (t>=m*m) return;
  int r=t/m, c=t%m;
  g_B[r*512+c]=(c<=r)?g_A[r*512+c]:make_float2(0.f,0.f);
}
__global__ void k_copyM(){
  int t=blockIdx.x*blockDim.x+threadIdx.x;
  if (t<512*512) g_B[t]=g_A[t];
}
__global__ void k_copyR_b(){
  int t=blockIdx.x*blockDim.x+threadIdx.x;
  if (t>=512*512) return;
  int r=t/512, c=t%512;
  g_B[t]=(c>r)?g_A[t]:((c==r)?make_float2(g_betaq[r+1],0.f):make_float2(0.f,0.f));
}

__global__ __launch_bounds__(1024) void k_bd(int n){
  const int tid=threadIdx.x, lane=tid&63, wv=tid>>6;
  __shared__ float s_part[16];
  __shared__ cplx s_tau, s_scal;
  __shared__ float s_beta; __shared__ int s_skip;
  for (int i=1;i<=n;++i){
    float sq=0.f;
    for (int r=i+1+tid;r<=n;r+=1024){
      cplx a=g_B[(r-1)*512+(i-1)];
      sq=fmaf(a.x,a.x,fmaf(a.y,a.y,sq));
    }
    sq=wred(sq);
    if (lane==0) s_part[wv]=sq;
    __syncthreads();
    if (tid==0){
      float xn2=0.f; for (int w=0;w<16;w++) xn2+=s_part[w];
      RfgOut o=clarfg_head(g_B[(i-1)*512+(i-1)],xn2);
      s_beta=o.beta; s_tau=o.tau; s_scal=o.scal; s_skip=o.skip;
      g_d[i]=o.beta;
    }
    __syncthreads();
    if (!s_skip){
      for (int r=i+1+tid;r<=n;r+=1024)
        g_B[(r-1)*512+(i-1)]=cmul(g_B[(r-1)*512+(i-1)],s_scal);
    }
    __syncthreads();
    if (!s_skip){
      cplx tauc=conjc(s_tau);
      for (int c=i+1+wv;c<=n;c+=16){
        cplx acc=make_float2(0.f,0.f);
        for (int r=i+lane;r<=n;r+=64){
          cplx v=(r==i)?make_float2(1.f,0.f):g_B[(r-1)*512+(i-1)];
          acc=cadd(acc,cmulc(v,g_B[(r-1)*512+(c-1)]));
        }
        acc.x=wred(acc.x); acc.y=wred(acc.y);
        acc.x=__shfl(acc.x,0); acc.y=__shfl(acc.y,0);
        cplx tw=cmul(tauc,acc);
        for (int r=i+lane;r<=n;r+=64){
          cplx v=(r==i)?make_float2(1.f,0.f):g_B[(r-1)*512+(i-1)];
          g_B[(r-1)*512+(c-1)]=csub(g_B[(r-1)*512+(c-1)],cmul(tw,v));
        }
      }
    }
    __syncthreads();
    if (tid==0) g_B[(i-1)*512+(i-1)]=make_float2(s_beta,0.f);
    __syncthreads();
    if (i<n){
      for (int c=i+1+tid;c<=n;c+=1024) g_B[(i-1)*512+(c-1)].y=-g_B[(i-1)*512+(c-1)].y;
      __syncthreads();
      float sq2=0.f;
      for (int c=i+2+tid;c<=n;c+=1024){
        cplx a=g_B[(i-1)*512+(c-1)];
        sq2=fmaf(a.x,a.x,fmaf(a.y,a.y,sq2));
      }
      sq2=wred(sq2);
      if (lane==0) s_part[wv]=sq2;
      __syncthreads();
      if (tid==0){
        float xn2=0.f; for (int w=0;w<16;w++) xn2+=s_part[w];
        RfgOut o=clarfg_head(g_B[(i-1)*512+(i)],xn2);
        s_beta=o.beta; s_tau=o.tau; s_scal=o.scal; s_skip=o.skip;
        g_e[i]=o.beta; g_taup[i]=o.tau;
      }
      __syncthreads();
      if (!s_skip){
        for (int c=i+2+tid;c<=n;c+=1024)
          g_B[(i-1)*512+(c-1)]=cmul(g_B[(i-1)*512+(c-1)],s_scal);
      }
      __syncthreads();
      if (!s_skip){
        cplx tau=s_tau;
        for (int r=i+1+wv;r<=n;r+=16){
          cplx acc=make_float2(0.f,0.f);
          for (int c=i+1+lane;c<=n;c+=64){
            cplx v=(c==i+1)?make_float2(1.f,0.f):g_B[(i-1)*512+(c-1)];
            acc=cadd(acc,cmul(g_B[(r-1)*512+(c-1)],v));
          }
          acc.x=wred(acc.x); acc.y=wred(acc.y);
          acc.x=__shfl(acc.x,0); acc.y=__shfl(acc.y,0);
          cplx tw=cmul(tau,acc);
          for (int c=i+1+lane;c<=n;c+=64){
            cplx v=(c==i+1)?make_float2(1.f,0.f):g_B[(i-1)*512+(c-1)];
            g_B[(r-1)*512+(c-1)]=csub(g_B[(r-1)*512+(c-1)],cmul(tw,conjc(v)));
          }
        }
      }
      __syncthreads();
      for (int c=i+2+tid;c<=n;c+=1024) g_B[(i-1)*512+(c-1)].y=-g_B[(i-1)*512+(c-1)].y;
      if (tid==0) g_B[(i-1)*512+(i)]=make_float2(s_beta,0.f);
      __syncthreads();
    }
  }
}

__global__ __launch_bounds__(1024) void k_applyPH(int n){
  const int tid=threadIdx.x, lane=tid&63, wv=tid>>6;
  for (int i=n-1;i>=1;--i){
    cplx tau=g_taup[i];
    if (tau.x==0.f && tau.y==0.f) continue;
    cplx tauc=conjc(tau);
    for (int r=1+wv;r<=n;r+=16){
      cplx acc=make_float2(0.f,0.f);
      for (int c=i+1+lane;c<=n;c+=64){
        cplx v=(c==i+1)?make_float2(1.f,0.f):conjc(g_B[(i-1)*512+(c-1)]);
        acc=cadd(acc,cmul(g_VTc[(r-1)*512+(c-1)],v));
      }
      acc.x=wred(acc.x); acc.y=wred(acc.y);
      acc.x=__shfl(acc.x,0); acc.y=__shfl(acc.y,0);
      cplx tw=cmul(tauc,acc);
      for (int c=i+1+lane;c<=n;c+=64){
        cplx vb=(c==i+1)?make_float2(1.f,0.f):g_B[(i-1)*512+(c-1)];
        g_VTc[(r-1)*512+(c-1)]=csub(g_VTc[(r-1)*512+(c-1)],cmul(tw,vb));
      }
    }
    __syncthreads();
  }
}

__global__ __launch_bounds__(1024) void k_applyQlq(int m){
  const int tid=threadIdx.x, lane=tid&63, wv=tid>>6;
  for (int i=m;i>=1;--i){
    cplx tau=g_tauf[i];
    if (tau.x==0.f && tau.y==0.f) continue;
    cplx tauc=conjc(tau);
    for (int r=1+wv;r<=m;r+=16){
      cplx acc=make_float2(0.f,0.f);
      for (int c=i+lane;c<=512;c+=64){
        cplx u=(c==i)?make_float2(1.f,0.f):g_A[(i-1)*512+(c-1)];
        acc=cadd(acc,cmul(g_VTc[(r-1)*512+(c-1)],u));
      }
      acc.x=wred(acc.x); acc.y=wred(acc.y);
      acc.x=__shfl(acc.x,0); acc.y=__shfl(acc.y,0);
      cplx tw=cmul(tauc,acc);
      for (int c=i+lane;c<=512;c+=64){
        cplx u=(c==i)?make_float2(1.f,0.f):g_A[(i-1)*512+(c-1)];
        g_VTc[(r-1)*512+(c-1)]=csub(g_VTc[(r-1)*512+(c-1)],cmul(tw,conjc(u)));
      }
    }
    __syncthreads();
  }
}

// ---------------- persistent big-site kernels (R6 phase bodies + gbar) ----------------

// cgeqr2 on g_A (1024 x 512), all 512 reflectors in one launch.
__global__ __launch_bounds__(256) void pk_qr(){
  const int m=1024, n=512;
  const int gtid=blockIdx.x*256+threadIdx.x;
  const int lane=gtid&63, gw=gtid>>6;
  { // prologue: col-1 tail norm (redundant per block; block 0 writes)
    __shared__ float sr[256];
    int t=threadIdx.x;
    float sq=0.f;
    for (int r=2+t;r<=1024;r+=256){ cplx a=g_A[(r-1)*512]; sq=fmaf(a.x,a.x,fmaf(a.y,a.y,sq)); }
    sr[t]=sq; __syncthreads();
    for (int s=128;s>0;s>>=1){ if (t<s) sr[t]+=sr[t+s]; __syncthreads(); }
    if (gtid==0) g_scq[1]=sr[0];
  }
  gbar();
  for (int j=1;j<=n;++j){
    float xn2=g_scq[j];
    cplx alpha=g_A[(j-1)*512+(j-1)];
    RfgOut o=clarfg_head(alpha,xn2);
    if (gtid==0) g_betaq[j]=o.beta;
    cplx tauc=conjc(o.tau);
    float nsq=0.f;
    for (int c=j+1+gw;c<=n;c+=UW){
      cplx acc=make_float2(0.f,0.f);
      for (int r=j+lane;r<=m;r+=64){
        cplx v=(r==j)?make_float2(1.f,0.f):cmul(g_A[(r-1)*512+(j-1)],o.scal);
        acc=cadd(acc,cmulc(v,g_A[(r-1)*512+(c-1)]));
      }
      acc.x=wred(acc.x); acc.y=wred(acc.y);
      acc.x=__shfl(acc.x,0); acc.y=__shfl(acc.y,0);
      cplx tw=cmul(tauc,acc);
      for (int r=j+lane;r<=m;r+=64){
        cplx v=(r==j)?make_float2(1.f,0.f):cmul(g_A[(r-1)*512+(j-1)],o.scal);
        cplx nv=csub(g_A[(r-1)*512+(c-1)],cmul(tw,v));
        g_A[(r-1)*512+(c-1)]=nv;
        if (c==j+1 && r>=j+2) nsq=fmaf(nv.x,nv.x,fmaf(nv.y,nv.y,nsq));
      }
    }
    if (gw==0){
      nsq=wred(nsq);
      if (lane==0) g_scq[j+1]=nsq;
    }
    gbar();
  }
}

// cgebd2 on g_B (512 x 512), all 1023 phases in one launch.
__global__ __launch_bounds__(256) void pk_bd(){
  const int n=512;
  const int gtid=blockIdx.x*256+threadIdx.x;
  const int lane=gtid&63, gw=gtid>>6;
  // prologue: col-1 tail norm partials (512 threads worth -> blocks 0,1)
  if (blockIdx.x<2){
    int t=gtid;
    float sq=0.f;
    for (int r=2+t;r<=512;r+=512){ cplx a=g_B[(r-1)*512]; sq=fmaf(a.x,a.x,fmaf(a.y,a.y,sq)); }
    g_partR[t]=sq;
  }
  gbar();
  for (int i=1;i<=n;++i){
    { // ---- column phase (u_bd_col body) ----
      float xn2c=reduce512(g_partR);
      cplx alpha=g_B[(i-1)*512+(i-1)];
      RfgOut oc=clarfg_head(alpha,xn2c);
      if (gtid==0) g_d[i]=oc.beta;
      cplx tauc=conjc(oc.tau);
      float nsqA=0.f;
      for (int c=i+1+gw;c<=n;c+=UW){
        cplx acc=make_float2(0.f,0.f);
        for (int r=i+lane;r<=n;r+=64){
          cplx v=(r==i)?make_float2(1.f,0.f):cmul(g_B[(r-1)*512+(i-1)],oc.scal);
          acc=cadd(acc,cmulc(v,g_B[(r-1)*512+(c-1)]));
        }
        acc.x=wred(acc.x); acc.y=wred(acc.y);
        acc.x=__shfl(acc.x,0); acc.y=__shfl(acc.y,0);
        cplx tw=cmul(tauc,acc);
        for (int r=i+lane;r<=n;r+=64){
          cplx v=(r==i)?make_float2(1.f,0.f):cmul(g_B[(r-1)*512+(i-1)],oc.scal);
          cplx nv=csub(g_B[(r-1)*512+(c-1)],cmul(tw,v));
          g_B[(r-1)*512+(c-1)]=nv;
          if (r==i && c>=i+2) nsqA=fmaf(nv.x,nv.x,fmaf(nv.y,nv.y,nsqA));
        }
      }
      if (lane==0) g_partC[gw]=nsqA;
    }
    gbar();
    if (i==n) break;
    { // ---- row phase (u_bd_row body) ----
      float xn2r=reduce512(g_partC);
      cplx alphar=conjc(g_B[(i-1)*512+(i)]);
      RfgOut orr=clarfg_head(alphar,xn2r);
      if (gtid==0){ g_e[i]=orr.beta; g_taup[i]=orr.tau; g_rn[i]=xn2r; }
      float nsqB=0.f;
      for (int r=i+1+gw;r<=n;r+=UW){
        cplx acc=make_float2(0.f,0.f);
        for (int c=i+1+lane;c<=n;c+=64){
          cplx v=(c==i+1)?make_float2(1.f,0.f):cmul(conjc(g_B[(i-1)*512+(c-1)]),orr.scal);
          acc=cadd(acc,cmul(g_B[(r-1)*512+(c-1)],v));
        }
        acc.x=wred(acc.x); acc.y=wred(acc.y);
        acc.x=__shfl(acc.x,0); acc.y=__shfl(acc.y,0);
        cplx tw=cmul(orr.tau,acc);
        for (int c=i+1+lane;c<=n;c+=64){
          cplx v=(c==i+1)?make_float2(1.f,0.f):cmul(conjc(g_B[(i-1)*512+(c-1)]),orr.scal);
          cplx nv=csub(g_B[(r-1)*512+(c-1)],cmul(tw,conjc(v)));
          g_B[(r-1)*512+(c-1)]=nv;
          if (c==i+1 && r>=i+2) nsqB=fmaf(nv.x,nv.x,fmaf(nv.y,nv.y,nsqB));
        }
      }
      if (lane==0) g_partR[gw]=nsqB;
    }
    gbar();
  }
}

// big-site P^H chain: VTc (512x512) <- VTc * prod_{i=511..1} G_i^H.
// 128 blocks x 4 waves, one VTc row per wave.
__global__ __launch_bounds__(256) void u_ph(){
  const int n=512;
  int b=blockIdx.x;
  int wv=threadIdx.x>>6, lane=threadIdx.x&63;
  int r=b*4+wv+1;   // 1-based row, 512 rows over 512 waves
  for (int i=n-1;i>=1;--i){
    cplx alphar=conjc(g_B[(i-1)*512+(i)]);
    RfgOut o=clarfg_head(alphar,g_rn[i]);
    if (o.skip) continue;
    cplx tauc=conjc(o.tau);
    cplx acc=make_float2(0.f,0.f);
    for (int c=i+1+lane;c<=n;c+=64){
      cplx v=(c==i+1)?make_float2(1.f,0.f):cmul(conjc(g_B[(i-1)*512+(c-1)]),o.scal);
      acc=cadd(acc,cmul(g_VTc[(r-1)*512+(c-1)],v));
    }
    acc.x=wred(acc.x); acc.y=wred(acc.y);
    acc.x=__shfl(acc.x,0); acc.y=__shfl(acc.y,0);
    cplx tw=cmul(tauc,acc);
    for (int c=i+1+lane;c<=n;c+=64){
      cplx v=(c==i+1)?make_float2(1.f,0.f):cmul(conjc(g_B[(i-1)*512+(c-1)]),o.scal);
      g_VTc[(r-1)*512+(c-1)]=csub(g_VTc[(r-1)*512+(c-1)],cmul(tw,conjc(v)));
    }
  }
}

// ---------------- glue kernels ----------------
__global__ void k_formR(int kk){
  int t=blockIdx.x*blockDim.x+threadIdx.x;
  if (t>=kk*512) return;
  float s=g_sig[t/512];
  cplx v=g_VTc[t];
  g_R[t]=make_float2(s*v.x,s*v.y);
}

__global__ void k_next(const float* __restrict__ tmid, int site){
  int row=blockIdx.x;
  int a=row>>1, s=row&1;
  int b=blockIdx.y*blockDim.x+threadIdx.x;
  const float* base=tmid+(size_t)site*512*2*512*2;
  cplx acc=make_float2(0.f,0.f);
  for (int c=0;c<512;++c){
    cplx r=g_R[a*512+c];
    size_t off=((((size_t)c)*2+s)*512+b)*2;
    cplx x=make_float2(base[off],base[off+1]);
    acc=cadd(acc,cmul(r,x));
  }
  g_A[row*512+b]=acc;
}

__global__ void k_final(const float* __restrict__ tlast, float* __restrict__ out){
  int a=blockIdx.x*blockDim.x+threadIdx.x;
  if (a>=512) return;
  for (int s=0;s<2;++s){
    cplx acc=make_float2(0.f,0.f);
    for (int c=0;c<512;++c){
      cplx r=g_R[a*512+c];
      cplx x=make_float2(tlast[(c*2+s)*2],tlast[(c*2+s)*2+1]);
      acc=cadd(acc,cmul(r,x));
    }
    out[a*4+s*2+0]=acc.x;
    out[a*4+s*2+1]=acc.y;
  }
}

extern "C" void kernel_launch(void* const* d_in, const int* in_sizes, int n_in,
                              void* d_out, int out_size, void* d_ws, size_t ws_size,
                              hipStream_t stream) {
  const float* t_first=(const float*)d_in[0];
  const float* t_mid  =(const float*)d_in[1];
  const float* t_last =(const float*)d_in[2];
  float* out=(float*)d_out;
  (void)in_sizes; (void)n_in; (void)d_ws; (void)ws_size; (void)out_size;

  k_m0<<<dim3(4),256,0,stream>>>(t_first);

  int rows=2;
  for (int site=0;site<23;++site){
    int mm=rows;
    int nb=(mm<512)?mm:512;
    if (mm<512){
      // small sites: round-2 verified single-block path
      k_lq<<<1,1024,0,stream>>>(mm);
      k_copyL<<<dim3((mm*mm+255)/256),256,0,stream>>>(mm);
      k_bd<<<1,1024,0,stream>>>(mm);
      k_sbdsdc<<<1,1024,0,stream>>>(mm);
      k_applyPH<<<1,1024,0,stream>>>(mm);
      k_applyQlq<<<1,1024,0,stream>>>(mm);
    } else {
      if (mm==512){
        k_copyM<<<dim3((512*512+255)/256),256,0,stream>>>();
      } else {
        pk_qr<<<UBLK,256,0,stream>>>();
        k_copyR_b<<<dim3((512*512+255)/256),256,0,stream>>>();
      }
      pk_bd<<<UBLK,256,0,stream>>>();
      k_sbdsdc<<<1,1024,0,stream>>>(512);
      u_ph<<<UBLK,256,0,stream>>>();
    }
    k_formR<<<dim3((nb*512+255)/256),256,0,stream>>>(nb);
    if (site<22){
      k_next<<<dim3(2*nb,2),256,0,stream>>>(t_mid,site);
      rows=2*nb;
    } else {
      k_final<<<dim3(2),256,0,stream>>>(t_last,out);
    }
  }
}

// Round 9
// 1411125.781 us; speedup vs baseline: 1.1107x; 1.1103x over previous
//
#include <hip/hip_runtime.h>
#include <math.h>

// MPS center-orthogonalization sweep (CHI=512, Q=2, NQUBIT=24, complex64).
// Faithful GPU port of the Vh/S side of LAPACK cgesdd (jobz='S') over 23
// sites.  Round 9 = Round 7 (persistent pk_qr/pk_bd, verified absmax 32)
// with ONE change: the device barrier is now a contention-free flag tree.
// R7's counter barrier put arrivals (fetch_add) and the spin word in one
// cache line -> 128-way cross-XCD line ping-pong, ~60us/barrier.  New gbar:
// per-block 128B-strided arrival slots (parallel stores), block 0 polls the
// 127 slots in parallel (1 thread/slot), then publishes a line-aligned
// generation counter.  Generation is monotonic across launches and graph
// replays (read at kernel entry).  Phase bodies byte-identical to R7/R6.

#define LDV 513
typedef float2 cplx;

__device__ __forceinline__ cplx cmul(cplx a, cplx b){ return make_float2(a.x*b.x - a.y*b.y, a.x*b.y + a.y*b.x); }
__device__ __forceinline__ cplx cmulc(cplx a, cplx b){ /*conj(a)*b*/ return make_float2(a.x*b.x + a.y*b.y, a.x*b.y - a.y*b.x); }
__device__ __forceinline__ cplx cadd(cplx a, cplx b){ return make_float2(a.x+b.x, a.y+b.y); }
__device__ __forceinline__ cplx csub(cplx a, cplx b){ return make_float2(a.x-b.x, a.y-b.y); }
__device__ __forceinline__ cplx conjc(cplx a){ return make_float2(a.x, -a.y); }

#define EPS_S 5.9604645e-8f
#define UNFL_S 1.17549435e-38f
#define UW 512    // waves in persistent update grid (128 blocks x 256 thr)
#define UBLK 128  // blocks for persistent/hot kernels
#define SLOT 32   // arrival-slot stride in unsigned (128 B)

// ---------------- device global workspace ----------------
__device__ cplx g_A[1024*512];     // current M / QR-LQ factors (raw)
__device__ cplx g_B[512*512];      // square matrix for bidiagonalization (raw)
__device__ cplx g_VTc[512*512];    // complex VT being assembled
__device__ cplx g_R[512*512];      // bond matrix R = diag(s)*VT
__device__ cplx g_tauf[520];       // LQ taus (small path)
__device__ cplx g_taup[520];       // cgebd2 row taus
__device__ float g_d[520], g_e[520];
__device__ float g_VTr[LDV*LDV];
__device__ float g_VT2[LDV*LDV];
__device__ float g_W[LDV*LDV];
__device__ float g_z[520], g_zz[520], g_zorig[520], g_dtmp[520], g_ztmp[520], g_dsig[520];
__device__ double g_root[520];
__device__ int g_idxq[520], g_idx[520], g_idxp[520], g_rowmap[520];
__device__ int g_inode[80], g_ndiml[80], g_ndimr[80];
__device__ float g_sig[520];
__device__ int g_K, g_nlvl_, g_nd_;
__device__ float g_tol_, g_z1_;
__device__ double g_rho_;
// big-path chain scalars
__device__ float g_scq[520];       // QR column-tail norms
__device__ float g_betaq[520];     // QR betas (R diagonal)
__device__ float g_rn[520];        // BD row-reflector tail norms (u_ph recompute)
__device__ float g_partC[UW];      // BD col-phase per-wave partials
__device__ float g_partR[UW];      // BD row-phase / prologue partials
// flag-tree barrier state
__device__ unsigned g_arrive[UBLK*SLOT];                     // slot b at [b*SLOT]
__device__ __attribute__((aligned(128))) unsigned g_gen = 0; // generation, own line
__device__ int g_barfail = 0;

// ---------------- contention-free device barrier ----------------
__device__ __forceinline__ unsigned gbar_init(){
  __shared__ unsigned s_g;
  if (threadIdx.x==0)
    s_g=__hip_atomic_load(&g_gen,__ATOMIC_RELAXED,__HIP_MEMORY_SCOPE_AGENT);
  __syncthreads();
  return s_g;
}

__device__ __forceinline__ void gbar(unsigned &gen){
  __syncthreads();
  gen++;
  if (blockIdx.x==0){
    if (threadIdx.x>=1 && threadIdx.x<UBLK){
      long k=0;
      while(!g_barfail &&
            (int)(__hip_atomic_load(&g_arrive[threadIdx.x*SLOT],__ATOMIC_ACQUIRE,__HIP_MEMORY_SCOPE_AGENT)-gen)<0){
        __builtin_amdgcn_s_sleep(4);
        if(++k>(1L<<22)){ g_barfail=1; break; }
      }
    }
    __syncthreads();
    if (threadIdx.x==0){
      __threadfence();
      __hip_atomic_store(&g_gen,gen,__ATOMIC_RELEASE,__HIP_MEMORY_SCOPE_AGENT);
    }
  } else {
    if (threadIdx.x==0){
      __threadfence();
      __hip_atomic_store(&g_arrive[blockIdx.x*SLOT],gen,__ATOMIC_RELEASE,__HIP_MEMORY_SCOPE_AGENT);
      long k=0;
      while(!g_barfail &&
            (int)(__hip_atomic_load(&g_gen,__ATOMIC_ACQUIRE,__HIP_MEMORY_SCOPE_AGENT)-gen)<0){
        __builtin_amdgcn_s_sleep(4);
        if(++k>(1L<<22)){ g_barfail=1; break; }
      }
      __threadfence();
    }
  }
  __syncthreads();
}

// ---------------- reduce helpers ----------------
__device__ __forceinline__ float wred(float v){
  for (int off=32;off;off>>=1) v+=__shfl_down(v,off);
  return v;
}
// deterministic 512-entry reduce done identically in every block (256 thr)
__device__ __forceinline__ float reduce512(const float* arr){
  __shared__ float sr[256];
  sr[threadIdx.x]=arr[threadIdx.x]+arr[threadIdx.x+256];
  __syncthreads();
  for (int s=128;s>0;s>>=1){
    if (threadIdx.x<s) sr[threadIdx.x]+=sr[threadIdx.x+s];
    __syncthreads();
  }
  float v=sr[0];
  __syncthreads();
  return v;
}

// ---------------- clarfg (LAPACK conventions) ----------------
struct RfgOut { float beta; cplx tau; cplx scal; int skip; };
__device__ RfgOut clarfg_head(cplx alpha, float xn2){
  RfgOut o;
  if (xn2==0.f && alpha.y==0.f){
    o.beta=alpha.x; o.tau=make_float2(0.f,0.f); o.scal=make_float2(0.f,0.f); o.skip=1;
  } else {
    float anorm=sqrtf(alpha.x*alpha.x+alpha.y*alpha.y+xn2);
    float beta=(alpha.x>=0.f)?-anorm:anorm;
    o.beta=beta;
    o.tau=make_float2((beta-alpha.x)/beta,-alpha.y/beta);
    cplx dd=make_float2(alpha.x-beta,alpha.y);
    float dn=dd.x*dd.x+dd.y*dd.y;
    o.scal=make_float2(dd.x/dn,-dd.y/dn);
    o.skip=0;
  }
  return o;
}

// ---------------- small serial real-LAPACK helpers (round-2 verbatim) ----------------
__device__ float slapy2(float x, float y){
  float xa=fabsf(x), ya=fabsf(y);
  float w=fmaxf(xa,ya), z=fminf(xa,ya);
  if (z==0.f) return w;
  float q=z/w; return w*sqrtf(1.f+q*q);
}

__device__ void slartg(float f, float g, float* cs, float* sn, float* r){
  if (g==0.f){ *cs=1.f; *sn=0.f; *r=f; }
  else if (f==0.f){ *cs=0.f; *sn=(g>0.f)?1.f:-1.f; *r=fabsf(g); }
  else {
    float f1=fabsf(f);
    float d=sqrtf(f*f+g*g);
    *cs = f1/d;
    *r = (f>0.f)? d : -d;
    *sn = g / *r;
  }
}

__device__ void slas2(float f, float g, float h, float* ssmin, float* ssmax){
  float fa=fabsf(f), ga=fabsf(g), ha=fabsf(h);
  float fhmn=fminf(fa,ha), fhmx=fmaxf(fa,ha);
  if (fhmn==0.f){
    *ssmin=0.f;
    if (fhmx==0.f) *ssmax=ga;
    else { float mx=fmaxf(fhmx,ga), mn=fminf(fhmx,ga); float q=mn/mx; *ssmax=mx*sqrtf(1.f+q*q); }
  } else {
    if (ga < fhmx){
      float as=1.f+fhmn/fhmx, at=(fhmx-fhmn)/fhmx;
      float au=ga/fhmx; au=au*au;
      float c=2.f/(sqrtf(as*as+au)+sqrtf(at*at+au));
      *ssmin=fhmn*c; *ssmax=fhmx/c;
    } else {
      float au=fhmx/ga;
      if (au==0.f){ *ssmin=(fhmn*fhmx)/ga; *ssmax=ga; }
      else {
        float as=1.f+fhmn/fhmx, at=(fhmx-fhmn)/fhmx;
        float c=1.f/(sqrtf(1.f+(as*au)*(as*au))+sqrtf(1.f+(at*au)*(at*au)));
        *ssmin=(fhmn*c)*au; *ssmin=*ssmin+*ssmin;
        *ssmax=ga/(c+c);
      }
    }
  }
}

__device__ void slasv2(float f, float g, float h, float* ssmin, float* ssmax,
                       float* snr, float* csr, float* snl, float* csl){
  float ft=f, fa=fabsf(f), ht=h, ha=fabsf(h);
  int pmax=1;
  bool swap_=(ha>fa);
  if (swap_){ pmax=3; float t=ft; ft=ht; ht=t; t=fa; fa=ha; ha=t; }
  float gt=g, ga=fabsf(g);
  float clt=0.f, crt=0.f, slt=0.f, srt=0.f;
  if (ga==0.f){ *ssmin=ha; *ssmax=fa; clt=1.f; crt=1.f; slt=0.f; srt=0.f; }
  else {
    bool gasmal=true;
    if (ga>fa){
      pmax=2;
      if ((fa/ga) < EPS_S){
        gasmal=false;
        *ssmax=ga;
        if (ha>1.f) *ssmin=fa/(ga/ha); else *ssmin=(fa/ga)*ha;
        clt=1.f; slt=ht/gt; srt=1.f; crt=ft/gt;
      }
    }
    if (gasmal){
      float d=fa-ha;
      float l=(d==fa)?1.f:(d/fa);
      float mm=gt/ft;
      float t=2.f-l;
      float mm2=mm*mm, tt=t*t;
      float s=sqrtf(tt+mm2);
      float r=(l==0.f)?fabsf(mm):sqrtf(l*l+mm2);
      float a=0.5f*(s+r);
      *ssmin=ha/a; *ssmax=fa*a;
      if (mm2==0.f){
        if (l==0.f) t=copysignf(2.f,ft)*copysignf(1.f,gt);
        else t=gt/copysignf(d,ft)+mm/t;
      } else {
        t=(mm/(s+t)+mm/(r+l))*(1.f+a);
      }
      float l2=sqrtf(t*t+4.f);
      crt=2.f/l2; srt=t/l2;
      clt=(crt+srt*mm)/a;
      slt=(ht/ft)*srt/a;
    }
  }
  if (swap_){ *csl=srt; *snl=crt; *csr=slt; *snr=clt; }
  else      { *csl=clt; *snl=slt; *csr=crt; *snr=srt; }
  float tsign=0.f;
  if (pmax==1) tsign=copysignf(1.f,*csr)*copysignf(1.f,*csl)*copysignf(1.f,f);
  if (pmax==2) tsign=copysignf(1.f,*snr)*copysignf(1.f,*csl)*copysignf(1.f,g);
  if (pmax==3) tsign=copysignf(1.f,*snr)*copysignf(1.f,*snl)*copysignf(1.f,h);
  *ssmax=copysignf(*ssmax,tsign);
  *ssmin=copysignf(*ssmin,tsign*copysignf(1.f,f)*copysignf(1.f,h));
}

__device__ void slasr_f(int mrows, int ncols, const float* c1, const float* s1, float* a, int lda){
  for (int j=1;j<=mrows-1;++j){
    float ct=c1[j], st=s1[j];
    if (ct!=1.f || st!=0.f){
      float* rj=&a[(j-1)*lda]; float* rj1=&a[j*lda];
      for (int i=0;i<ncols;++i){
        float tmp=rj1[i];
        rj1[i]=ct*tmp-st*rj[i];
        rj[i]=st*tmp+ct*rj[i];
      }
    }
  }
}
__device__ void slasr_b(int mrows, int ncols, const float* c1, const float* s1, float* a, int lda){
  for (int j=mrows-1;j>=1;--j){
    float ct=c1[j], st=s1[j];
    if (ct!=1.f || st!=0.f){
      float* rj=&a[(j-1)*lda]; float* rj1=&a[j*lda];
      for (int i=0;i<ncols;++i){
        float tmp=rj1[i];
        rj1[i]=ct*tmp-st*rj[i];
        rj[i]=st*tmp+ct*rj[i];
      }
    }
  }
}

// serial SBDSQR('U', n, ncvt, 0, 0) — VT only.
__device__ void sbdsqr_u(int n, int ncvt, float* d, float* e, float* vt, int ldvt){
  const int MAXITR=6;
  if (n==0) return;
  if (n>1){
    int nm1=n-1, nm12=nm1+nm1, nm13=nm12+nm1;
    float wk[112];
    float tolmul=10.f;
    float tol=tolmul*EPS_S;
    float smax=0.f;
    for (int i=1;i<=n;i++) smax=fmaxf(smax,fabsf(d[i]));
    for (int i=1;i<=n-1;i++) smax=fmaxf(smax,fabsf(e[i]));
    float sminl=0.f, thresh;
    {
      float sminoa=fabsf(d[1]);
      if (sminoa!=0.f){
        float mu=sminoa;
        for (int i=2;i<=n;i++){
          mu=fabsf(d[i])*(mu/(mu+fabsf(e[i-1])));
          sminoa=fminf(sminoa,mu);
          if (sminoa==0.f) break;
        }
      }
      sminoa=sminoa/sqrtf((float)n);
      thresh=fmaxf(tol*sminoa,(float)(MAXITR*n*n)*UNFL_S);
    }
    int M=n, iter=0, maxit=MAXITR*n*n;
    int oldll=-1, oldm=-1, idir=0;
    while (1){
      if (M<=1) break;
      if (iter>maxit) break;
      int ll=0; bool split=false;
      smax=fabsf(d[M]);
      for (int lll=1;lll<=M-1;++lll){
        ll=M-lll;
        float abss=fabsf(d[ll]), abse=fabsf(e[ll]);
        if (abse<=thresh){ split=true; break; }
        smax=fmaxf(smax,fmaxf(abss,abse));
      }
      if (!split) ll=0;
      else {
        e[ll]=0.f;
        if (ll==M-1){ M=M-1; continue; }
      }
      ll=ll+1;
      if (ll==M-1){
        float sigmn,sigmx,sinr,cosr,sinl,cosl;
        slasv2(d[M-1],e[M-1],d[M],&sigmn,&sigmx,&sinr,&cosr,&sinl,&cosl);
        d[M-1]=sigmx; e[M-1]=0.f; d[M]=sigmn;
        if (ncvt>0){
          float* x=&vt[(M-2)*ldvt]; float* y=&vt[(M-1)*ldvt];
          for (int c=0;c<ncvt;c++){ float xv=x[c],yv=y[c]; x[c]=cosr*xv+sinr*yv; y[c]=cosr*yv-sinr*xv; }
        }
        M-=2; continue;
      }
      if (ll>oldm || M<oldll) idir=(fabsf(d[ll])>=fabsf(d[M]))?1:2;
      bool conv=false;
      if (idir==1){
        if (fabsf(e[M-1])<=fabsf(tol)*fabsf(d[M])){ e[M-1]=0.f; conv=true; }
        else {
          float mu=fabsf(d[ll]); sminl=mu;
          for (int lll=ll;lll<=M-1;++lll){
            if (fabsf(e[lll])<=tol*mu){ e[lll]=0.f; conv=true; break; }
            mu=fabsf(d[lll+1])*(mu/(mu+fabsf(e[lll])));
            sminl=fminf(sminl,mu);
          }
        }
      } else {
        if (fabsf(e[ll])<=fabsf(tol)*fabsf(d[ll])){ e[ll]=0.f; conv=true; }
        else {
          float mu=fabsf(d[M]); sminl=mu;
          for (int lll=M-1;lll>=ll;--lll){
            if (fabsf(e[lll])<=tol*mu){ e[lll]=0.f; conv=true; break; }
            mu=fabsf(d[lll])*(mu/(mu+fabsf(e[lll])));
            sminl=fminf(sminl,mu);
          }
        }
      }
      if (conv) continue;
      oldll=ll; oldm=M;
      float shift=0.f, rr;
      if ((float)n*tol*(sminl/smax)<=fmaxf(EPS_S,0.01f*tol)) shift=0.f;
      else {
        float sll;
        if (idir==1){ sll=fabsf(d[ll]); slas2(d[M-1],e[M-1],d[M],&shift,&rr); }
        else        { sll=fabsf(d[M]);  slas2(d[ll],e[ll],d[ll+1],&shift,&rr); }
        if (sll>0.f){ float q=shift/sll; if (q*q<EPS_S) shift=0.f; }
      }
      iter += M-ll;
      if (shift==0.f){
        if (idir==1){
          float cs=1.f, oldcs=1.f, sn=0.f, oldsn=0.f;
          for (int i=ll;i<=M-1;++i){
            float c2,r1;
            slartg(d[i]*cs,e[i],&c2,&sn,&r1); cs=c2;
            if (i>ll) e[i-1]=oldsn*r1;
            float oc2;
            slartg(oldcs*r1,d[i+1]*sn,&oc2,&oldsn,&d[i]); oldcs=oc2;
            wk[i-ll+1]=cs; wk[i-ll+1+nm1]=sn;
          }
          float h=d[M]*cs; d[M]=h*oldcs; e[M-1]=h*oldsn;
          if (ncvt>0) slasr_f(M-ll+1,ncvt,wk,wk+nm1,&vt[(ll-1)*ldvt],ldvt);
          if (fabsf(e[M-1])<=thresh) e[M-1]=0.f;
        } else {
          float cs=1.f, oldcs=1.f, sn=0.f, oldsn=0.f;
          for (int i=M;i>=ll+1;--i){
            float c2,r1;
            slartg(d[i]*cs,e[i-1],&c2,&sn,&r1); cs=c2;
            if (i<M) e[i]=oldsn*r1;
            float oc2;
            slartg(oldcs*r1,d[i-1]*sn,&oc2,&oldsn,&d[i]); oldcs=oc2;
            wk[i-ll]=cs; wk[i-ll+nm1]=-sn;
            wk[i-ll+nm12]=oldcs; wk[i-ll+nm13]=-oldsn;
          }
          float h=d[ll]*cs; d[ll]=h*oldcs; e[ll]=h*oldsn;
          if (ncvt>0) slasr_b(M-ll+1,ncvt,wk+nm12,wk+nm13,&vt[(ll-1)*ldvt],ldvt);
          if (fabsf(e[ll])<=thresh) e[ll]=0.f;
        }
      } else {
        if (idir==1){
          float f=(fabsf(d[ll])-shift)*(copysignf(1.f,d[ll])+shift/d[ll]);
          float g=e[ll], cosr,sinr,cosl,sinl,r1;
          for (int i=ll;i<=M-1;++i){
            slartg(f,g,&cosr,&sinr,&r1);
            if (i>ll) e[i-1]=r1;
            f=cosr*d[i]+sinr*e[i];
            e[i]=cosr*e[i]-sinr*d[i];
            g=sinr*d[i+1];
            d[i+1]=cosr*d[i+1];
            slartg(f,g,&cosl,&sinl,&r1);
            d[i]=r1;
            f=cosl*e[i]+sinl*d[i+1];
            d[i+1]=cosl*d[i+1]-sinl*e[i];
            if (i<M-1){ g=sinl*e[i+1]; e[i+1]=cosl*e[i+1]; }
            wk[i-ll+1]=cosr; wk[i-ll+1+nm1]=sinr;
            wk[i-ll+1+nm12]=cosl; wk[i-ll+1+nm13]=sinl;
          }
          e[M-1]=f;
          if (ncvt>0) slasr_f(M-ll+1,ncvt,wk,wk+nm1,&vt[(ll-1)*ldvt],ldvt);
          if (fabsf(e[M-1])<=thresh) e[M-1]=0.f;
        } else {
          float f=(fabsf(d[M])-shift)*(copysignf(1.f,d[M])+shift/d[M]);
          float g=e[M-1], cosr,sinr,cosl,sinl,r1;
          for (int i=M;i>=ll+1;--i){
            slartg(f,g,&cosr,&sinr,&r1);
            if (i<M) e[i]=r1;
            f=cosr*d[i]+sinr*e[i-1];
            e[i-1]=cosr*e[i-1]-sinr*d[i];
            g=sinr*d[i-1];
            d[i-1]=cosr*d[i-1];
            slartg(f,g,&cosl,&sinl,&r1);
            d[i]=r1;
            f=cosl*e[i-1]+sinl*d[i-1];
            d[i-1]=cosl*d[i-1]-sinl*e[i-1];
            if (i>ll+1){ g=sinl*e[i-2]; e[i-2]=cosl*e[i-2]; }
            wk[i-ll]=cosr; wk[i-ll+nm1]=-sinr;
            wk[i-ll+nm12]=cosl; wk[i-ll+nm13]=-sinl;
          }
          e[ll]=f;
          if (fabsf(e[ll])<=thresh) e[ll]=0.f;
          if (ncvt>0) slasr_b(M-ll+1,ncvt,wk+nm12,wk+nm13,&vt[(ll-1)*ldvt],ldvt);
        }
      }
    }
  }
  for (int i=1;i<=n;i++){
    if (d[i]<0.f){
      d[i]=-d[i];
      if (ncvt>0){ float* row=&vt[(i-1)*ldvt]; for (int c=0;c<ncvt;c++) row[c]=-row[c]; }
    }
  }
  for (int i=1;i<=n-1;i++){
    int isub=1; float smin2=d[1];
    for (int j=2;j<=n+1-i;j++){ if (d[j]<=smin2){ isub=j; smin2=d[j]; } }
    if (isub!=n+1-i){
      d[isub]=d[n+1-i]; d[n+1-i]=smin2;
      if (ncvt>0){
        float* a=&vt[(isub-1)*ldvt]; float* b=&vt[(n-i)*ldvt];
        for (int c=0;c<ncvt;c++){ float t=a[c]; a[c]=b[c]; b[c]=t; }
      }
    }
  }
}

__device__ void slasdq_u(int sqre, int n, int ncvt, float* d, float* e, float* vt, int ldvt){
  if (n==0) return;
  float cwk[33], swk[33];
  int np1=n+1;
  if (sqre==1){
    for (int i=1;i<=n-1;i++){
      float cs,sn,r; slartg(d[i],e[i],&cs,&sn,&r);
      d[i]=r; e[i]=sn*d[i+1]; d[i+1]=cs*d[i+1];
      cwk[i]=cs; swk[i]=sn;
    }
    { float cs,sn,r; slartg(d[n],e[n],&cs,&sn,&r);
      d[n]=r; e[n]=0.f; cwk[n]=cs; swk[n]=sn; }
    if (ncvt>0) slasr_f(np1,ncvt,cwk,swk,vt,ldvt);
    for (int i=1;i<=n-1;i++){
      float cs,sn,r; slartg(d[i],e[i],&cs,&sn,&r);
      d[i]=r; e[i]=sn*d[i+1]; d[i+1]=cs*d[i+1];
    }
  }
  sbdsqr_u(n,ncvt,d,e,vt,ldvt);
  for (int i=1;i<=n;i++){
    int isub=i; float smin2=d[i];
    for (int j=i+1;j<=n;j++){ if (d[j]<smin2){ isub=j; smin2=d[j]; } }
    if (isub!=i){
      d[isub]=d[i]; d[i]=smin2;
      if (ncvt>0){
        float* a=&vt[(isub-1)*ldvt]; float* b=&vt[(i-1)*ldvt];
        for (int c=0;c<ncvt;c++){ float t=a[c]; a[c]=b[c]; b[c]=t; }
      }
    }
  }
}

__device__ void slamrg(int n1, int n2, const float* a, int s1, int s2, int* idx){
  int n1sv=n1, n2sv=n2, i=1;
  int ind1=(s1>0)?1:n1;
  int ind2=(s2>0)?(1+n1):(n1+n2);
  while (n1sv>0 && n2sv>0){
    if (a[ind1]<=a[ind2]){ idx[i++]=ind1; ind1+=s1; n1sv--; }
    else { idx[i++]=ind2; ind2+=s2; n2sv--; }
  }
  if (n1sv==0){ for(;n2sv>0;n2sv--){ idx[i++]=ind2; ind2+=s2; } }
  else { for(;n1sv>0;n1sv--){ idx[i++]=ind1; ind1+=s1; } }
}

__device__ void slasdt(int n, int* lvl, int* nd, int* inode, int* ndiml, int* ndimr, int msub){
  int maxn=(n>1)?n:1;
  float temp=logf((float)maxn/(float)(msub+1))/logf(2.f);
  *lvl=(int)temp+1;
  int i=n/2;
  inode[1]=i+1; ndiml[1]=i; ndimr[1]=n-i-1;
  int il=0, ir=1, llst=1;
  for (int nl=1;nl<=*lvl-1;++nl){
    for (int j=0;j<=llst-1;++j){
      il+=2; ir+=2;
      int nc=llst+j;
      ndiml[il]=ndiml[nc]/2;
      ndimr[il]=ndiml[nc]-ndiml[il]-1;
      inode[il]=inode[nc]-ndimr[il]-1;
      ndiml[ir]=ndimr[nc]/2;
      ndimr[ir]=ndimr[nc]-ndiml[ir]-1;
      inode[ir]=inode[nc]+ndiml[ir]+1;
    }
    llst*=2;
  }
  *nd=llst*2-1;
}

// ---------------- block-cooperative slasd1 (round-2 verbatim) ----------------
__device__ void merge_node(int nl, int nr, int sqre, float* d, int* idxq,
                           float alpha, float beta, float* VT, int ld)
{
  const int tid=threadIdx.x, nth=blockDim.x;
  const int n=nl+nr+1, m=n+sqre, nlp1=nl+1, nlp2=nl+2;
  if (tid==0){
    float* z=g_z;
    float z1=alpha*VT[(nlp1-1)*ld+(nlp1-1)];
    z[1]=z1; g_z1_=z1;
    for (int i=nl;i>=1;--i){
      z[i+1]=alpha*VT[(i-1)*ld+(nlp1-1)];
      d[i+1]=d[i];
      idxq[i+1]=idxq[i]+1;
    }
    for (int i=nlp2;i<=m;++i) z[i]=beta*VT[(i-1)*ld+(nlp2-1)];
    d[1]=0.f;
    for (int i=nlp2;i<=n;++i) idxq[i]+=nlp1;
    for (int i=2;i<=n;++i){ g_dtmp[i]=d[idxq[i]]; g_ztmp[i]=z[idxq[i]]; }
    slamrg(nl,nr,g_dtmp+1,1,1,g_idx+1);
    for (int i=2;i<=n;++i){
      int idxi=1+g_idx[i];
      d[i]=g_dtmp[idxi];
      z[i]=g_ztmp[idxi];
    }
    float tol=fmaxf(fabsf(alpha),fabsf(beta));
    tol=8.f*EPS_S*fmaxf(fabsf(d[n]),tol);
    g_tol_=tol;
    int K=1, K2=n+1, jprev=0, j;
    for (j=2;j<=n;++j){
      if (fabsf(z[j])<=tol){
        K2--; g_idxp[K2]=j;
        if (j==n){ jprev=0; break; }
      } else { jprev=j; break; }
    }
    if (jprev>0){
      j=jprev;
      for (;;){
        j++;
        if (j>n) break;
        if (fabsf(z[j])<=tol){ K2--; g_idxp[K2]=j; }
        else {
          if (fabsf(d[j]-d[jprev])<=tol){
            float s_=z[jprev], c_=z[j];
            float tau_=slapy2(c_,s_);
            c_/=tau_; s_=-s_/tau_;
            z[j]=tau_; z[jprev]=0.f;
            int idxjp=idxq[g_idx[jprev]+1];
            int idxj =idxq[g_idx[j]+1];
            if (idxjp<=nlp1) idxjp--;
            if (idxj <=nlp1) idxj--;
            float* xr=&VT[(idxjp-1)*ld];
            float* yr=&VT[(idxj-1)*ld];
            for (int cc=0;cc<m;++cc){
              float xv=xr[cc], yv=yr[cc];
              xr[cc]=c_*xv+s_*yv;
              yr[cc]=c_*yv-s_*xv;
            }
            K2--; g_idxp[K2]=jprev;
            jprev=j;
          } else {
            K++; g_zz[K]=z[jprev]; g_idxp[K]=jprev;
            jprev=j;
          }
        }
      }
      K++; g_zz[K]=z[jprev]; g_idxp[K]=jprev;
    }
    g_K=K;
    for (int jj=2;jj<=n;++jj){
      g_dsig[jj]=d[g_idxp[jj]];
      int rm=idxq[g_idx[g_idxp[jj]]+1];
      if (rm<=nlp1) rm--;
      g_rowmap[jj]=rm;
    }
  }
  __syncthreads();
  int K=g_K;
  for (int t=tid;t<(n-1)*m;t+=nth){
    int jj=2+t/m, cc=t%m;
    g_VT2[(jj-1)*LDV+cc]=VT[(g_rowmap[jj]-1)*ld+cc];
  }
  __syncthreads();
  if (tid==0){
    float tol=g_tol_;
    g_dsig[1]=0.f;
    float hlftol=tol*0.5f;
    if (fabsf(g_dsig[2])<=hlftol) g_dsig[2]=hlftol;
    float z1=g_z1_;
    float c_=1.f, s_=0.f;
    if (m>n){
      float t1=slapy2(z1,g_z[m]);
      if (t1<=tol){ c_=1.f; s_=0.f; g_z[1]=tol; }
      else { g_z[1]=t1; c_=z1/t1; s_=g_z[m]/t1; }
    } else {
      if (fabsf(z1)<=tol) g_z[1]=tol; else g_z[1]=z1;
    }
    for (int jj=2;jj<=K;++jj) g_z[jj]=g_zz[jj];
    if (m>n){
      for (int i=1;i<=nlp1;++i){
        float v=VT[(nlp1-1)*ld+(i-1)];
        VT[(m-1)*ld+(i-1)]=-s_*v;
        g_VT2[(i-1)]=c_*v;
      }
      for (int i=nlp2;i<=m;++i){
        float v=VT[(m-1)*ld+(i-1)];
        g_VT2[(i-1)]=s_*v;
        VT[(m-1)*ld+(i-1)]=c_*v;
      }
    } else {
      for (int i=1;i<=m;++i) g_VT2[(i-1)]=VT[(nlp1-1)*ld+(i-1)];
    }
    for (int jj=K+1;jj<=n;++jj) d[jj]=g_dsig[jj];
    double rho=0.0;
    for (int jj=1;jj<=K;++jj){ double zz2=(double)g_z[jj]; rho+=zz2*zz2; g_zorig[jj]=g_z[jj]; }
    g_rho_=rho;
  }
  __syncthreads();
  for (int t=tid;t<(n-K)*m;t+=nth){
    int jj=K+1+t/m, cc=t%m;
    VT[(jj-1)*ld+cc]=g_VT2[(jj-1)*LDV+cc];
  }
  __syncthreads();
  if (K==1){
    if (tid==0){
      d[1]=fabsf(g_z[1]);
      for (int cc=0;cc<m;++cc) VT[cc]=g_VT2[cc];
      slamrg(1,n-1,d,1,-1,idxq);
    }
    __syncthreads();
    return;
  }
  {
    double rho=g_rho_;
    for (int i=1+tid;i<=K;i+=nth){
      double di=(double)g_dsig[i];
      double lo=di*di, hi;
      if (i<K){ double dn=(double)g_dsig[i+1]; hi=dn*dn; }
      else { double dn=(double)g_dsig[K]; hi=dn*dn+rho; }
      for (int it=0;it<110;++it){
        double mid=0.5*(lo+hi);
        double f=1.0;
        for (int j=1;j<=K;++j){
          double dj=(double)g_dsig[j];
          double zj=(double)g_z[j];
          f+=zj*zj/(dj*dj-mid);
        }
        if (f>=0.0) hi=mid; else lo=mid;
      }
      g_root[i]=0.5*(lo+hi);
      d[i]=(float)sqrt(g_root[i]);
    }
  }
  __syncthreads();
  for (int i=1+tid;i<=K;i+=nth){
    double di=(double)g_dsig[i], di2=di*di;
    double p=di2-g_root[K];
    for (int j=1;j<=i-1;++j){
      double dj=(double)g_dsig[j];
      p*=(di2-g_root[j])/((di-dj)*(di+dj));
    }
    for (int j=i;j<=K-1;++j){
      double dj1=(double)g_dsig[j+1];
      p*=(di2-g_root[j])/((di-dj1)*(di+dj1));
    }
    g_ztmp[i]=copysignf((float)sqrt(fabs(p)),g_zorig[i]);
  }
  __syncthreads();
  for (int i=1+tid;i<=K;i+=nth) g_z[i]=g_ztmp[i];
  __syncthreads();
  for (int i=1+tid;i<=K;i+=nth){
    double xi=g_root[i];
    double nrm=0.0;
    for (int j=1;j<=K;++j){
      double dj=(double)g_dsig[j];
      double w=(double)g_z[j]/(dj*dj-xi);
      g_W[(i-1)*LDV+(j-1)]=(float)w;
      nrm+=w*w;
    }
    float inv=(float)(1.0/sqrt(nrm));
    for (int j=1;j<=K;++j) g_W[(i-1)*LDV+(j-1)]*=inv;
  }
  __syncthreads();
  for (int t=tid;t<K*m;t+=nth){
    int i=1+t/m, cc=t%m;
    float acc=0.f;
    for (int j=1;j<=K;++j)
      acc=fmaf(g_W[(i-1)*LDV+(j-1)],g_VT2[(j-1)*LDV+cc],acc);
    VT[(i-1)*ld+cc]=acc;
  }
  __syncthreads();
  if (tid==0) slamrg(K,n-K,d,1,-1,idxq);
  __syncthreads();
}

// ---------------- sbdsdc driver kernel (round-2 verbatim) ----------------
__global__ __launch_bounds__(1024) void k_sbdsdc(int n){
  const int tid=threadIdx.x, lane=tid&63, wv=tid>>6;
  for (int t=tid;t<n*n;t+=1024)
    g_VTr[(t/n)*LDV+(t%n)]=((t/n)==(t%n))?1.f:0.f;
  __syncthreads();
  if (n<=25){
    if (tid==0){
      slasdq_u(0,n,n,g_d,g_e,g_VTr,LDV);
      for (int j=1;j<=n;++j) g_idxq[j]=j;
    }
    __syncthreads();
  } else {
    if (tid==0){
      int lvl,nd;
      slasdt(n,&lvl,&nd,g_inode,g_ndiml,g_ndimr,25);
      g_nlvl_=lvl; g_nd_=nd;
    }
    __syncthreads();
    int nd=g_nd_, nlvl=g_nlvl_;
    int ndb1=(nd+1)/2;
    int ntask=(nd-ndb1+1)*2;
    for (int task=wv;task<ntask;task+=16){
      if (lane==0){
        int node=ndb1+(task>>1);
        int ic=g_inode[node], nl=g_ndiml[node], nr=g_ndimr[node];
        if ((task&1)==0){
          int nlf=ic-nl;
          slasdq_u(1,nl,nl+1,g_d+(nlf-1),g_e+(nlf-1),&g_VTr[(nlf-1)*LDV+(nlf-1)],LDV);
          for (int j2=1;j2<=nl;++j2) g_idxq[nlf-1+j2]=j2;
        } else {
          int nrf=ic+1;
          int sq=(node==nd)?0:1;
          slasdq_u(sq,nr,nr+sq,g_d+(nrf-1),g_e+(nrf-1),&g_VTr[(nrf-1)*LDV+(nrf-1)],LDV);
          for (int j2=1;j2<=nr;++j2) g_idxq[nrf-1+j2]=j2;
        }
      }
    }
    __syncthreads();
    for (int lvl=nlvl;lvl>=1;--lvl){
      int lf=(lvl==1)?1:(1<<(lvl-1));
      int llast=(lvl==1)?1:(2*lf-1);
      for (int node=lf;node<=llast;++node){
        int ic=g_inode[node], nl=g_ndiml[node], nr=g_ndimr[node];
        int nlf=ic-nl;
        int sq=(node==llast)?0:1;
        float alpha=g_d[ic], beta=g_e[ic];
        merge_node(nl,nr,sq,g_d+(nlf-1),g_idxq+(nlf-1),alpha,beta,
                   &g_VTr[(nlf-1)*LDV+(nlf-1)],LDV);
      }
    }
  }
  __syncthreads();
  for (int t=tid;t<n*512;t+=1024){
    int i=t/512, c=t%512;
    int o=g_idxq[n-i];
    float v=(c<n)?g_VTr[(o-1)*LDV+c]:0.f;
    g_VTc[i*512+c]=make_float2(v,0.f);
    if (c==0) g_sig[i]=g_d[o];
  }
}

// ---------------- small-site single-block kernels (round-2 verbatim) ----------------
__global__ void k_m0(const float* __restrict__ tf){
  int i=blockIdx.x*blockDim.x+threadIdx.x;
  if (i<1024) g_A[i]=make_float2(tf[2*i],tf[2*i+1]);
}

__global__ __launch_bounds__(1024) void k_lq(int m){
  const int n=512;
  const int tid=threadIdx.x, lane=tid&63, wv=tid>>6;
  __shared__ float s_part[16];
  __shared__ cplx s_tau, s_scal;
  __shared__ float s_beta; __shared__ int s_skip;
  for (int i=1;i<=m;++i){
    for (int c=i+tid;c<=n;c+=1024) g_A[(i-1)*512+(c-1)].y=-g_A[(i-1)*512+(c-1)].y;
    __syncthreads();
    float sq=0.f;
    for (int c=i+1+tid;c<=n;c+=1024){
      cplx a=g_A[(i-1)*512+(c-1)];
      sq=fmaf(a.x,a.x,fmaf(a.y,a.y,sq));
    }
    sq=wred(sq);
    if (lane==0) s_part[wv]=sq;
    __syncthreads();
    if (tid==0){
      float xn2=0.f; for (int w=0;w<16;w++) xn2+=s_part[w];
      RfgOut o=clarfg_head(g_A[(i-1)*512+(i-1)],xn2);
      s_beta=o.beta; s_tau=o.tau; s_scal=o.scal; s_skip=o.skip;
      g_tauf[i]=o.tau;
    }
    __syncthreads();
    if (!s_skip){
      for (int c=i+1+tid;c<=n;c+=1024)
        g_A[(i-1)*512+(c-1)]=cmul(g_A[(i-1)*512+(c-1)],s_scal);
    }
    __syncthreads();
    if (!s_skip){
      cplx tau=s_tau;
      for (int r=i+1+wv;r<=m;r+=16){
        cplx acc=make_float2(0.f,0.f);
        for (int c=i+lane;c<=n;c+=64){
          cplx u=(c==i)?make_float2(1.f,0.f):g_A[(i-1)*512+(c-1)];
          acc=cadd(acc,cmul(g_A[(r-1)*512+(c-1)],u));
        }
        acc.x=wred(acc.x); acc.y=wred(acc.y);
        acc.x=__shfl(acc.x,0); acc.y=__shfl(acc.y,0);
        cplx tw=cmul(tau,acc);
        for (int c=i+lane;c<=n;c+=64){
          cplx u=(c==i)?make_float2(1.f,0.f):g_A[(i-1)*512+(c-1)];
          g_A[(r-1)*512+(c-1)]=csub(g_A[(r-1)*512+(c-1)],cmul(tw,conjc(u)));
        }
      }
    }
    __syncthreads();
    if (tid==0) g_A[(i-1)*512+(i-1)]=make_float2(s_beta,0.f);
    __syncthreads();
  }
}

__global__ void k_copyL(int m){
  int t=blockIdx.x*blockDim.x+threadIdx.x;
  if (t>=m*m) return;
  int r=t/m, c=t%m;
  g_B[r*512+c]=(c<=r)?g_A[r*512+c]:make_float2(0.f,0.f);
}
__global__ void k_copyM(){
  int t=blockIdx.x*blockDim.x+threadIdx.x;
  if (t<512*512) g_B[t]=g_A[t];
}
__global__ void k_copyR_b(){
  int t=blockIdx.x*blockDim.x+threadIdx.x;
  if (t>=512*512) return;
  int r=t/512, c=t%512;
  g_B[t]=(c>r)?g_A[t]:((c==r)?make_float2(g_betaq[r+1],0.f):make_float2(0.f,0.f));
}

__global__ __launch_bounds__(1024) void k_bd(int n){
  const int tid=threadIdx.x, lane=tid&63, wv=tid>>6;
  __shared__ float s_part[16];
  __shared__ cplx s_tau, s_scal;
  __shared__ float s_beta; __shared__ int s_skip;
  for (int i=1;i<=n;++i){
    float sq=0.f;
    for (int r=i+1+tid;r<=n;r+=1024){
      cplx a=g_B[(r-1)*512+(i-1)];
      sq=fmaf(a.x,a.x,fmaf(a.y,a.y,sq));
    }
    sq=wred(sq);
    if (lane==0) s_part[wv]=sq;
    __syncthreads();
    if (tid==0){
      float xn2=0.f; for (int w=0;w<16;w++) xn2+=s_part[w];
      RfgOut o=clarfg_head(g_B[(i-1)*512+(i-1)],xn2);
      s_beta=o.beta; s_tau=o.tau; s_scal=o.scal; s_skip=o.skip;
      g_d[i]=o.beta;
    }
    __syncthreads();
    if (!s_skip){
      for (int r=i+1+tid;r<=n;r+=1024)
        g_B[(r-1)*512+(i-1)]=cmul(g_B[(r-1)*512+(i-1)],s_scal);
    }
    __syncthreads();
    if (!s_skip){
      cplx tauc=conjc(s_tau);
      for (int c=i+1+wv;c<=n;c+=16){
        cplx acc=make_float2(0.f,0.f);
        for (int r=i+lane;r<=n;r+=64){
          cplx v=(r==i)?make_float2(1.f,0.f):g_B[(r-1)*512+(i-1)];
          acc=cadd(acc,cmulc(v,g_B[(r-1)*512+(c-1)]));
        }
        acc.x=wred(acc.x); acc.y=wred(acc.y);
        acc.x=__shfl(acc.x,0); acc.y=__shfl(acc.y,0);
        cplx tw=cmul(tauc,acc);
        for (int r=i+lane;r<=n;r+=64){
          cplx v=(r==i)?make_float2(1.f,0.f):g_B[(r-1)*512+(i-1)];
          g_B[(r-1)*512+(c-1)]=csub(g_B[(r-1)*512+(c-1)],cmul(tw,v));
        }
      }
    }
    __syncthreads();
    if (tid==0) g_B[(i-1)*512+(i-1)]=make_float2(s_beta,0.f);
    __syncthreads();
    if (i<n){
      for (int c=i+1+tid;c<=n;c+=1024) g_B[(i-1)*512+(c-1)].y=-g_B[(i-1)*512+(c-1)].y;
      __syncthreads();
      float sq2=0.f;
      for (int c=i+2+tid;c<=n;c+=1024){
        cplx a=g_B[(i-1)*512+(c-1)];
        sq2=fmaf(a.x,a.x,fmaf(a.y,a.y,sq2));
      }
      sq2=wred(sq2);
      if (lane==0) s_part[wv]=sq2;
      __syncthreads();
      if (tid==0){
        float xn2=0.f; for (int w=0;w<16;w++) xn2+=s_part[w];
        RfgOut o=clarfg_head(g_B[(i-1)*512+(i)],xn2);
        s_beta=o.beta; s_tau=o.tau; s_scal=o.scal; s_skip=o.skip;
        g_e[i]=o.beta; g_taup[i]=o.tau;
      }
      __syncthreads();
      if (!s_skip){
        for (int c=i+2+tid;c<=n;c+=1024)
          g_B[(i-1)*512+(c-1)]=cmul(g_B[(i-1)*512+(c-1)],s_scal);
      }
      __syncthreads();
      if (!s_skip){
        cplx tau=s_tau;
        for (int r=i+1+wv;r<=n;r+=16){
          cplx acc=make_float2(0.f,0.f);
          for (int c=i+1+lane;c<=n;c+=64){
            cplx v=(c==i+1)?make_float2(1.f,0.f):g_B[(i-1)*512+(c-1)];
            acc=cadd(acc,cmul(g_B[(r-1)*512+(c-1)],v));
          }
          acc.x=wred(acc.x); acc.y=wred(acc.y);
          acc.x=__shfl(acc.x,0); acc.y=__shfl(acc.y,0);
          cplx tw=cmul(tau,acc);
          for (int c=i+1+lane;c<=n;c+=64){
            cplx v=(c==i+1)?make_float2(1.f,0.f):g_B[(i-1)*512+(c-1)];
            g_B[(r-1)*512+(c-1)]=csub(g_B[(r-1)*512+(c-1)],cmul(tw,conjc(v)));
          }
        }
      }
      __syncthreads();
      for (int c=i+2+tid;c<=n;c+=1024) g_B[(i-1)*512+(c-1)].y=-g_B[(i-1)*512+(c-1)].y;
      if (tid==0) g_B[(i-1)*512+(i)]=make_float2(s_beta,0.f);
      __syncthreads();
    }
  }
}

__global__ __launch_bounds__(1024) void k_applyPH(int n){
  const int tid=threadIdx.x, lane=tid&63, wv=tid>>6;
  for (int i=n-1;i>=1;--i){
    cplx tau=g_taup[i];
    if (tau.x==0.f && tau.y==0.f) continue;
    cplx tauc=conjc(tau);
    for (int r=1+wv;r<=n;r+=16){
      cplx acc=make_float2(0.f,0.f);
      for (int c=i+1+lane;c<=n;c+=64){
        cplx v=(c==i+1)?make_float2(1.f,0.f):conjc(g_B[(i-1)*512+(c-1)]);
        acc=cadd(acc,cmul(g_VTc[(r-1)*512+(c-1)],v));
      }
      acc.x=wred(acc.x); acc.y=wred(acc.y);
      acc.x=__shfl(acc.x,0); acc.y=__shfl(acc.y,0);
      cplx tw=cmul(tauc,acc);
      for (int c=i+1+lane;c<=n;c+=64){
        cplx vb=(c==i+1)?make_float2(1.f,0.f):g_B[(i-1)*512+(c-1)];
        g_VTc[(r-1)*512+(c-1)]=csub(g_VTc[(r-1)*512+(c-1)],cmul(tw,vb));
      }
    }
    __syncthreads();
  }
}

__global__ __launch_bounds__(1024) void k_applyQlq(int m){
  const int tid=threadIdx.x, lane=tid&63, wv=tid>>6;
  for (int i=m;i>=1;--i){
    cplx tau=g_tauf[i];
    if (tau.x==0.f && tau.y==0.f) continue;
    cplx tauc=conjc(tau);
    for (int r=1+wv;r<=m;r+=16){
      cplx acc=make_float2(0.f,0.f);
      for (int c=i+lane;c<=512;c+=64){
        cplx u=(c==i)?make_float2(1.f,0.f):g_A[(i-1)*512+(c-1)];
        acc=cadd(acc,cmul(g_VTc[(r-1)*512+(c-1)],u));
      }
      acc.x=wred(acc.x); acc.y=wred(acc.y);
      acc.x=__shfl(acc.x,0); acc.y=__shfl(acc.y,0);
      cplx tw=cmul(tauc,acc);
      for (int c=i+lane;c<=512;c+=64){
        cplx u=(c==i)?make_float2(1.f,0.f):g_A[(i-1)*512+(c-1)];
        g_VTc[(r-1)*512+(c-1)]=csub(g_VTc[(r-1)*512+(c-1)],cmul(tw,conjc(u)));
      }
    }
    __syncthreads();
  }
}

// ---------------- persistent big-site kernels (verified phase bodies + new gbar) ----------------

// cgeqr2 on g_A (1024 x 512), all 512 reflectors in one launch.
__global__ __launch_bounds__(256) void pk_qr(){
  const int m=1024, n=512;
  const int gtid=blockIdx.x*256+threadIdx.x;
  const int lane=gtid&63, gw=gtid>>6;
  unsigned gen=gbar_init();
  { // prologue: col-1 tail norm (redundant per block; gtid 0 writes)
    __shared__ float sr[256];
    int t=threadIdx.x;
    float sq=0.f;
    for (int r=2+t;r<=1024;r+=256){ cplx a=g_A[(r-1)*512]; sq=fmaf(a.x,a.x,fmaf(a.y,a.y,sq)); }
    sr[t]=sq; __syncthreads();
    for (int s=128;s>0;s>>=1){ if (t<s) sr[t]+=sr[t+s]; __syncthreads(); }
    if (gtid==0) g_scq[1]=sr[0];
  }
  gbar(gen);
  for (int j=1;j<=n;++j){
    float xn2=g_scq[j];
    cplx alpha=g_A[(j-1)*512+(j-1)];
    RfgOut o=clarfg_head(alpha,xn2);
    if (gtid==0) g_betaq[j]=o.beta;
    cplx tauc=conjc(o.tau);
    float nsq=0.f;
    for (int c=j+1+gw;c<=n;c+=UW){
      cplx acc=make_float2(0.f,0.f);
      for (int r=j+lane;r<=m;r+=64){
        cplx v=(r==j)?make_float2(1.f,0.f):cmul(g_A[(r-1)*512+(j-1)],o.scal);
        acc=cadd(acc,cmulc(v,g_A[(r-1)*512+(c-1)]));
      }
      acc.x=wred(acc.x); acc.y=wred(acc.y);
      acc.x=__shfl(acc.x,0); acc.y=__shfl(acc.y,0);
      cplx tw=cmul(tauc,acc);
      for (int r=j+lane;r<=m;r+=64){
        cplx v=(r==j)?make_float2(1.f,0.f):cmul(g_A[(r-1)*512+(j-1)],o.scal);
        cplx nv=csub(g_A[(r-1)*512+(c-1)],cmul(tw,v));
        g_A[(r-1)*512+(c-1)]=nv;
        if (c==j+1 && r>=j+2) nsq=fmaf(nv.x,nv.x,fmaf(nv.y,nv.y,nsq));
      }
    }
    if (gw==0){
      nsq=wred(nsq);
      if (lane==0) g_scq[j+1]=nsq;
    }
    gbar(gen);
  }
}

// cgebd2 on g_B (512 x 512), all 1023 phases in one launch.
__global__ __launch_bounds__(256) void pk_bd(){
  const int n=512;
  const int gtid=blockIdx.x*256+threadIdx.x;
  const int lane=gtid&63, gw=gtid>>6;
  unsigned gen=gbar_init();
  // prologue: col-1 tail norm partials (512 threads worth -> blocks 0,1)
  if (blockIdx.x<2){
    int t=gtid;
    float sq=0.f;
    for (int r=2+t;r<=512;r+=512){ cplx a=g_B[(r-1)*512]; sq=fmaf(a.x,a.x,fmaf(a.y,a.y,sq)); }
    g_partR[t]=sq;
  }
  gbar(gen);
  for (int i=1;i<=n;++i){
    { // ---- column phase (u_bd_col body) ----
      float xn2c=reduce512(g_partR);
      cplx alpha=g_B[(i-1)*512+(i-1)];
      RfgOut oc=clarfg_head(alpha,xn2c);
      if (gtid==0) g_d[i]=oc.beta;
      cplx tauc=conjc(oc.tau);
      float nsqA=0.f;
      for (int c=i+1+gw;c<=n;c+=UW){
        cplx acc=make_float2(0.f,0.f);
        for (int r=i+lane;r<=n;r+=64){
          cplx v=(r==i)?make_float2(1.f,0.f):cmul(g_B[(r-1)*512+(i-1)],oc.scal);
          acc=cadd(acc,cmulc(v,g_B[(r-1)*512+(c-1)]));
        }
        acc.x=wred(acc.x); acc.y=wred(acc.y);
        acc.x=__shfl(acc.x,0); acc.y=__shfl(acc.y,0);
        cplx tw=cmul(tauc,acc);
        for (int r=i+lane;r<=n;r+=64){
          cplx v=(r==i)?make_float2(1.f,0.f):cmul(g_B[(r-1)*512+(i-1)],oc.scal);
          cplx nv=csub(g_B[(r-1)*512+(c-1)],cmul(tw,v));
          g_B[(r-1)*512+(c-1)]=nv;
          if (r==i && c>=i+2) nsqA=fmaf(nv.x,nv.x,fmaf(nv.y,nv.y,nsqA));
        }
      }
      if (lane==0) g_partC[gw]=nsqA;
    }
    gbar(gen);
    if (i==n) break;
    { // ---- row phase (u_bd_row body) ----
      float xn2r=reduce512(g_partC);
      cplx alphar=conjc(g_B[(i-1)*512+(i)]);
      RfgOut orr=clarfg_head(alphar,xn2r);
      if (gtid==0){ g_e[i]=orr.beta; g_taup[i]=orr.tau; g_rn[i]=xn2r; }
      float nsqB=0.f;
      for (int r=i+1+gw;r<=n;r+=UW){
        cplx acc=make_float2(0.f,0.f);
        for (int c=i+1+lane;c<=n;c+=64){
          cplx v=(c==i+1)?make_float2(1.f,0.f):cmul(conjc(g_B[(i-1)*512+(c-1)]),orr.scal);
          acc=cadd(acc,cmul(g_B[(r-1)*512+(c-1)],v));
        }
        acc.x=wred(acc.x); acc.y=wred(acc.y);
        acc.x=__shfl(acc.x,0); acc.y=__shfl(acc.y,0);
        cplx tw=cmul(orr.tau,acc);
        for (int c=i+1+lane;c<=n;c+=64){
          cplx v=(c==i+1)?make_float2(1.f,0.f):cmul(conjc(g_B[(i-1)*512+(c-1)]),orr.scal);
          cplx nv=csub(g_B[(r-1)*512+(c-1)],cmul(tw,conjc(v)));
          g_B[(r-1)*512+(c-1)]=nv;
          if (c==i+1 && r>=i+2) nsqB=fmaf(nv.x,nv.x,fmaf(nv.y,nv.y,nsqB));
        }
      }
      if (lane==0) g_partR[gw]=nsqB;
    }
    gbar(gen);
  }
}

// big-site P^H chain: VTc (512x512) <- VTc * prod_{i=511..1} G_i^H.
// 128 blocks x 4 waves, one VTc row per wave.
__global__ __launch_bounds__(256) void u_ph(){
  const int n=512;
  int b=blockIdx.x;
  int wv=threadIdx.x>>6, lane=threadIdx.x&63;
  int r=b*4+wv+1;   // 1-based row, 512 rows over 512 waves
  for (int i=n-1;i>=1;--i){
    cplx alphar=conjc(g_B[(i-1)*512+(i)]);
    RfgOut o=clarfg_head(alphar,g_rn[i]);
    if (o.skip) continue;
    cplx tauc=conjc(o.tau);
    cplx acc=make_float2(0.f,0.f);
    for (int c=i+1+lane;c<=n;c+=64){
      cplx v=(c==i+1)?make_float2(1.f,0.f):cmul(conjc(g_B[(i-1)*512+(c-1)]),o.scal);
      acc=cadd(acc,cmul(g_VTc[(r-1)*512+(c-1)],v));
    }
    acc.x=wred(acc.x); acc.y=wred(acc.y);
    acc.x=__shfl(acc.x,0); acc.y=__shfl(acc.y,0);
    cplx tw=cmul(tauc,acc);
    for (int c=i+1+lane;c<=n;c+=64){
      cplx v=(c==i+1)?make_float2(1.f,0.f):cmul(conjc(g_B[(i-1)*512+(c-1)]),o.scal);
      g_VTc[(r-1)*512+(c-1)]=csub(g_VTc[(r-1)*512+(c-1)],cmul(tw,conjc(v)));
    }
  }
}

// ---------------- glue kernels ----------------
__global__ void k_formR(int kk){
  int t=blockIdx.x*blockDim.x+threadIdx.x;
  if (t>=kk*512) return;
  float s=g_sig[t/512];
  cplx v=g_VTc[t];
  g_R[t]=make_float2(s*v.x,s*v.y);
}

__global__ void k_next(const float* __restrict__ tmid, int site){
  int row=blockIdx.x;
  int a=row>>1, s=row&1;
  int b=blockIdx.y*blockDim.x+threadIdx.x;
  const float* base=tmid+(size_t)site*512*2*512*2;
  cplx acc=make_float2(0.f,0.f);
  for (int c=0;c<512;++c){
    cplx r=g_R[a*512+c];
    size_t off=((((size_t)c)*2+s)*512+b)*2;
    cplx x=make_float2(base[off],base[off+1]);
    acc=cadd(acc,cmul(r,x));
  }
  g_A[row*512+b]=acc;
}

__global__ void k_final(const float* __restrict__ tlast, float* __restrict__ out){
  int a=blockIdx.x*blockDim.x+threadIdx.x;
  if (a>=512) return;
  for (int s=0;s<2;++s){
    cplx acc=make_float2(0.f,0.f);
    for (int c=0;c<512;++c){
      cplx r=g_R[a*512+c];
      cplx x=make_float2(tlast[(c*2+s)*2],tlast[(c*2+s)*2+1]);
      acc=cadd(acc,cmul(r,x));
    }
    out[a*4+s*2+0]=acc.x;
    out[a*4+s*2+1]=acc.y;
  }
}

extern "C" void kernel_launch(void* const* d_in, const int* in_sizes, int n_in,
                              void* d_out, int out_size, void* d_ws, size_t ws_size,
                              hipStream_t stream) {
  const float* t_first=(const float*)d_in[0];
  const float* t_mid  =(const float*)d_in[1];
  const float* t_last =(const float*)d_in[2];
  float* out=(float*)d_out;
  (void)in_sizes; (void)n_in; (void)d_ws; (void)ws_size; (void)out_size;

  k_m0<<<dim3(4),256,0,stream>>>(t_first);

  int rows=2;
  for (int site=0;site<23;++site){
    int mm=rows;
    int nb=(mm<512)?mm:512;
    if (mm<512){
      // small sites: round-2 verified single-block path
      k_lq<<<1,1024,0,stream>>>(mm);
      k_copyL<<<dim3((mm*mm+255)/256),256,0,stream>>>(mm);
      k_bd<<<1,1024,0,stream>>>(mm);
      k_sbdsdc<<<1,1024,0,stream>>>(mm);
      k_applyPH<<<1,1024,0,stream>>>(mm);
      k_applyQlq<<<1,1024,0,stream>>>(mm);
    } else {
      if (mm==512){
        k_copyM<<<dim3((512*512+255)/256),256,0,stream>>>();
      } else {
        pk_qr<<<UBLK,256,0,stream>>>();
        k_copyR_b<<<dim3((512*512+255)/256),256,0,stream>>>();
      }
      pk_bd<<<UBLK,256,0,stream>>>();
      k_sbdsdc<<<1,1024,0,stream>>>(512);
      u_ph<<<UBLK,256,0,stream>>>();
    }
    k_formR<<<dim3((nb*512+255)/256),256,0,stream>>>(nb);
    if (site<22){
      k_next<<<dim3(2*nb,2),256,0,stream>>>(t_mid,site);
      rows=2*nb;
    } else {
      k_final<<<dim3(2),256,0,stream>>>(t_last,out);
    }
  }
}

// Round 10
// 1058147.656 us; speedup vs baseline: 1.4812x; 1.3336x over previous
//
#include <hip/hip_runtime.h>
#include <math.h>

// MPS center-orthogonalization sweep (CHI=512, Q=2, NQUBIT=24, complex64).
// Faithful GPU port of the Vh/S side of LAPACK cgesdd (jobz='S') over 23
// sites.  Round 10 = R6 (measured best, 1.080s, launch-per-phase) with sync
// COUNT reduced (~22.7k -> ~12.6k launches):
//  - QR: LDS-resident 16-column panels (p_qr16, 1 block, intra-block syncs
//    only) + 16-deep chained apply (p_apply16, 128 blocks).  R5-verified
//    panel/apply semantics (raw storage, clarfg recompute, g_scq chain).
//  - BD: steps 385..512 (trailing 128x128, fits LDS) fused into one
//    single-block kernel (u_bd_tail_lds), R5-verified tail arithmetic.
//  - Everything else byte-identical to R6.

#define LDV 513
typedef float2 cplx;

__device__ __forceinline__ cplx cmul(cplx a, cplx b){ return make_float2(a.x*b.x - a.y*b.y, a.x*b.y + a.y*b.x); }
__device__ __forceinline__ cplx cmulc(cplx a, cplx b){ /*conj(a)*b*/ return make_float2(a.x*b.x + a.y*b.y, a.x*b.y - a.y*b.x); }
__device__ __forceinline__ cplx cadd(cplx a, cplx b){ return make_float2(a.x+b.x, a.y+b.y); }
__device__ __forceinline__ cplx csub(cplx a, cplx b){ return make_float2(a.x-b.x, a.y-b.y); }
__device__ __forceinline__ cplx conjc(cplx a){ return make_float2(a.x, -a.y); }

#define EPS_S 5.9604645e-8f
#define UNFL_S 1.17549435e-38f
#define UW 512    // waves in hot update grid (128 blocks x 256 thr)
#define UBLK 128
#define PNB 16    // QR panel width
#define PLS 17    // panel LDS row stride (cplx) - bank-conflict pad
#define TI0 385   // BD LDS tail start (trailing 128)
#define TN 128
#define TLS 129   // tail LDS row stride (cplx)

// ---------------- device global workspace ----------------
__device__ cplx g_A[1024*512];     // current M / QR-LQ factors (raw)
__device__ cplx g_B[512*512];      // square matrix for bidiagonalization (raw)
__device__ cplx g_VTc[512*512];    // complex VT being assembled
__device__ cplx g_R[512*512];      // bond matrix R = diag(s)*VT
__device__ cplx g_tauf[520];       // LQ taus (small path)
__device__ cplx g_taup[520];       // cgebd2 row taus
__device__ float g_d[520], g_e[520];
__device__ float g_VTr[LDV*LDV];
__device__ float g_VT2[LDV*LDV];
__device__ float g_W[LDV*LDV];
__device__ float g_z[520], g_zz[520], g_zorig[520], g_dtmp[520], g_ztmp[520], g_dsig[520];
__device__ double g_root[520];
__device__ int g_idxq[520], g_idx[520], g_idxp[520], g_rowmap[520];
__device__ int g_inode[80], g_ndiml[80], g_ndimr[80];
__device__ float g_sig[520];
__device__ int g_K, g_nlvl_, g_nd_;
__device__ float g_tol_, g_z1_;
__device__ double g_rho_;
// big-path chain scalars
__device__ float g_scq[520];       // QR column-tail norms
__device__ float g_betaq[520];     // QR betas (R diagonal)
__device__ float g_rn[520];        // BD row-reflector tail norms (u_ph recompute)
__device__ float g_partC[UW];      // BD col-phase per-wave partials
__device__ float g_partR[UW];      // BD row-phase / prologue partials

// ---------------- reduce helpers ----------------
__device__ __forceinline__ float wred(float v){
  for (int off=32;off;off>>=1) v+=__shfl_down(v,off);
  return v;
}
// deterministic 512-entry reduce done identically in every block (256 thr)
__device__ __forceinline__ float reduce512(const float* arr){
  __shared__ float sr[256];
  sr[threadIdx.x]=arr[threadIdx.x]+arr[threadIdx.x+256];
  __syncthreads();
  for (int s=128;s>0;s>>=1){
    if (threadIdx.x<s) sr[threadIdx.x]+=sr[threadIdx.x+s];
    __syncthreads();
  }
  float v=sr[0];
  __syncthreads();
  return v;
}

// ---------------- clarfg (LAPACK conventions) ----------------
struct RfgOut { float beta; cplx tau; cplx scal; int skip; };
__device__ RfgOut clarfg_head(cplx alpha, float xn2){
  RfgOut o;
  if (xn2==0.f && alpha.y==0.f){
    o.beta=alpha.x; o.tau=make_float2(0.f,0.f); o.scal=make_float2(0.f,0.f); o.skip=1;
  } else {
    float anorm=sqrtf(alpha.x*alpha.x+alpha.y*alpha.y+xn2);
    float beta=(alpha.x>=0.f)?-anorm:anorm;
    o.beta=beta;
    o.tau=make_float2((beta-alpha.x)/beta,-alpha.y/beta);
    cplx dd=make_float2(alpha.x-beta,alpha.y);
    float dn=dd.x*dd.x+dd.y*dd.y;
    o.scal=make_float2(dd.x/dn,-dd.y/dn);
    o.skip=0;
  }
  return o;
}

// ---------------- small serial real-LAPACK helpers (round-2 verbatim) ----------------
__device__ float slapy2(float x, float y){
  float xa=fabsf(x), ya=fabsf(y);
  float w=fmaxf(xa,ya), z=fminf(xa,ya);
  if (z==0.f) return w;
  float q=z/w; return w*sqrtf(1.f+q*q);
}

__device__ void slartg(float f, float g, float* cs, float* sn, float* r){
  if (g==0.f){ *cs=1.f; *sn=0.f; *r=f; }
  else if (f==0.f){ *cs=0.f; *sn=(g>0.f)?1.f:-1.f; *r=fabsf(g); }
  else {
    float f1=fabsf(f);
    float d=sqrtf(f*f+g*g);
    *cs = f1/d;
    *r = (f>0.f)? d : -d;
    *sn = g / *r;
  }
}

__device__ void slas2(float f, float g, float h, float* ssmin, float* ssmax){
  float fa=fabsf(f), ga=fabsf(g), ha=fabsf(h);
  float fhmn=fminf(fa,ha), fhmx=fmaxf(fa,ha);
  if (fhmn==0.f){
    *ssmin=0.f;
    if (fhmx==0.f) *ssmax=ga;
    else { float mx=fmaxf(fhmx,ga), mn=fminf(fhmx,ga); float q=mn/mx; *ssmax=mx*sqrtf(1.f+q*q); }
  } else {
    if (ga < fhmx){
      float as=1.f+fhmn/fhmx, at=(fhmx-fhmn)/fhmx;
      float au=ga/fhmx; au=au*au;
      float c=2.f/(sqrtf(as*as+au)+sqrtf(at*at+au));
      *ssmin=fhmn*c; *ssmax=fhmx/c;
    } else {
      float au=fhmx/ga;
      if (au==0.f){ *ssmin=(fhmn*fhmx)/ga; *ssmax=ga; }
      else {
        float as=1.f+fhmn/fhmx, at=(fhmx-fhmn)/fhmx;
        float c=1.f/(sqrtf(1.f+(as*au)*(as*au))+sqrtf(1.f+(at*au)*(at*au)));
        *ssmin=(fhmn*c)*au; *ssmin=*ssmin+*ssmin;
        *ssmax=ga/(c+c);
      }
    }
  }
}

__device__ void slasv2(float f, float g, float h, float* ssmin, float* ssmax,
                       float* snr, float* csr, float* snl, float* csl){
  float ft=f, fa=fabsf(f), ht=h, ha=fabsf(h);
  int pmax=1;
  bool swap_=(ha>fa);
  if (swap_){ pmax=3; float t=ft; ft=ht; ht=t; t=fa; fa=ha; ha=t; }
  float gt=g, ga=fabsf(g);
  float clt=0.f, crt=0.f, slt=0.f, srt=0.f;
  if (ga==0.f){ *ssmin=ha; *ssmax=fa; clt=1.f; crt=1.f; slt=0.f; srt=0.f; }
  else {
    bool gasmal=true;
    if (ga>fa){
      pmax=2;
      if ((fa/ga) < EPS_S){
        gasmal=false;
        *ssmax=ga;
        if (ha>1.f) *ssmin=fa/(ga/ha); else *ssmin=(fa/ga)*ha;
        clt=1.f; slt=ht/gt; srt=1.f; crt=ft/gt;
      }
    }
    if (gasmal){
      float d=fa-ha;
      float l=(d==fa)?1.f:(d/fa);
      float mm=gt/ft;
      float t=2.f-l;
      float mm2=mm*mm, tt=t*t;
      float s=sqrtf(tt+mm2);
      float r=(l==0.f)?fabsf(mm):sqrtf(l*l+mm2);
      float a=0.5f*(s+r);
      *ssmin=ha/a; *ssmax=fa*a;
      if (mm2==0.f){
        if (l==0.f) t=copysignf(2.f,ft)*copysignf(1.f,gt);
        else t=gt/copysignf(d,ft)+mm/t;
      } else {
        t=(mm/(s+t)+mm/(r+l))*(1.f+a);
      }
      float l2=sqrtf(t*t+4.f);
      crt=2.f/l2; srt=t/l2;
      clt=(crt+srt*mm)/a;
      slt=(ht/ft)*srt/a;
    }
  }
  if (swap_){ *csl=srt; *snl=crt; *csr=slt; *snr=clt; }
  else      { *csl=clt; *snl=slt; *csr=crt; *snr=srt; }
  float tsign=0.f;
  if (pmax==1) tsign=copysignf(1.f,*csr)*copysignf(1.f,*csl)*copysignf(1.f,f);
  if (pmax==2) tsign=copysignf(1.f,*snr)*copysignf(1.f,*csl)*copysignf(1.f,g);
  if (pmax==3) tsign=copysignf(1.f,*snr)*copysignf(1.f,*snl)*copysignf(1.f,h);
  *ssmax=copysignf(*ssmax,tsign);
  *ssmin=copysignf(*ssmin,tsign*copysignf(1.f,f)*copysignf(1.f,h));
}

__device__ void slasr_f(int mrows, int ncols, const float* c1, const float* s1, float* a, int lda){
  for (int j=1;j<=mrows-1;++j){
    float ct=c1[j], st=s1[j];
    if (ct!=1.f || st!=0.f){
      float* rj=&a[(j-1)*lda]; float* rj1=&a[j*lda];
      for (int i=0;i<ncols;++i){
        float tmp=rj1[i];
        rj1[i]=ct*tmp-st*rj[i];
        rj[i]=st*tmp+ct*rj[i];
      }
    }
  }
}
__device__ void slasr_b(int mrows, int ncols, const float* c1, const float* s1, float* a, int lda){
  for (int j=mrows-1;j>=1;--j){
    float ct=c1[j], st=s1[j];
    if (ct!=1.f || st!=0.f){
      float* rj=&a[(j-1)*lda]; float* rj1=&a[j*lda];
      for (int i=0;i<ncols;++i){
        float tmp=rj1[i];
        rj1[i]=ct*tmp-st*rj[i];
        rj[i]=st*tmp+ct*rj[i];
      }
    }
  }
}

// serial SBDSQR('U', n, ncvt, 0, 0) — VT only.
__device__ void sbdsqr_u(int n, int ncvt, float* d, float* e, float* vt, int ldvt){
  const int MAXITR=6;
  if (n==0) return;
  if (n>1){
    int nm1=n-1, nm12=nm1+nm1, nm13=nm12+nm1;
    float wk[112];
    float tolmul=10.f;
    float tol=tolmul*EPS_S;
    float smax=0.f;
    for (int i=1;i<=n;i++) smax=fmaxf(smax,fabsf(d[i]));
    for (int i=1;i<=n-1;i++) smax=fmaxf(smax,fabsf(e[i]));
    float sminl=0.f, thresh;
    {
      float sminoa=fabsf(d[1]);
      if (sminoa!=0.f){
        float mu=sminoa;
        for (int i=2;i<=n;i++){
          mu=fabsf(d[i])*(mu/(mu+fabsf(e[i-1])));
          sminoa=fminf(sminoa,mu);
          if (sminoa==0.f) break;
        }
      }
      sminoa=sminoa/sqrtf((float)n);
      thresh=fmaxf(tol*sminoa,(float)(MAXITR*n*n)*UNFL_S);
    }
    int M=n, iter=0, maxit=MAXITR*n*n;
    int oldll=-1, oldm=-1, idir=0;
    while (1){
      if (M<=1) break;
      if (iter>maxit) break;
      int ll=0; bool split=false;
      smax=fabsf(d[M]);
      for (int lll=1;lll<=M-1;++lll){
        ll=M-lll;
        float abss=fabsf(d[ll]), abse=fabsf(e[ll]);
        if (abse<=thresh){ split=true; break; }
        smax=fmaxf(smax,fmaxf(abss,abse));
      }
      if (!split) ll=0;
      else {
        e[ll]=0.f;
        if (ll==M-1){ M=M-1; continue; }
      }
      ll=ll+1;
      if (ll==M-1){
        float sigmn,sigmx,sinr,cosr,sinl,cosl;
        slasv2(d[M-1],e[M-1],d[M],&sigmn,&sigmx,&sinr,&cosr,&sinl,&cosl);
        d[M-1]=sigmx; e[M-1]=0.f; d[M]=sigmn;
        if (ncvt>0){
          float* x=&vt[(M-2)*ldvt]; float* y=&vt[(M-1)*ldvt];
          for (int c=0;c<ncvt;c++){ float xv=x[c],yv=y[c]; x[c]=cosr*xv+sinr*yv; y[c]=cosr*yv-sinr*xv; }
        }
        M-=2; continue;
      }
      if (ll>oldm || M<oldll) idir=(fabsf(d[ll])>=fabsf(d[M]))?1:2;
      bool conv=false;
      if (idir==1){
        if (fabsf(e[M-1])<=fabsf(tol)*fabsf(d[M])){ e[M-1]=0.f; conv=true; }
        else {
          float mu=fabsf(d[ll]); sminl=mu;
          for (int lll=ll;lll<=M-1;++lll){
            if (fabsf(e[lll])<=tol*mu){ e[lll]=0.f; conv=true; break; }
            mu=fabsf(d[lll+1])*(mu/(mu+fabsf(e[lll])));
            sminl=fminf(sminl,mu);
          }
        }
      } else {
        if (fabsf(e[ll])<=fabsf(tol)*fabsf(d[ll])){ e[ll]=0.f; conv=true; }
        else {
          float mu=fabsf(d[M]); sminl=mu;
          for (int lll=M-1;lll>=ll;--lll){
            if (fabsf(e[lll])<=tol*mu){ e[lll]=0.f; conv=true; break; }
            mu=fabsf(d[lll])*(mu/(mu+fabsf(e[lll])));
            sminl=fminf(sminl,mu);
          }
        }
      }
      if (conv) continue;
      oldll=ll; oldm=M;
      float shift=0.f, rr;
      if ((float)n*tol*(sminl/smax)<=fmaxf(EPS_S,0.01f*tol)) shift=0.f;
      else {
        float sll;
        if (idir==1){ sll=fabsf(d[ll]); slas2(d[M-1],e[M-1],d[M],&shift,&rr); }
        else        { sll=fabsf(d[M]);  slas2(d[ll],e[ll],d[ll+1],&shift,&rr); }
        if (sll>0.f){ float q=shift/sll; if (q*q<EPS_S) shift=0.f; }
      }
      iter += M-ll;
      if (shift==0.f){
        if (idir==1){
          float cs=1.f, oldcs=1.f, sn=0.f, oldsn=0.f;
          for (int i=ll;i<=M-1;++i){
            float c2,r1;
            slartg(d[i]*cs,e[i],&c2,&sn,&r1); cs=c2;
            if (i>ll) e[i-1]=oldsn*r1;
            float oc2;
            slartg(oldcs*r1,d[i+1]*sn,&oc2,&oldsn,&d[i]); oldcs=oc2;
            wk[i-ll+1]=cs; wk[i-ll+1+nm1]=sn;
          }
          float h=d[M]*cs; d[M]=h*oldcs; e[M-1]=h*oldsn;
          if (ncvt>0) slasr_f(M-ll+1,ncvt,wk,wk+nm1,&vt[(ll-1)*ldvt],ldvt);
          if (fabsf(e[M-1])<=thresh) e[M-1]=0.f;
        } else {
          float cs=1.f, oldcs=1.f, sn=0.f, oldsn=0.f;
          for (int i=M;i>=ll+1;--i){
            float c2,r1;
            slartg(d[i]*cs,e[i-1],&c2,&sn,&r1); cs=c2;
            if (i<M) e[i]=oldsn*r1;
            float oc2;
            slartg(oldcs*r1,d[i-1]*sn,&oc2,&oldsn,&d[i]); oldcs=oc2;
            wk[i-ll]=cs; wk[i-ll+nm1]=-sn;
            wk[i-ll+nm12]=oldcs; wk[i-ll+nm13]=-oldsn;
          }
          float h=d[ll]*cs; d[ll]=h*oldcs; e[ll]=h*oldsn;
          if (ncvt>0) slasr_b(M-ll+1,ncvt,wk+nm12,wk+nm13,&vt[(ll-1)*ldvt],ldvt);
          if (fabsf(e[ll])<=thresh) e[ll]=0.f;
        }
      } else {
        if (idir==1){
          float f=(fabsf(d[ll])-shift)*(copysignf(1.f,d[ll])+shift/d[ll]);
          float g=e[ll], cosr,sinr,cosl,sinl,r1;
          for (int i=ll;i<=M-1;++i){
            slartg(f,g,&cosr,&sinr,&r1);
            if (i>ll) e[i-1]=r1;
            f=cosr*d[i]+sinr*e[i];
            e[i]=cosr*e[i]-sinr*d[i];
            g=sinr*d[i+1];
            d[i+1]=cosr*d[i+1];
            slartg(f,g,&cosl,&sinl,&r1);
            d[i]=r1;
            f=cosl*e[i]+sinl*d[i+1];
            d[i+1]=cosl*d[i+1]-sinl*e[i];
            if (i<M-1){ g=sinl*e[i+1]; e[i+1]=cosl*e[i+1]; }
            wk[i-ll+1]=cosr; wk[i-ll+1+nm1]=sinr;
            wk[i-ll+1+nm12]=cosl; wk[i-ll+1+nm13]=sinl;
          }
          e[M-1]=f;
          if (ncvt>0) slasr_f(M-ll+1,ncvt,wk,wk+nm1,&vt[(ll-1)*ldvt],ldvt);
          if (fabsf(e[M-1])<=thresh) e[M-1]=0.f;
        } else {
          float f=(fabsf(d[M])-shift)*(copysignf(1.f,d[M])+shift/d[M]);
          float g=e[M-1], cosr,sinr,cosl,sinl,r1;
          for (int i=M;i>=ll+1;--i){
            slartg(f,g,&cosr,&sinr,&r1);
            if (i<M) e[i]=r1;
            f=cosr*d[i]+sinr*e[i-1];
            e[i-1]=cosr*e[i-1]-sinr*d[i];
            g=sinr*d[i-1];
            d[i-1]=cosr*d[i-1];
            slartg(f,g,&cosl,&sinl,&r1);
            d[i]=r1;
            f=cosl*e[i-1]+sinl*d[i-1];
            d[i-1]=cosl*d[i-1]-sinl*e[i-1];
            if (i>ll+1){ g=sinl*e[i-2]; e[i-2]=cosl*e[i-2]; }
            wk[i-ll]=cosr; wk[i-ll+nm1]=-sinr;
            wk[i-ll+nm12]=cosl; wk[i-ll+nm13]=-sinl;
          }
          e[ll]=f;
          if (fabsf(e[ll])<=thresh) e[ll]=0.f;
          if (ncvt>0) slasr_b(M-ll+1,ncvt,wk+nm12,wk+nm13,&vt[(ll-1)*ldvt],ldvt);
        }
      }
    }
  }
  for (int i=1;i<=n;i++){
    if (d[i]<0.f){
      d[i]=-d[i];
      if (ncvt>0){ float* row=&vt[(i-1)*ldvt]; for (int c=0;c<ncvt;c++) row[c]=-row[c]; }
    }
  }
  for (int i=1;i<=n-1;i++){
    int isub=1; float smin2=d[1];
    for (int j=2;j<=n+1-i;j++){ if (d[j]<=smin2){ isub=j; smin2=d[j]; } }
    if (isub!=n+1-i){
      d[isub]=d[n+1-i]; d[n+1-i]=smin2;
      if (ncvt>0){
        float* a=&vt[(isub-1)*ldvt]; float* b=&vt[(n-i)*ldvt];
        for (int c=0;c<ncvt;c++){ float t=a[c]; a[c]=b[c]; b[c]=t; }
      }
    }
  }
}

__device__ void slasdq_u(int sqre, int n, int ncvt, float* d, float* e, float* vt, int ldvt){
  if (n==0) return;
  float cwk[33], swk[33];
  int np1=n+1;
  if (sqre==1){
    for (int i=1;i<=n-1;i++){
      float cs,sn,r; slartg(d[i],e[i],&cs,&sn,&r);
      d[i]=r; e[i]=sn*d[i+1]; d[i+1]=cs*d[i+1];
      cwk[i]=cs; swk[i]=sn;
    }
    { float cs,sn,r; slartg(d[n],e[n],&cs,&sn,&r);
      d[n]=r; e[n]=0.f; cwk[n]=cs; swk[n]=sn; }
    if (ncvt>0) slasr_f(np1,ncvt,cwk,swk,vt,ldvt);
    for (int i=1;i<=n-1;i++){
      float cs,sn,r; slartg(d[i],e[i],&cs,&sn,&r);
      d[i]=r; e[i]=sn*d[i+1]; d[i+1]=cs*d[i+1];
    }
  }
  sbdsqr_u(n,ncvt,d,e,vt,ldvt);
  for (int i=1;i<=n;i++){
    int isub=i; float smin2=d[i];
    for (int j=i+1;j<=n;j++){ if (d[j]<smin2){ isub=j; smin2=d[j]; } }
    if (isub!=i){
      d[isub]=d[i]; d[i]=smin2;
      if (ncvt>0){
        float* a=&vt[(isub-1)*ldvt]; float* b=&vt[(i-1)*ldvt];
        for (int c=0;c<ncvt;c++){ float t=a[c]; a[c]=b[c]; b[c]=t; }
      }
    }
  }
}

__device__ void slamrg(int n1, int n2, const float* a, int s1, int s2, int* idx){
  int n1sv=n1, n2sv=n2, i=1;
  int ind1=(s1>0)?1:n1;
  int ind2=(s2>0)?(1+n1):(n1+n2);
  while (n1sv>0 && n2sv>0){
    if (a[ind1]<=a[ind2]){ idx[i++]=ind1; ind1+=s1; n1sv--; }
    else { idx[i++]=ind2; ind2+=s2; n2sv--; }
  }
  if (n1sv==0){ for(;n2sv>0;n2sv--){ idx[i++]=ind2; ind2+=s2; } }
  else { for(;n1sv>0;n1sv--){ idx[i++]=ind1; ind1+=s1; } }
}

__device__ void slasdt(int n, int* lvl, int* nd, int* inode, int* ndiml, int* ndimr, int msub){
  int maxn=(n>1)?n:1;
  float temp=logf((float)maxn/(float)(msub+1))/logf(2.f);
  *lvl=(int)temp+1;
  int i=n/2;
  inode[1]=i+1; ndiml[1]=i; ndimr[1]=n-i-1;
  int il=0, ir=1, llst=1;
  for (int nl=1;nl<=*lvl-1;++nl){
    for (int j=0;j<=llst-1;++j){
      il+=2; ir+=2;
      int nc=llst+j;
      ndiml[il]=ndiml[nc]/2;
      ndimr[il]=ndiml[nc]-ndiml[il]-1;
      inode[il]=inode[nc]-ndimr[il]-1;
      ndiml[ir]=ndimr[nc]/2;
      ndimr[ir]=ndimr[nc]-ndiml[ir]-1;
      inode[ir]=inode[nc]+ndiml[ir]+1;
    }
    llst*=2;
  }
  *nd=llst*2-1;
}

// ---------------- block-cooperative slasd1 (round-2 verbatim) ----------------
__device__ void merge_node(int nl, int nr, int sqre, float* d, int* idxq,
                           float alpha, float beta, float* VT, int ld)
{
  const int tid=threadIdx.x, nth=blockDim.x;
  const int n=nl+nr+1, m=n+sqre, nlp1=nl+1, nlp2=nl+2;
  if (tid==0){
    float* z=g_z;
    float z1=alpha*VT[(nlp1-1)*ld+(nlp1-1)];
    z[1]=z1; g_z1_=z1;
    for (int i=nl;i>=1;--i){
      z[i+1]=alpha*VT[(i-1)*ld+(nlp1-1)];
      d[i+1]=d[i];
      idxq[i+1]=idxq[i]+1;
    }
    for (int i=nlp2;i<=m;++i) z[i]=beta*VT[(i-1)*ld+(nlp2-1)];
    d[1]=0.f;
    for (int i=nlp2;i<=n;++i) idxq[i]+=nlp1;
    for (int i=2;i<=n;++i){ g_dtmp[i]=d[idxq[i]]; g_ztmp[i]=z[idxq[i]]; }
    slamrg(nl,nr,g_dtmp+1,1,1,g_idx+1);
    for (int i=2;i<=n;++i){
      int idxi=1+g_idx[i];
      d[i]=g_dtmp[idxi];
      z[i]=g_ztmp[idxi];
    }
    float tol=fmaxf(fabsf(alpha),fabsf(beta));
    tol=8.f*EPS_S*fmaxf(fabsf(d[n]),tol);
    g_tol_=tol;
    int K=1, K2=n+1, jprev=0, j;
    for (j=2;j<=n;++j){
      if (fabsf(z[j])<=tol){
        K2--; g_idxp[K2]=j;
        if (j==n){ jprev=0; break; }
      } else { jprev=j; break; }
    }
    if (jprev>0){
      j=jprev;
      for (;;){
        j++;
        if (j>n) break;
        if (fabsf(z[j])<=tol){ K2--; g_idxp[K2]=j; }
        else {
          if (fabsf(d[j]-d[jprev])<=tol){
            float s_=z[jprev], c_=z[j];
            float tau_=slapy2(c_,s_);
            c_/=tau_; s_=-s_/tau_;
            z[j]=tau_; z[jprev]=0.f;
            int idxjp=idxq[g_idx[jprev]+1];
            int idxj =idxq[g_idx[j]+1];
            if (idxjp<=nlp1) idxjp--;
            if (idxj <=nlp1) idxj--;
            float* xr=&VT[(idxjp-1)*ld];
            float* yr=&VT[(idxj-1)*ld];
            for (int cc=0;cc<m;++cc){
              float xv=xr[cc], yv=yr[cc];
              xr[cc]=c_*xv+s_*yv;
              yr[cc]=c_*yv-s_*xv;
            }
            K2--; g_idxp[K2]=jprev;
            jprev=j;
          } else {
            K++; g_zz[K]=z[jprev]; g_idxp[K]=jprev;
            jprev=j;
          }
        }
      }
      K++; g_zz[K]=z[jprev]; g_idxp[K]=jprev;
    }
    g_K=K;
    for (int jj=2;jj<=n;++jj){
      g_dsig[jj]=d[g_idxp[jj]];
      int rm=idxq[g_idx[g_idxp[jj]]+1];
      if (rm<=nlp1) rm--;
      g_rowmap[jj]=rm;
    }
  }
  __syncthreads();
  int K=g_K;
  for (int t=tid;t<(n-1)*m;t+=nth){
    int jj=2+t/m, cc=t%m;
    g_VT2[(jj-1)*LDV+cc]=VT[(g_rowmap[jj]-1)*ld+cc];
  }
  __syncthreads();
  if (tid==0){
    float tol=g_tol_;
    g_dsig[1]=0.f;
    float hlftol=tol*0.5f;
    if (fabsf(g_dsig[2])<=hlftol) g_dsig[2]=hlftol;
    float z1=g_z1_;
    float c_=1.f, s_=0.f;
    if (m>n){
      float t1=slapy2(z1,g_z[m]);
      if (t1<=tol){ c_=1.f; s_=0.f; g_z[1]=tol; }
      else { g_z[1]=t1; c_=z1/t1; s_=g_z[m]/t1; }
    } else {
      if (fabsf(z1)<=tol) g_z[1]=tol; else g_z[1]=z1;
    }
    for (int jj=2;jj<=K;++jj) g_z[jj]=g_zz[jj];
    if (m>n){
      for (int i=1;i<=nlp1;++i){
        float v=VT[(nlp1-1)*ld+(i-1)];
        VT[(m-1)*ld+(i-1)]=-s_*v;
        g_VT2[(i-1)]=c_*v;
      }
      for (int i=nlp2;i<=m;++i){
        float v=VT[(m-1)*ld+(i-1)];
        g_VT2[(i-1)]=s_*v;
        VT[(m-1)*ld+(i-1)]=c_*v;
      }
    } else {
      for (int i=1;i<=m;++i) g_VT2[(i-1)]=VT[(nlp1-1)*ld+(i-1)];
    }
    for (int jj=K+1;jj<=n;++jj) d[jj]=g_dsig[jj];
    double rho=0.0;
    for (int jj=1;jj<=K;++jj){ double zz2=(double)g_z[jj]; rho+=zz2*zz2; g_zorig[jj]=g_z[jj]; }
    g_rho_=rho;
  }
  __syncthreads();
  for (int t=tid;t<(n-K)*m;t+=nth){
    int jj=K+1+t/m, cc=t%m;
    VT[(jj-1)*ld+cc]=g_VT2[(jj-1)*LDV+cc];
  }
  __syncthreads();
  if (K==1){
    if (tid==0){
      d[1]=fabsf(g_z[1]);
      for (int cc=0;cc<m;++cc) VT[cc]=g_VT2[cc];
      slamrg(1,n-1,d,1,-1,idxq);
    }
    __syncthreads();
    return;
  }
  {
    double rho=g_rho_;
    for (int i=1+tid;i<=K;i+=nth){
      double di=(double)g_dsig[i];
      double lo=di*di, hi;
      if (i<K){ double dn=(double)g_dsig[i+1]; hi=dn*dn; }
      else { double dn=(double)g_dsig[K]; hi=dn*dn+rho; }
      for (int it=0;it<110;++it){
        double mid=0.5*(lo+hi);
        double f=1.0;
        for (int j=1;j<=K;++j){
          double dj=(double)g_dsig[j];
          double zj=(double)g_z[j];
          f+=zj*zj/(dj*dj-mid);
        }
        if (f>=0.0) hi=mid; else lo=mid;
      }
      g_root[i]=0.5*(lo+hi);
      d[i]=(float)sqrt(g_root[i]);
    }
  }
  __syncthreads();
  for (int i=1+tid;i<=K;i+=nth){
    double di=(double)g_dsig[i], di2=di*di;
    double p=di2-g_root[K];
    for (int j=1;j<=i-1;++j){
      double dj=(double)g_dsig[j];
      p*=(di2-g_root[j])/((di-dj)*(di+dj));
    }
    for (int j=i;j<=K-1;++j){
      double dj1=(double)g_dsig[j+1];
      p*=(di2-g_root[j])/((di-dj1)*(di+dj1));
    }
    g_ztmp[i]=copysignf((float)sqrt(fabs(p)),g_zorig[i]);
  }
  __syncthreads();
  for (int i=1+tid;i<=K;i+=nth) g_z[i]=g_ztmp[i];
  __syncthreads();
  for (int i=1+tid;i<=K;i+=nth){
    double xi=g_root[i];
    double nrm=0.0;
    for (int j=1;j<=K;++j){
      double dj=(double)g_dsig[j];
      double w=(double)g_z[j]/(dj*dj-xi);
      g_W[(i-1)*LDV+(j-1)]=(float)w;
      nrm+=w*w;
    }
    float inv=(float)(1.0/sqrt(nrm));
    for (int j=1;j<=K;++j) g_W[(i-1)*LDV+(j-1)]*=inv;
  }
  __syncthreads();
  for (int t=tid;t<K*m;t+=nth){
    int i=1+t/m, cc=t%m;
    float acc=0.f;
    for (int j=1;j<=K;++j)
      acc=fmaf(g_W[(i-1)*LDV+(j-1)],g_VT2[(j-1)*LDV+cc],acc);
    VT[(i-1)*ld+cc]=acc;
  }
  __syncthreads();
  if (tid==0) slamrg(K,n-K,d,1,-1,idxq);
  __syncthreads();
}

// ---------------- sbdsdc driver kernel (round-2 verbatim) ----------------
__global__ __launch_bounds__(1024) void k_sbdsdc(int n){
  const int tid=threadIdx.x, lane=tid&63, wv=tid>>6;
  for (int t=tid;t<n*n;t+=1024)
    g_VTr[(t/n)*LDV+(t%n)]=((t/n)==(t%n))?1.f:0.f;
  __syncthreads();
  if (n<=25){
    if (tid==0){
      slasdq_u(0,n,n,g_d,g_e,g_VTr,LDV);
      for (int j=1;j<=n;++j) g_idxq[j]=j;
    }
    __syncthreads();
  } else {
    if (tid==0){
      int lvl,nd;
      slasdt(n,&lvl,&nd,g_inode,g_ndiml,g_ndimr,25);
      g_nlvl_=lvl; g_nd_=nd;
    }
    __syncthreads();
    int nd=g_nd_, nlvl=g_nlvl_;
    int ndb1=(nd+1)/2;
    int ntask=(nd-ndb1+1)*2;
    for (int task=wv;task<ntask;task+=16){
      if (lane==0){
        int node=ndb1+(task>>1);
        int ic=g_inode[node], nl=g_ndiml[node], nr=g_ndimr[node];
        if ((task&1)==0){
          int nlf=ic-nl;
          slasdq_u(1,nl,nl+1,g_d+(nlf-1),g_e+(nlf-1),&g_VTr[(nlf-1)*LDV+(nlf-1)],LDV);
          for (int j2=1;j2<=nl;++j2) g_idxq[nlf-1+j2]=j2;
        } else {
          int nrf=ic+1;
          int sq=(node==nd)?0:1;
          slasdq_u(sq,nr,nr+sq,g_d+(nrf-1),g_e+(nrf-1),&g_VTr[(nrf-1)*LDV+(nrf-1)],LDV);
          for (int j2=1;j2<=nr;++j2) g_idxq[nrf-1+j2]=j2;
        }
      }
    }
    __syncthreads();
    for (int lvl=nlvl;lvl>=1;--lvl){
      int lf=(lvl==1)?1:(1<<(lvl-1));
      int llast=(lvl==1)?1:(2*lf-1);
      for (int node=lf;node<=llast;++node){
        int ic=g_inode[node], nl=g_ndiml[node], nr=g_ndimr[node];
        int nlf=ic-nl;
        int sq=(node==llast)?0:1;
        float alpha=g_d[ic], beta=g_e[ic];
        merge_node(nl,nr,sq,g_d+(nlf-1),g_idxq+(nlf-1),alpha,beta,
                   &g_VTr[(nlf-1)*LDV+(nlf-1)],LDV);
      }
    }
  }
  __syncthreads();
  for (int t=tid;t<n*512;t+=1024){
    int i=t/512, c=t%512;
    int o=g_idxq[n-i];
    float v=(c<n)?g_VTr[(o-1)*LDV+c]:0.f;
    g_VTc[i*512+c]=make_float2(v,0.f);
    if (c==0) g_sig[i]=g_d[o];
  }
}

// ---------------- small-site single-block kernels (round-2 verbatim) ----------------
__global__ void k_m0(const float* __restrict__ tf){
  int i=blockIdx.x*blockDim.x+threadIdx.x;
  if (i<1024) g_A[i]=make_float2(tf[2*i],tf[2*i+1]);
}

__global__ __launch_bounds__(1024) void k_lq(int m){
  const int n=512;
  const int tid=threadIdx.x, lane=tid&63, wv=tid>>6;
  __shared__ float s_part[16];
  __shared__ cplx s_tau, s_scal;
  __shared__ float s_beta; __shared__ int s_skip;
  for (int i=1;i<=m;++i){
    for (int c=i+tid;c<=n;c+=1024) g_A[(i-1)*512+(c-1)].y=-g_A[(i-1)*512+(c-1)].y;
    __syncthreads();
    float sq=0.f;
    for (int c=i+1+tid;c<=n;c+=1024){
      cplx a=g_A[(i-1)*512+(c-1)];
      sq=fmaf(a.x,a.x,fmaf(a.y,a.y,sq));
    }
    sq=wred(sq);
    if (lane==0) s_part[wv]=sq;
    __syncthreads();
    if (tid==0){
      float xn2=0.f; for (int w=0;w<16;w++) xn2+=s_part[w];
      RfgOut o=clarfg_head(g_A[(i-1)*512+(i-1)],xn2);
      s_beta=o.beta; s_tau=o.tau; s_scal=o.scal; s_skip=o.skip;
      g_tauf[i]=o.tau;
    }
    __syncthreads();
    if (!s_skip){
      for (int c=i+1+tid;c<=n;c+=1024)
        g_A[(i-1)*512+(c-1)]=cmul(g_A[(i-1)*512+(c-1)],s_scal);
    }
    __syncthreads();
    if (!s_skip){
      cplx tau=s_tau;
      for (int r=i+1+wv;r<=m;r+=16){
        cplx acc=make_float2(0.f,0.f);
        for (int c=i+lane;c<=n;c+=64){
          cplx u=(c==i)?make_float2(1.f,0.f):g_A[(i-1)*512+(c-1)];
          acc=cadd(acc,cmul(g_A[(r-1)*512+(c-1)],u));
        }
        acc.x=wred(acc.x); acc.y=wred(acc.y);
        acc.x=__shfl(acc.x,0); acc.y=__shfl(acc.y,0);
        cplx tw=cmul(tau,acc);
        for (int c=i+lane;c<=n;c+=64){
          cplx u=(c==i)?make_float2(1.f,0.f):g_A[(i-1)*512+(c-1)];
          g_A[(r-1)*512+(c-1)]=csub(g_A[(r-1)*512+(c-1)],cmul(tw,conjc(u)));
        }
      }
    }
    __syncthreads();
    if (tid==0) g_A[(i-1)*512+(i-1)]=make_float2(s_beta,0.f);
    __syncthreads();
  }
}

__global__ void k_copyL(int m){
  int t=blockIdx.x*blockDim.x+threadIdx.x;
  if (t>=m*m) return;
  int r=t/m, c=t%m;
  g_B[r*512+c]=(c<=r)?g_A[r*512+c]:make_float2(0.f,0.f);
}
__global__ void k_copyM(){
  int t=blockIdx.x*blockDim.x+threadIdx.x;
  if (t<512*512) g_B[t]=g_A[t];
}
__global__ void k_copyR_b(){
  int t=blockIdx.x*blockDim.x+threadIdx.x;
  if (t>=512*512) return;
  int r=t/512, c=t%512;
  g_B[t]=(c>r)?g_A[t]:((c==r)?make_float2(g_betaq[r+1],0.f):make_float2(0.f,0.f));
}

__global__ __launch_bounds__(1024) void k_bd(int n){
  const int tid=threadIdx.x, lane=tid&63, wv=tid>>6;
  __shared__ float s_part[16];
  __shared__ cplx s_tau, s_scal;
  __shared__ float s_beta; __shared__ int s_skip;
  for (int i=1;i<=n;++i){
    float sq=0.f;
    for (int r=i+1+tid;r<=n;r+=1024){
      cplx a=g_B[(r-1)*512+(i-1)];
      sq=fmaf(a.x,a.x,fmaf(a.y,a.y,sq));
    }
    sq=wred(sq);
    if (lane==0) s_part[wv]=sq;
    __syncthreads();
    if (tid==0){
      float xn2=0.f; for (int w=0;w<16;w++) xn2+=s_part[w];
      RfgOut o=clarfg_head(g_B[(i-1)*512+(i-1)],xn2);
      s_beta=o.beta; s_tau=o.tau; s_scal=o.scal; s_skip=o.skip;
      g_d[i]=o.beta;
    }
    __syncthreads();
    if (!s_skip){
      for (int r=i+1+tid;r<=n;r+=1024)
        g_B[(r-1)*512+(i-1)]=cmul(g_B[(r-1)*512+(i-1)],s_scal);
    }
    __syncthreads();
    if (!s_skip){
      cplx tauc=conjc(s_tau);
      for (int c=i+1+wv;c<=n;c+=16){
        cplx acc=make_float2(0.f,0.f);
        for (int r=i+lane;r<=n;r+=64){
          cplx v=(r==i)?make_float2(1.f,0.f):g_B[(r-1)*512+(i-1)];
          acc=cadd(acc,cmulc(v,g_B[(r-1)*512+(c-1)]));
        }
        acc.x=wred(acc.x); acc.y=wred(acc.y);
        acc.x=__shfl(acc.x,0); acc.y=__shfl(acc.y,0);
        cplx tw=cmul(tauc,acc);
        for (int r=i+lane;r<=n;r+=64){
          cplx v=(r==i)?make_float2(1.f,0.f):g_B[(r-1)*512+(i-1)];
          g_B[(r-1)*512+(c-1)]=csub(g_B[(r-1)*512+(c-1)],cmul(tw,v));
        }
      }
    }
    __syncthreads();
    if (tid==0) g_B[(i-1)*512+(i-1)]=make_float2(s_beta,0.f);
    __syncthreads();
    if (i<n){
      for (int c=i+1+tid;c<=n;c+=1024) g_B[(i-1)*512+(c-1)].y=-g_B[(i-1)*512+(c-1)].y;
      __syncthreads();
      float sq2=0.f;
      for (int c=i+2+tid;c<=n;c+=1024){
        cplx a=g_B[(i-1)*512+(c-1)];
        sq2=fmaf(a.x,a.x,fmaf(a.y,a.y,sq2));
      }
      sq2=wred(sq2);
      if (lane==0) s_part[wv]=sq2;
      __syncthreads();
      if (tid==0){
        float xn2=0.f; for (int w=0;w<16;w++) xn2+=s_part[w];
        RfgOut o=clarfg_head(g_B[(i-1)*512+(i)],xn2);
        s_beta=o.beta; s_tau=o.tau; s_scal=o.scal; s_skip=o.skip;
        g_e[i]=o.beta; g_taup[i]=o.tau;
      }
      __syncthreads();
      if (!s_skip){
        for (int c=i+2+tid;c<=n;c+=1024)
          g_B[(i-1)*512+(c-1)]=cmul(g_B[(i-1)*512+(c-1)],s_scal);
      }
      __syncthreads();
      if (!s_skip){
        cplx tau=s_tau;
        for (int r=i+1+wv;r<=n;r+=16){
          cplx acc=make_float2(0.f,0.f);
          for (int c=i+1+lane;c<=n;c+=64){
            cplx v=(c==i+1)?make_float2(1.f,0.f):g_B[(i-1)*512+(c-1)];
            acc=cadd(acc,cmul(g_B[(r-1)*512+(c-1)],v));
          }
          acc.x=wred(acc.x); acc.y=wred(acc.y);
          acc.x=__shfl(acc.x,0); acc.y=__shfl(acc.y,0);
          cplx tw=cmul(tau,acc);
          for (int c=i+1+lane;c<=n;c+=64){
            cplx v=(c==i+1)?make_float2(1.f,0.f):g_B[(i-1)*512+(c-1)];
            g_B[(r-1)*512+(c-1)]=csub(g_B[(r-1)*512+(c-1)],cmul(tw,conjc(v)));
          }
        }
      }
      __syncthreads();
      for (int c=i+2+tid;c<=n;c+=1024) g_B[(i-1)*512+(c-1)].y=-g_B[(i-1)*512+(c-1)].y;
      if (tid==0) g_B[(i-1)*512+(i)]=make_float2(s_beta,0.f);
      __syncthreads();
    }
  }
}

__global__ __launch_bounds__(1024) void k_applyPH(int n){
  const int tid=threadIdx.x, lane=tid&63, wv=tid>>6;
  for (int i=n-1;i>=1;--i){
    cplx tau=g_taup[i];
    if (tau.x==0.f && tau.y==0.f) continue;
    cplx tauc=conjc(tau);
    for (int r=1+wv;r<=n;r+=16){
      cplx acc=make_float2(0.f,0.f);
      for (int c=i+1+lane;c<=n;c+=64){
        cplx v=(c==i+1)?make_float2(1.f,0.f):conjc(g_B[(i-1)*512+(c-1)]);
        acc=cadd(acc,cmul(g_VTc[(r-1)*512+(c-1)],v));
      }
      acc.x=wred(acc.x); acc.y=wred(acc.y);
      acc.x=__shfl(acc.x,0); acc.y=__shfl(acc.y,0);
      cplx tw=cmul(tauc,acc);
      for (int c=i+1+lane;c<=n;c+=64){
        cplx vb=(c==i+1)?make_float2(1.f,0.f):g_B[(i-1)*512+(c-1)];
        g_VTc[(r-1)*512+(c-1)]=csub(g_VTc[(r-1)*512+(c-1)],cmul(tw,vb));
      }
    }
    __syncthreads();
  }
}

__global__ __launch_bounds__(1024) void k_applyQlq(int m){
  const int tid=threadIdx.x, lane=tid&63, wv=tid>>6;
  for (int i=m;i>=1;--i){
    cplx tau=g_tauf[i];
    if (tau.x==0.f && tau.y==0.f) continue;
    cplx tauc=conjc(tau);
    for (int r=1+wv;r<=m;r+=16){
      cplx acc=make_float2(0.f,0.f);
      for (int c=i+lane;c<=512;c+=64){
        cplx u=(c==i)?make_float2(1.f,0.f):g_A[(i-1)*512+(c-1)];
        acc=cadd(acc,cmul(g_VTc[(r-1)*512+(c-1)],u));
      }
      acc.x=wred(acc.x); acc.y=wred(acc.y);
      acc.x=__shfl(acc.x,0); acc.y=__shfl(acc.y,0);
      cplx tw=cmul(tauc,acc);
      for (int c=i+lane;c<=512;c+=64){
        cplx u=(c==i)?make_float2(1.f,0.f):g_A[(i-1)*512+(c-1)];
        g_VTc[(r-1)*512+(c-1)]=csub(g_VTc[(r-1)*512+(c-1)],cmul(tw,conjc(u)));
      }
    }
    __syncthreads();
  }
}

// ---------------- big-site QR: LDS panel (16 cols) + chained apply ----------------

// prologue: QR column-1 tail norm (rows 2..1024) -> g_scq[1]
__global__ __launch_bounds__(256) void u_qr_pro(){
  __shared__ float sr[256];
  int t=threadIdx.x;
  float sq=0.f;
  for (int r=2+t;r<=1024;r+=256){ cplx a=g_A[(r-1)*512]; sq=fmaf(a.x,a.x,fmaf(a.y,a.y,sq)); }
  sr[t]=sq; __syncthreads();
  for (int s=128;s>0;s>>=1){ if (t<s) sr[t]+=sr[t+s]; __syncthreads(); }
  if (t==0) g_scq[1]=sr[0];
}

// Panel: factor columns j0..j0+15 of g_A (1024x512) in LDS (raw storage,
// betas->g_betaq, norms->g_scq).  Per-column arithmetic identical to the
// verified u_qr / R5 p_qr_panel (wave-per-column, lanes over rows step 64).
__global__ __launch_bounds__(1024) void p_qr16(int j0){
  const int m=1024;
  const int tid=threadIdx.x, lane=tid&63, wv=tid>>6;
  __shared__ cplx slab[1024*PLS];
  __shared__ float s_x;
  const int nrow=m-j0+1;
  for (int t=tid;t<nrow*PNB;t+=1024){
    int rr=t/PNB, cl=t%PNB;
    slab[rr*PLS+cl]=g_A[(size_t)(j0-1+rr)*512+(j0-1+cl)];
  }
  if (tid==0) s_x=g_scq[j0];
  __syncthreads();
  for (int jl=0;jl<PNB;++jl){
    int j=j0+jl;
    float xn2=s_x;
    cplx alpha=slab[jl*PLS+jl];
    RfgOut o=clarfg_head(alpha,xn2);
    if (tid==0) g_betaq[j]=o.beta;
    __syncthreads();   // all reads of s_x/alpha done before overwrite
    cplx tauc=conjc(o.tau);
    for (int c=j+1+wv;c<=j0+PNB-1;c+=16){
      int cl=c-j0;
      cplx acc=make_float2(0.f,0.f);
      for (int r=j+lane;r<=m;r+=64){
        int rr=r-j0;
        cplx v=(r==j)?make_float2(1.f,0.f):cmul(slab[rr*PLS+jl],o.scal);
        acc=cadd(acc,cmulc(v,slab[rr*PLS+cl]));
      }
      acc.x=wred(acc.x); acc.y=wred(acc.y);
      acc.x=__shfl(acc.x,0); acc.y=__shfl(acc.y,0);
      cplx tw=cmul(tauc,acc);
      float nsq=0.f;
      for (int r=j+lane;r<=m;r+=64){
        int rr=r-j0;
        cplx v=(r==j)?make_float2(1.f,0.f):cmul(slab[rr*PLS+jl],o.scal);
        cplx nv=csub(slab[rr*PLS+cl],cmul(tw,v));
        slab[rr*PLS+cl]=nv;
        if (c==j+1 && r>=j+2) nsq=fmaf(nv.x,nv.x,fmaf(nv.y,nv.y,nsq));
      }
      if (c==j+1){
        nsq=wred(nsq);
        if (lane==0){ s_x=nsq; g_scq[j+1]=nsq; }
      }
    }
    __syncthreads();   // updates + s_x visible for next reflector
  }
  for (int t=tid;t<nrow*PNB;t+=1024){
    int rr=t/PNB, cl=t%PNB;
    g_A[(size_t)(j0-1+rr)*512+(j0-1+cl)]=slab[rr*PLS+cl];
  }
}

// Chained apply: trailing columns j0+16..512 receive reflectors j0..j0+15 in
// sequence (reflectors frozen; clarfg recomputed from g_A diag + g_scq).
// Wave owning column j0+16 computes next panel's entry norm (R5-verified).
__global__ __launch_bounds__(256) void p_apply16(int j0){
  const int m=1024, n=512;
  const int gtid=blockIdx.x*256+threadIdx.x;
  const int lane=gtid&63, gw=gtid>>6;
  for (int c=j0+PNB+gw;c<=n;c+=UW){
    for (int jl=0;jl<PNB;++jl){
      int j=j0+jl;
      RfgOut o=clarfg_head(g_A[(size_t)(j-1)*512+(j-1)], g_scq[j]);
      cplx tauc=conjc(o.tau);
      cplx acc=make_float2(0.f,0.f);
      for (int r=j+lane;r<=m;r+=64){
        cplx v=(r==j)?make_float2(1.f,0.f):cmul(g_A[(size_t)(r-1)*512+(j-1)],o.scal);
        acc=cadd(acc,cmulc(v,g_A[(size_t)(r-1)*512+(c-1)]));
      }
      acc.x=wred(acc.x); acc.y=wred(acc.y);
      acc.x=__shfl(acc.x,0); acc.y=__shfl(acc.y,0);
      cplx tw=cmul(tauc,acc);
      float nsq=0.f;
      for (int r=j+lane;r<=m;r+=64){
        cplx v=(r==j)?make_float2(1.f,0.f):cmul(g_A[(size_t)(r-1)*512+(j-1)],o.scal);
        cplx nv=csub(g_A[(size_t)(r-1)*512+(c-1)],cmul(tw,v));
        g_A[(size_t)(r-1)*512+(c-1)]=nv;
        if (c==j+1 && r>=j+2) nsq=fmaf(nv.x,nv.x,fmaf(nv.y,nv.y,nsq));
      }
      if (c==j+1 && jl==PNB-1){
        nsq=wred(nsq);
        if (lane==0) g_scq[j+1]=nsq;
      }
    }
  }
}

// ---------------- big-site BD: per-step kernels (R6) + LDS tail ----------------

// prologue: BD column-1 tail norm partials -> g_partR[0..511]
__global__ __launch_bounds__(512) void u_bd_pro(){
  int t=threadIdx.x;
  float sq=0.f;
  for (int r=2+t;r<=512;r+=512){ cplx a=g_B[(r-1)*512]; sq=fmaf(a.x,a.x,fmaf(a.y,a.y,sq)); }
  g_partR[t]=sq;
}

// cgebd2 column step i on g_B (512 x 512); raw; d[i]=beta; row-norm partials -> g_partC
__global__ __launch_bounds__(256) void u_bd_col(int i){
  const int n=512;
  float xn2c=reduce512(g_partR);
  int gtid=blockIdx.x*256+threadIdx.x;
  int lane=gtid&63, gw=gtid>>6;
  cplx alpha=g_B[(i-1)*512+(i-1)];
  RfgOut oc=clarfg_head(alpha,xn2c);
  if (gtid==0) g_d[i]=oc.beta;
  cplx tauc=conjc(oc.tau);
  float nsqA=0.f;
  for (int c=i+1+gw;c<=n;c+=UW){
    cplx acc=make_float2(0.f,0.f);
    for (int r=i+lane;r<=n;r+=64){
      cplx v=(r==i)?make_float2(1.f,0.f):cmul(g_B[(r-1)*512+(i-1)],oc.scal);
      acc=cadd(acc,cmulc(v,g_B[(r-1)*512+(c-1)]));
    }
    acc.x=wred(acc.x); acc.y=wred(acc.y);
    acc.x=__shfl(acc.x,0); acc.y=__shfl(acc.y,0);
    cplx tw=cmul(tauc,acc);
    for (int r=i+lane;r<=n;r+=64){
      cplx v=(r==i)?make_float2(1.f,0.f):cmul(g_B[(r-1)*512+(i-1)],oc.scal);
      cplx nv=csub(g_B[(r-1)*512+(c-1)],cmul(tw,v));
      g_B[(r-1)*512+(c-1)]=nv;
      if (r==i && c>=i+2) nsqA=fmaf(nv.x,nv.x,fmaf(nv.y,nv.y,nsqA));
    }
  }
  if (lane==0) g_partC[gw]=nsqA;
}

// cgebd2 row step i; raw; e[i]=beta, taup saved, row-norm saved to g_rn[i];
// next column-tail norm partials -> g_partR
__global__ __launch_bounds__(256) void u_bd_row(int i){
  const int n=512;
  float xn2r=reduce512(g_partC);
  int gtid=blockIdx.x*256+threadIdx.x;
  int lane=gtid&63, gw=gtid>>6;
  cplx alphar=conjc(g_B[(i-1)*512+(i)]);
  RfgOut orr=clarfg_head(alphar,xn2r);
  if (gtid==0){ g_e[i]=orr.beta; g_taup[i]=orr.tau; g_rn[i]=xn2r; }
  float nsqB=0.f;
  for (int r=i+1+gw;r<=n;r+=UW){
    cplx acc=make_float2(0.f,0.f);
    for (int c=i+1+lane;c<=n;c+=64){
      cplx v=(c==i+1)?make_float2(1.f,0.f):cmul(conjc(g_B[(i-1)*512+(c-1)]),orr.scal);
      acc=cadd(acc,cmul(g_B[(r-1)*512+(c-1)],v));
    }
    acc.x=wred(acc.x); acc.y=wred(acc.y);
    acc.x=__shfl(acc.x,0); acc.y=__shfl(acc.y,0);
    cplx tw=cmul(orr.tau,acc);
    for (int c=i+1+lane;c<=n;c+=64){
      cplx v=(c==i+1)?make_float2(1.f,0.f):cmul(conjc(g_B[(i-1)*512+(c-1)]),orr.scal);
      cplx nv=csub(g_B[(r-1)*512+(c-1)],cmul(tw,conjc(v)));
      g_B[(r-1)*512+(c-1)]=nv;
      if (c==i+1 && r>=i+2) nsqB=fmaf(nv.x,nv.x,fmaf(nv.y,nv.y,nsqB));
    }
  }
  if (lane==0) g_partR[gw]=nsqB;
}

// Fused LDS tail: steps TI0..512 (trailing 128x128 fits LDS).  Phase bodies
// mirror u_bd_col/u_bd_row (wave-per-column, lanes over rows); partial-sum
// grouping 16-wave (R5-verified class).
__global__ __launch_bounds__(1024) void u_bd_tail_lds(){
  const int n=512;
  const int tid=threadIdx.x, lane=tid&63, wv=tid>>6;
  __shared__ cplx tb[TN*TLS];
  __shared__ float s_p[16];
  __shared__ float sr[256];
  for (int t=tid;t<TN*TN;t+=1024){
    int rr=t/TN, cl=t%TN;
    tb[rr*TLS+cl]=g_B[(size_t)(TI0-1+rr)*512+(TI0-1+cl)];
  }
  if (tid<256) sr[tid]=g_partR[tid]+g_partR[tid+256];
  __syncthreads();
  for (int s=128;s>0;s>>=1){ if (tid<s) sr[tid]+=sr[tid+s]; __syncthreads(); }
  float xn2c=sr[0];
  for (int i=TI0;i<=n;++i){
    int il=i-TI0;
    // ---- column reflector ----
    cplx alpha=tb[il*TLS+il];
    RfgOut oc=clarfg_head(alpha,xn2c);
    if (tid==0) g_d[i]=oc.beta;
    __syncthreads();
    cplx tauc=conjc(oc.tau);
    float nsqA=0.f;
    for (int c=i+1+wv;c<=n;c+=16){
      int cl=c-TI0;
      cplx acc=make_float2(0.f,0.f);
      for (int r=i+lane;r<=n;r+=64){
        int rr=r-TI0;
        cplx v=(r==i)?make_float2(1.f,0.f):cmul(tb[rr*TLS+il],oc.scal);
        acc=cadd(acc,cmulc(v,tb[rr*TLS+cl]));
      }
      acc.x=wred(acc.x); acc.y=wred(acc.y);
      acc.x=__shfl(acc.x,0); acc.y=__shfl(acc.y,0);
      cplx tw=cmul(tauc,acc);
      for (int r=i+lane;r<=n;r+=64){
        int rr=r-TI0;
        cplx v=(r==i)?make_float2(1.f,0.f):cmul(tb[rr*TLS+il],oc.scal);
        cplx nv=csub(tb[rr*TLS+cl],cmul(tw,v));
        tb[rr*TLS+cl]=nv;
        if (r==i && c>=i+2) nsqA=fmaf(nv.x,nv.x,fmaf(nv.y,nv.y,nsqA));
      }
    }
    if (lane==0) s_p[wv]=nsqA;
    __syncthreads();
    if (i==n) break;
    float xn2r=0.f;
    for (int w=0;w<16;++w) xn2r+=s_p[w];
    // ---- row reflector ----
    cplx alphar=conjc(tb[il*TLS+(il+1)]);
    RfgOut orr=clarfg_head(alphar,xn2r);
    if (tid==0){ g_e[i]=orr.beta; g_taup[i]=orr.tau; g_rn[i]=xn2r; }
    __syncthreads();   // s_p reads complete before overwrite
    float nsqB=0.f;
    for (int r=i+1+wv;r<=n;r+=16){
      int rr=r-TI0;
      cplx acc=make_float2(0.f,0.f);
      for (int c=i+1+lane;c<=n;c+=64){
        int cl=c-TI0;
        cplx v=(c==i+1)?make_float2(1.f,0.f):cmul(conjc(tb[il*TLS+cl]),orr.scal);
        acc=cadd(acc,cmul(tb[rr*TLS+cl],v));
      }
      acc.x=wred(acc.x); acc.y=wred(acc.y);
      acc.x=__shfl(acc.x,0); acc.y=__shfl(acc.y,0);
      cplx tw=cmul(orr.tau,acc);
      for (int c=i+1+lane;c<=n;c+=64){
        int cl=c-TI0;
        cplx v=(c==i+1)?make_float2(1.f,0.f):cmul(conjc(tb[il*TLS+cl]),orr.scal);
        cplx nv=csub(tb[rr*TLS+cl],cmul(tw,conjc(v)));
        tb[rr*TLS+cl]=nv;
        if (c==i+1 && r>=i+2) nsqB=fmaf(nv.x,nv.x,fmaf(nv.y,nv.y,nsqB));
      }
    }
    if (lane==0) s_p[wv]=nsqB;
    __syncthreads();
    xn2c=0.f;
    for (int w=0;w<16;++w) xn2c+=s_p[w];
  }
  __syncthreads();
  for (int t=tid;t<TN*TN;t+=1024){
    int rr=t/TN, cl=t%TN;
    g_B[(size_t)(TI0-1+rr)*512+(TI0-1+cl)]=tb[rr*TLS+cl];
  }
}

// big-site P^H chain: VTc (512x512) <- VTc * prod_{i=511..1} G_i^H.
// 128 blocks x 4 waves, one VTc row per wave (R6 verbatim).
__global__ __launch_bounds__(256) void u_ph(){
  const int n=512;
  int b=blockIdx.x;
  int wv=threadIdx.x>>6, lane=threadIdx.x&63;
  int r=b*4+wv+1;
  for (int i=n-1;i>=1;--i){
    cplx alphar=conjc(g_B[(i-1)*512+(i)]);
    RfgOut o=clarfg_head(alphar,g_rn[i]);
    if (o.skip) continue;
    cplx tauc=conjc(o.tau);
    cplx acc=make_float2(0.f,0.f);
    for (int c=i+1+lane;c<=n;c+=64){
      cplx v=(c==i+1)?make_float2(1.f,0.f):cmul(conjc(g_B[(i-1)*512+(c-1)]),o.scal);
      acc=cadd(acc,cmul(g_VTc[(r-1)*512+(c-1)],v));
    }
    acc.x=wred(acc.x); acc.y=wred(acc.y);
    acc.x=__shfl(acc.x,0); acc.y=__shfl(acc.y,0);
    cplx tw=cmul(tauc,acc);
    for (int c=i+1+lane;c<=n;c+=64){
      cplx v=(c==i+1)?make_float2(1.f,0.f):cmul(conjc(g_B[(i-1)*512+(c-1)]),o.scal);
      g_VTc[(r-1)*512+(c-1)]=csub(g_VTc[(r-1)*512+(c-1)],cmul(tw,conjc(v)));
    }
  }
}

// ---------------- glue kernels ----------------
__global__ void k_formR(int kk){
  int t=blockIdx.x*blockDim.x+threadIdx.x;
  if (t>=kk*512) return;
  float s=g_sig[t/512];
  cplx v=g_VTc[t];
  g_R[t]=make_float2(s*v.x,s*v.y);
}

__global__ void k_next(const float* __restrict__ tmid, int site){
  int row=blockIdx.x;
  int a=row>>1, s=row&1;
  int b=blockIdx.y*blockDim.x+threadIdx.x;
  const float* base=tmid+(size_t)site*512*2*512*2;
  cplx acc=make_float2(0.f,0.f);
  for (int c=0;c<512;++c){
    cplx r=g_R[a*512+c];
    size_t off=((((size_t)c)*2+s)*512+b)*2;
    cplx x=make_float2(base[off],base[off+1]);
    acc=cadd(acc,cmul(r,x));
  }
  g_A[row*512+b]=acc;
}

__global__ void k_final(const float* __restrict__ tlast, float* __restrict__ out){
  int a=blockIdx.x*blockDim.x+threadIdx.x;
  if (a>=512) return;
  for (int s=0;s<2;++s){
    cplx acc=make_float2(0.f,0.f);
    for (int c=0;c<512;++c){
      cplx r=g_R[a*512+c];
      cplx x=make_float2(tlast[(c*2+s)*2],tlast[(c*2+s)*2+1]);
      acc=cadd(acc,cmul(r,x));
    }
    out[a*4+s*2+0]=acc.x;
    out[a*4+s*2+1]=acc.y;
  }
}

extern "C" void kernel_launch(void* const* d_in, const int* in_sizes, int n_in,
                              void* d_out, int out_size, void* d_ws, size_t ws_size,
                              hipStream_t stream) {
  const float* t_first=(const float*)d_in[0];
  const float* t_mid  =(const float*)d_in[1];
  const float* t_last =(const float*)d_in[2];
  float* out=(float*)d_out;
  (void)in_sizes; (void)n_in; (void)d_ws; (void)ws_size; (void)out_size;

  k_m0<<<dim3(4),256,0,stream>>>(t_first);

  int rows=2;
  for (int site=0;site<23;++site){
    int mm=rows;
    int nb=(mm<512)?mm:512;
    if (mm<512){
      // small sites: round-2 verified single-block path
      k_lq<<<1,1024,0,stream>>>(mm);
      k_copyL<<<dim3((mm*mm+255)/256),256,0,stream>>>(mm);
      k_bd<<<1,1024,0,stream>>>(mm);
      k_sbdsdc<<<1,1024,0,stream>>>(mm);
      k_applyPH<<<1,1024,0,stream>>>(mm);
      k_applyQlq<<<1,1024,0,stream>>>(mm);
    } else {
      if (mm==512){
        k_copyM<<<dim3((512*512+255)/256),256,0,stream>>>();
      } else {
        u_qr_pro<<<1,256,0,stream>>>();
        for (int p=0;p<32;++p){
          int j0=1+PNB*p;
          p_qr16<<<1,1024,0,stream>>>(j0);
          if (p<31) p_apply16<<<UBLK,256,0,stream>>>(j0);
        }
        k_copyR_b<<<dim3((512*512+255)/256),256,0,stream>>>();
      }
      u_bd_pro<<<1,512,0,stream>>>();
      for (int i=1;i<TI0;++i){
        u_bd_col<<<UBLK,256,0,stream>>>(i);
        u_bd_row<<<UBLK,256,0,stream>>>(i);
      }
      u_bd_tail_lds<<<1,1024,0,stream>>>();
      k_sbdsdc<<<1,1024,0,stream>>>(512);
      u_ph<<<UBLK,256,0,stream>>>();
    }
    k_formR<<<dim3((nb*512+255)/256),256,0,stream>>>(nb);
    if (site<22){
      k_next<<<dim3(2*nb,2),256,0,stream>>>(t_mid,site);
      rows=2*nb;
    } else {
      k_final<<<dim3(2),256,0,stream>>>(t_last,out);
    }
  }
}